// Round 11
// baseline (586.712 us; speedup 1.0000x reference)
//
#include <hip/hip_runtime.h>

#define NN 20000
#define NE 320000
#define EPN (NE + NN)   // edges + self loops = 340000
#define RP_STRIDE 20004
#define DCAP 96
#define KSPLIT 8
#define NQ (NE / 4)     // int4 groups per type

#define LRELU(e) ((e) > 0.f ? (e) : 0.2f * (e))

__device__ __forceinline__ void fma4(float4& a, float s, const float4& v) {
  a.x = fmaf(s, v.x, a.x); a.y = fmaf(s, v.y, a.y);
  a.z = fmaf(s, v.z, a.z); a.w = fmaf(s, v.w, a.w);
}

// ---------------- CSR build ----------------
__global__ void k_count(const int4* __restrict__ d0, const int4* __restrict__ d1,
                        const int4* __restrict__ d2, const int4* __restrict__ d3,
                        int* __restrict__ cnt) {
  int i = blockIdx.x * blockDim.x + threadIdx.x;
  if (i >= 4 * NQ) return;
  int t = i / NQ, j = i - t * NQ;
  const int4* d = t == 0 ? d0 : t == 1 ? d1 : t == 2 ? d2 : d3;
  int4 v = d[j];
  int* c = cnt + t * NN;
  atomicAdd(&c[v.x], 1); atomicAdd(&c[v.y], 1);
  atomicAdd(&c[v.z], 1); atomicAdd(&c[v.w], 1);
}

// self-loop (+1 per node) folded into the scan
__global__ void k_scan(const int* __restrict__ cnt, int* __restrict__ rp, int* __restrict__ tmp) {
  int t = blockIdx.x;
  const int* c = cnt + t * NN;
  int* r = rp + t * RP_STRIDE;
  int* tm = tmp + t * NN;
  __shared__ int part[256];
  int tid = threadIdx.x;
  const int CH = (NN + 255) / 256;
  int lo = tid * CH, hi = min(lo + CH, NN);
  int s = 0;
  for (int i = lo; i < hi; i++) s += c[i] + 1;
  part[tid] = s;
  __syncthreads();
  if (tid == 0) {
    int run = 0;
    for (int i = 0; i < 256; i++) { int v = part[i]; part[i] = run; run += v; }
  }
  __syncthreads();
  int run = part[tid];
  for (int i = lo; i < hi; i++) { r[i] = run; tm[i] = run; run += c[i] + 1; }
  if (lo < NN && hi == NN) r[NN] = run;
}

// dst-partitioned fill: blockIdx.x = partition (consecutive ids -> distinct XCDs),
// so each partition's col range is written by one XCD's L2 (no false sharing).
#define FCHUNK 4096
__global__ __launch_bounds__(256) void k_fill(
    const int* __restrict__ e0, const int* __restrict__ e1,
    const int* __restrict__ e2, const int* __restrict__ e3,
    int* __restrict__ tmp, int* __restrict__ col) {
  int p = blockIdx.x;
  int dlo = p * (NN / 8), dhi = dlo + (NN / 8);
  int base = blockIdx.y * FCHUNK;
  for (int o = threadIdx.x; o < FCHUNK; o += 256) {
    int i = base + o;
    if (i >= 4 * EPN) return;
    int t = i / EPN, j = i - t * EPN;
    int s, d;
    if (j < NE) {
      const int* eb = t == 0 ? e0 : t == 1 ? e1 : t == 2 ? e2 : e3;
      d = eb[NE + j];
      if (d < dlo || d >= dhi) continue;
      s = eb[j];
    } else {
      s = d = j - NE;
      if (d < dlo || d >= dhi) continue;
    }
    int pos = atomicAdd(&tmp[t * NN + d], 1);
    col[(size_t)t * EPN + pos] = s;
  }
}

// ---------------- prep: PT[slot][k] = sum_c W[t][k][h*64+c]*a[t][h][c]; bmean ----
__global__ void k_prep(const float* __restrict__ W0, const float* __restrict__ as0,
                       const float* __restrict__ ad0, const float* __restrict__ b0,
                       const float* __restrict__ W1, const float* __restrict__ as1,
                       const float* __restrict__ ad1, const float* __restrict__ b1,
                       float* __restrict__ PT0, float* __restrict__ PT1,
                       float* __restrict__ bmean) {
  int i = blockIdx.x * blockDim.x + threadIdx.x;
  if (i < 4096) {
    int r = i >> 7, k = i & 127;
    int sd = r >> 4, t = (r >> 2) & 3, h = r & 3;
    const float* a = (sd ? ad0 : as0) + (t * 4 + h) * 64;
    const float* wr = W0 + ((size_t)t * 128 + k) * 256 + h * 64;
    float s = 0.f;
    for (int c = 0; c < 64; c++) s = fmaf(wr[c], a[c], s);
    PT0[r * 128 + k] = s;
  } else if (i < 6144) {
    int j = i - 4096;
    int r = j >> 6, k = j & 63;
    int sd = r >> 4, t = (r >> 2) & 3, h = r & 3;
    const float* a = (sd ? ad1 : as1) + (t * 4 + h) * 64;
    const float* wr = W1 + ((size_t)t * 64 + k) * 256 + h * 64;
    float s = 0.f;
    for (int c = 0; c < 64; c++) s = fmaf(wr[c], a[c], s);
    PT1[r * 64 + k] = s;
  } else if (i < 6272) {
    int j = i - 6144;
    int l = j >> 6, c = j & 63;
    const float* b = l ? b1 : b0;
    bmean[j] = 0.25f * (b[c] + b[64 + c] + b[128 + c] + b[192 + c]);
  }
}

// ---------------- coefficients: asrc/adst[v][16] = x[v] @ PT^T ----------------
template <int K>
__global__ __launch_bounds__(256) void k_coef(const float* __restrict__ xin,
                                              const float* __restrict__ PT,
                                              float* __restrict__ asrc,
                                              float* __restrict__ adst) {
  __shared__ float PTs[32][K + 4];
  __shared__ float Xs[4][K];
  int tid = threadIdx.x;
#pragma unroll
  for (int j = 0; j < (32 * K) / 1024; j++) {
    int f4 = tid + j * 256;
    int r = f4 / (K / 4), c4 = (f4 % (K / 4)) * 4;
    *(float4*)&PTs[r][c4] = *(const float4*)(PT + r * K + c4);
  }
  int w = tid >> 6, lane = tid & 63;
  int v = blockIdx.x * 4 + w;
  if (lane * 2 < K)
    *(float2*)&Xs[w][lane * 2] = *(const float2*)(xin + (size_t)v * K + lane * 2);
  __syncthreads();
  int s = lane & 31, h2 = lane >> 5;
  float acc = 0.f;
#pragma unroll
  for (int i = 0; i < K / 8; i++) {
    int k = h2 * (K / 2) + i * 4;
    float4 p = *(const float4*)&PTs[s][k];
    float4 xv = *(const float4*)&Xs[w][k];
    acc = fmaf(p.x, xv.x, fmaf(p.y, xv.y, fmaf(p.z, xv.z, fmaf(p.w, xv.w, acc))));
  }
  acc += __shfl_xor(acc, 32);
  if (lane < 16) asrc[(size_t)v * 16 + lane] = acc;
  else if (lane < 32) adst[(size_t)v * 16 + (lane - 16)] = acc;
}

// ---------------- softmax weights: wlbuf[t*EPN+e] = alpha (4 heads) ----------
__global__ __launch_bounds__(256) void k_soft(
    const int* __restrict__ rp, const int* __restrict__ col,
    const float* __restrict__ asrc, const float* __restrict__ adst,
    float4* __restrict__ wlbuf) {
  __shared__ float wl[4][DCAP * 4];
  int t = threadIdx.x >> 6, lane = threadIdx.x & 63;
  int v = blockIdx.x;
  int beg = rp[t * RP_STRIDE + v], deg = rp[t * RP_STRIDE + v + 1] - beg;
  const int* colt = col + (size_t)t * EPN + beg;
  const float4* as4 = (const float4*)asrc;
  float4 adv = *(const float4*)(adst + (size_t)v * 16 + t * 4);
  float4* wlo = wlbuf + (size_t)t * EPN + beg;

  if (deg <= DCAP) {
    float m0 = -1e30f, m1 = -1e30f, m2 = -1e30f, m3 = -1e30f;
    for (int i = lane; i < deg; i += 64) {
      float4 a = as4[(size_t)colt[i] * 4 + t];
      float e0 = LRELU(a.x + adv.x), e1 = LRELU(a.y + adv.y);
      float e2 = LRELU(a.z + adv.z), e3 = LRELU(a.w + adv.w);
      *(float4*)&wl[t][i * 4] = make_float4(e0, e1, e2, e3);
      m0 = fmaxf(m0, e0); m1 = fmaxf(m1, e1);
      m2 = fmaxf(m2, e2); m3 = fmaxf(m3, e3);
    }
#pragma unroll
    for (int st = 1; st < 64; st <<= 1) {
      m0 = fmaxf(m0, __shfl_xor(m0, st)); m1 = fmaxf(m1, __shfl_xor(m1, st));
      m2 = fmaxf(m2, __shfl_xor(m2, st)); m3 = fmaxf(m3, __shfl_xor(m3, st));
    }
    float z0 = 0.f, z1 = 0.f, z2 = 0.f, z3 = 0.f;
    for (int i = lane; i < deg; i += 64) {
      float4 e = *(const float4*)&wl[t][i * 4];
      e.x = __expf(e.x - m0); e.y = __expf(e.y - m1);
      e.z = __expf(e.z - m2); e.w = __expf(e.w - m3);
      *(float4*)&wl[t][i * 4] = e;
      z0 += e.x; z1 += e.y; z2 += e.z; z3 += e.w;
    }
#pragma unroll
    for (int st = 1; st < 64; st <<= 1) {
      z0 += __shfl_xor(z0, st); z1 += __shfl_xor(z1, st);
      z2 += __shfl_xor(z2, st); z3 += __shfl_xor(z3, st);
    }
    float r0 = 1.f / z0, r1 = 1.f / z1, r2 = 1.f / z2, r3 = 1.f / z3;
    for (int i = lane; i < deg; i += 64) {
      float4 e = *(const float4*)&wl[t][i * 4];
      wlo[i] = make_float4(e.x * r0, e.y * r1, e.z * r2, e.w * r3);
    }
  } else {
    // unbounded-degree fallback: per-lane online, wave merge, streaming write
    float m[4] = {-1e30f, -1e30f, -1e30f, -1e30f};
    float z[4] = {0.f, 0.f, 0.f, 0.f};
    float ad[4] = {adv.x, adv.y, adv.z, adv.w};
    for (int i = lane; i < deg; i += 64) {
      float4 a = as4[(size_t)colt[i] * 4 + t];
      float ev[4] = {LRELU(a.x + ad[0]), LRELU(a.y + ad[1]),
                     LRELU(a.z + ad[2]), LRELU(a.w + ad[3])};
#pragma unroll
      for (int h = 0; h < 4; h++) {
        float nm = fmaxf(m[h], ev[h]);
        z[h] = z[h] * __expf(m[h] - nm) + __expf(ev[h] - nm);
        m[h] = nm;
      }
    }
#pragma unroll
    for (int st = 1; st < 64; st <<= 1)
#pragma unroll
      for (int h = 0; h < 4; h++) {
        float m2_ = __shfl_xor(m[h], st), z2_ = __shfl_xor(z[h], st);
        float nm = fmaxf(m[h], m2_);
        z[h] = z[h] * __expf(m[h] - nm) + z2_ * __expf(m2_ - nm);
        m[h] = nm;
      }
    float rz[4];
#pragma unroll
    for (int h = 0; h < 4; h++) rz[h] = 1.f / z[h];
    for (int i = lane; i < deg; i += 64) {
      float4 a = as4[(size_t)colt[i] * 4 + t];
      float4 o;
      o.x = __expf(LRELU(a.x + ad[0]) - m[0]) * rz[0];
      o.y = __expf(LRELU(a.y + ad[1]) - m[1]) * rz[1];
      o.z = __expf(LRELU(a.z + ad[2]) - m[2]) * rz[2];
      o.w = __expf(LRELU(a.w + ad[3]) - m[3]) * rz[3];
      wlo[i] = o;
    }
  }
}

// ------- chunked gather: grid (NN/8, K/32); 8-lane group = one (node,type) ----
// Chunk (32 cols = 2.5 MB slice) is the slow grid axis -> stays L2-resident.
template <int K>
__global__ __launch_bounds__(256) void k_gather(
    const int* __restrict__ rp, const int* __restrict__ col,
    const float4* __restrict__ wlbuf, const float* __restrict__ x,
    float* __restrict__ y) {
  int g = threadIdx.x >> 3, l8 = threadIdx.x & 7;
  int v = blockIdx.x * 8 + (g >> 2), t = g & 3;
  int cc = blockIdx.y << 5;
  int beg = rp[t * RP_STRIDE + v], deg = rp[t * RP_STRIDE + v + 1] - beg;
  const int* colt = col + (size_t)t * EPN + beg;
  const float4* wlt = wlbuf + (size_t)t * EPN + beg;
  const float* xb = x + cc + l8 * 4;
  float4 a0 = {0, 0, 0, 0}, a1 = a0, a2 = a0, a3 = a0;
  int i = 0;
  for (; i + 2 <= deg; i += 2) {
    int s0 = colt[i], s1 = colt[i + 1];
    float4 w0 = wlt[i], w1 = wlt[i + 1];
    float4 x0 = *(const float4*)(xb + (size_t)s0 * K);
    float4 x1 = *(const float4*)(xb + (size_t)s1 * K);
    fma4(a0, w0.x, x0); fma4(a1, w0.y, x0); fma4(a2, w0.z, x0); fma4(a3, w0.w, x0);
    fma4(a0, w1.x, x1); fma4(a1, w1.y, x1); fma4(a2, w1.z, x1); fma4(a3, w1.w, x1);
  }
  if (i < deg) {
    int s0 = colt[i];
    float4 w0 = wlt[i];
    float4 x0 = *(const float4*)(xb + (size_t)s0 * K);
    fma4(a0, w0.x, x0); fma4(a1, w0.y, x0); fma4(a2, w0.z, x0); fma4(a3, w0.w, x0);
  }
  float* yb = y + (size_t)v * (16 * K) + (size_t)t * 4 * K + cc + l8 * 4;
  *(float4*)(yb + 0 * K) = a0;
  *(float4*)(yb + 1 * K) = a1;
  *(float4*)(yb + 2 * K) = a2;
  *(float4*)(yb + 3 * K) = a3;
}

// ------- split-K output GEMM: part[ks] = y[:, chunk] @ B[chunk, :] -------
template <int K>
__global__ __launch_bounds__(256) void k_out_s(const float* __restrict__ y,
                                               const float* __restrict__ W,
                                               float* __restrict__ part) {
  constexpr int KT = 16 * K;
  constexpr int CHUNK = KT / KSPLIT;
  __shared__ float As[32][65];
  __shared__ float Bs[32][68];
  int tid = threadIdx.x;
  int row0 = blockIdx.x * 64;
  int ks = blockIdx.y;
  int tx = tid & 15, ty = tid >> 4;
  float acc[4][4] = {};
  for (int kb = ks * CHUNK; kb < (ks + 1) * CHUNK; kb += 32) {
    int tt = kb / (4 * K), hh = (kb / K) & 3, kk0 = kb % K;
#pragma unroll
    for (int j = 0; j < 2; j++) {
      int idx = tid + j * 256;
      int r = idx >> 3, k4 = (idx & 7) * 4;
      float4 vv = make_float4(0.f, 0.f, 0.f, 0.f);
      if (row0 + r < NN) vv = *(const float4*)(y + (size_t)(row0 + r) * KT + kb + k4);
      As[k4 + 0][r] = vv.x; As[k4 + 1][r] = vv.y;
      As[k4 + 2][r] = vv.z; As[k4 + 3][r] = vv.w;
    }
#pragma unroll
    for (int j = 0; j < 2; j++) {
      int idx = tid + j * 256;
      int kk = idx >> 4, cc4 = (idx & 15) * 4;
      *(float4*)&Bs[kk][cc4] =
          *(const float4*)(W + ((size_t)tt * K + kk0 + kk) * 256 + hh * 64 + cc4);
    }
    __syncthreads();
#pragma unroll 4
    for (int kk = 0; kk < 32; kk++) {
      float4 a4 = *(const float4*)&As[kk][ty * 4];
      float4 b4 = *(const float4*)&Bs[kk][tx * 4];
      float aa[4] = {a4.x, a4.y, a4.z, a4.w};
      float bb[4] = {b4.x, b4.y, b4.z, b4.w};
#pragma unroll
      for (int i = 0; i < 4; i++)
#pragma unroll
        for (int j = 0; j < 4; j++) acc[i][j] = fmaf(aa[i], bb[j], acc[i][j]);
    }
    __syncthreads();
  }
#pragma unroll
  for (int i = 0; i < 4; i++) {
    int gr = row0 + ty * 4 + i;
    if (gr < NN)
      *(float4*)(part + (size_t)ks * NN * 64 + (size_t)gr * 64 + tx * 4) =
          make_float4(acc[i][0], acc[i][1], acc[i][2], acc[i][3]);
  }
}

// reduce KSPLIT partials: xout = relu(1/16*sum + bmean)
__global__ void k_red(const float* __restrict__ part, const float* __restrict__ bm,
                      float* __restrict__ xout) {
  int i = blockIdx.x * blockDim.x + threadIdx.x;   // float4 index
  if (i >= NN * 16) return;
  float4 s = make_float4(0.f, 0.f, 0.f, 0.f);
#pragma unroll
  for (int ks = 0; ks < KSPLIT; ks++) {
    float4 p = *(const float4*)(part + (size_t)ks * NN * 64 + (size_t)i * 4);
    s.x += p.x; s.y += p.y; s.z += p.z; s.w += p.w;
  }
  float4 b = *(const float4*)(bm + ((i & 15) << 2));
  float4 o;
  o.x = fmaxf(0.0625f * s.x + b.x, 0.f);
  o.y = fmaxf(0.0625f * s.y + b.y, 0.f);
  o.z = fmaxf(0.0625f * s.z + b.z, 0.f);
  o.w = fmaxf(0.0625f * s.w + b.w, 0.f);
  *(float4*)(xout + (size_t)i * 4) = o;
}

// ------- merged (non-split) output GEMM, fallback for smaller ws -------
template <int K>
__global__ __launch_bounds__(256) void k_out_m(const float* __restrict__ y,
                                               const float* __restrict__ W,
                                               const float* __restrict__ bm,
                                               float* __restrict__ xout) {
  constexpr int KT = 16 * K;
  __shared__ float As[32][65];
  __shared__ float Bs[32][68];
  int tid = threadIdx.x;
  int row0 = blockIdx.x * 64;
  int tx = tid & 15, ty = tid >> 4;
  float acc[4][4] = {};
  for (int kb = 0; kb < KT; kb += 32) {
    int tt = kb / (4 * K), hh = (kb / K) & 3, kk0 = kb % K;
#pragma unroll
    for (int j = 0; j < 2; j++) {
      int idx = tid + j * 256;
      int r = idx >> 3, k4 = (idx & 7) * 4;
      float4 vv = make_float4(0.f, 0.f, 0.f, 0.f);
      if (row0 + r < NN) vv = *(const float4*)(y + (size_t)(row0 + r) * KT + kb + k4);
      As[k4 + 0][r] = vv.x; As[k4 + 1][r] = vv.y;
      As[k4 + 2][r] = vv.z; As[k4 + 3][r] = vv.w;
    }
#pragma unroll
    for (int j = 0; j < 2; j++) {
      int idx = tid + j * 256;
      int kk = idx >> 4, cc4 = (idx & 15) * 4;
      *(float4*)&Bs[kk][cc4] =
          *(const float4*)(W + ((size_t)tt * K + kk0 + kk) * 256 + hh * 64 + cc4);
    }
    __syncthreads();
#pragma unroll 4
    for (int kk = 0; kk < 32; kk++) {
      float4 a4 = *(const float4*)&As[kk][ty * 4];
      float4 b4 = *(const float4*)&Bs[kk][tx * 4];
      float aa[4] = {a4.x, a4.y, a4.z, a4.w};
      float bb[4] = {b4.x, b4.y, b4.z, b4.w};
#pragma unroll
      for (int i = 0; i < 4; i++)
#pragma unroll
        for (int j = 0; j < 4; j++) acc[i][j] = fmaf(aa[i], bb[j], acc[i][j]);
    }
    __syncthreads();
  }
#pragma unroll
  for (int i = 0; i < 4; i++) {
    int gr = row0 + ty * 4 + i;
    if (gr < NN) {
      float4 o;
      o.x = fmaxf(0.0625f * acc[i][0] + bm[tx * 4 + 0], 0.f);
      o.y = fmaxf(0.0625f * acc[i][1] + bm[tx * 4 + 1], 0.f);
      o.z = fmaxf(0.0625f * acc[i][2] + bm[tx * 4 + 2], 0.f);
      o.w = fmaxf(0.0625f * acc[i][3] + bm[tx * 4 + 3], 0.f);
      *(float4*)(xout + (size_t)gr * 64 + tx * 4) = o;
    }
  }
}

__global__ void k_linear(const float* __restrict__ x, const float* __restrict__ W,
                         const float* __restrict__ b, float* __restrict__ out) {
  int i = blockIdx.x * blockDim.x + threadIdx.x;
  if (i >= NN * 32) return;
  int v = i >> 5, o = i & 31;
  float acc = b[o];
#pragma unroll
  for (int c = 0; c < 64; c++) acc = fmaf(x[v * 64 + c], W[c * 32 + o], acc);
  out[i] = acc;
}

extern "C" void kernel_launch(void* const* d_in, const int* in_sizes, int n_in,
                              void* d_out, int out_size, void* d_ws, size_t ws_size,
                              hipStream_t stream) {
  const float* x = (const float*)d_in[0];
  const int* e0 = (const int*)d_in[1];
  const int* e1 = (const int*)d_in[2];
  const int* e2 = (const int*)d_in[3];
  const int* e3 = (const int*)d_in[4];
  const float* W0 = (const float*)d_in[5];
  const float* as0 = (const float*)d_in[6];
  const float* ad0 = (const float*)d_in[7];
  const float* b0 = (const float*)d_in[8];
  const float* W1 = (const float*)d_in[9];
  const float* as1 = (const float*)d_in[10];
  const float* ad1 = (const float*)d_in[11];
  const float* b1 = (const float*)d_in[12];
  const float* linW = (const float*)d_in[13];
  const float* linb = (const float*)d_in[14];
  float* out = (float*)d_out;
  (void)in_sizes; (void)n_in; (void)out_size;

  bool splitk = ws_size >= (size_t)230 * 1024 * 1024;

  char* wsb = (char*)d_ws;
  size_t off = 0;
  auto carve = [&](size_t bytes) -> char* {
    off = (off + 255) & ~(size_t)255;
    char* p = wsb + off;
    off += bytes;
    return p;
  };
  int* cnt     = (int*)carve((size_t)4 * NN * sizeof(int));
  int* tmp     = (int*)carve((size_t)4 * NN * sizeof(int));
  int* rp      = (int*)carve((size_t)4 * RP_STRIDE * sizeof(int));
  int* col     = (int*)carve((size_t)4 * EPN * sizeof(int));
  float* asrc  = (float*)carve((size_t)NN * 16 * sizeof(float));
  float* adst  = (float*)carve((size_t)NN * 16 * sizeof(float));
  float* PT0   = (float*)carve((size_t)32 * 128 * sizeof(float));
  float* PT1   = (float*)carve((size_t)32 * 64 * sizeof(float));
  float* bmean = (float*)carve((size_t)128 * sizeof(float));
  float* xmid  = (float*)carve((size_t)NN * 64 * sizeof(float));
  float* y     = (float*)carve((size_t)NN * 2048 * sizeof(float));
  float* part  = splitk ? (float*)carve((size_t)KSPLIT * NN * 64 * sizeof(float)) : nullptr;
  // wlbuf (21.8 MB) aliases part (41 MB): lifetimes are disjoint (soft/gather vs out_s/red)
  float4* wlbuf = splitk ? (float4*)part
                         : (float4*)carve((size_t)4 * EPN * 4 * sizeof(float));

  // CSR build
  hipMemsetAsync(cnt, 0, (size_t)4 * NN * sizeof(int), stream);
  k_count<<<(4 * NQ + 255) / 256, 256, 0, stream>>>(
      (const int4*)(e0 + NE), (const int4*)(e1 + NE),
      (const int4*)(e2 + NE), (const int4*)(e3 + NE), cnt);
  k_scan<<<4, 256, 0, stream>>>(cnt, rp, tmp);
  k_fill<<<dim3(8, (4 * EPN + FCHUNK - 1) / FCHUNK), 256, 0, stream>>>(
      e0, e1, e2, e3, tmp, col);

  k_prep<<<25, 256, 0, stream>>>(W0, as0, ad0, b0, W1, as1, ad1, b1, PT0, PT1, bmean);

  // ---- layer 0 (K=128, KT=2048) ----
  k_coef<128><<<5000, 256, 0, stream>>>(x, PT0, asrc, adst);
  k_soft<<<NN, 256, 0, stream>>>(rp, col, asrc, adst, wlbuf);
  k_gather<128><<<dim3(NN / 8, 4), 256, 0, stream>>>(rp, col, wlbuf, x, y);
  if (splitk) {
    k_out_s<128><<<dim3(313, KSPLIT), 256, 0, stream>>>(y, W0, part);
    k_red<<<(NN * 16 + 255) / 256, 256, 0, stream>>>(part, bmean, xmid);
  } else {
    k_out_m<128><<<313, 256, 0, stream>>>(y, W0, bmean, xmid);
  }

  // ---- layer 1 (K=64, KT=1024) ----
  k_coef<64><<<5000, 256, 0, stream>>>(xmid, PT1, asrc, adst);
  k_soft<<<NN, 256, 0, stream>>>(rp, col, asrc, adst, wlbuf);
  k_gather<64><<<dim3(NN / 8, 2), 256, 0, stream>>>(rp, col, wlbuf, xmid, y);
  if (splitk) {
    k_out_s<64><<<dim3(313, KSPLIT), 256, 0, stream>>>(y, W1, part);
    k_red<<<(NN * 16 + 255) / 256, 256, 0, stream>>>(part, bmean + 64, xmid);
  } else {
    k_out_m<64><<<313, 256, 0, stream>>>(y, W1, bmean + 64, xmid);
  }

  k_linear<<<(NN * 32 + 255) / 256, 256, 0, stream>>>(xmid, linW, linb, out);
}

// Round 12
// 497.720 us; speedup vs baseline: 1.1788x; 1.1788x over previous
//
#include <hip/hip_runtime.h>

#define NN 20000
#define NE 320000
#define EPN (NE + NN)   // edges + self loops = 340000
#define RP_STRIDE 20004
#define DCAP 96
#define KSPLIT 4

#define LRELU(e) ((e) > 0.f ? (e) : 0.2f * (e))

// round-to-nearest-even fp32 -> bf16
__device__ __forceinline__ unsigned short bf16r(float f) {
  union { float f; unsigned int u; } c;
  c.f = f;
  unsigned int r = (c.u + 0x7FFFu + ((c.u >> 16) & 1u)) >> 16;
  return (unsigned short)r;
}
__device__ __forceinline__ float bflo(unsigned int u) {
  return __uint_as_float(u << 16);
}
__device__ __forceinline__ float bfhi(unsigned int u) {
  return __uint_as_float(u & 0xFFFF0000u);
}

// ---------------- CSR build ----------------
__global__ void k_count(const int* __restrict__ d0, const int* __restrict__ d1,
                        const int* __restrict__ d2, const int* __restrict__ d3,
                        int* __restrict__ cnt) {
  int i = blockIdx.x * blockDim.x + threadIdx.x;
  if (i >= 4 * NE) return;
  int t = i / NE, e = i - t * NE;
  const int* d = t == 0 ? d0 : t == 1 ? d1 : t == 2 ? d2 : d3;
  atomicAdd(&cnt[t * NN + d[e]], 1);
}

// self-loop (+1 per node) folded into the scan
__global__ void k_scan(const int* __restrict__ cnt, int* __restrict__ rp, int* __restrict__ tmp) {
  int t = blockIdx.x;
  const int* c = cnt + t * NN;
  int* r = rp + t * RP_STRIDE;
  int* tm = tmp + t * NN;
  __shared__ int part[256];
  int tid = threadIdx.x;
  const int CH = (NN + 255) / 256;
  int lo = tid * CH, hi = min(lo + CH, NN);
  int s = 0;
  for (int i = lo; i < hi; i++) s += c[i] + 1;
  part[tid] = s;
  __syncthreads();
  if (tid == 0) {
    int run = 0;
    for (int i = 0; i < 256; i++) { int v = part[i]; part[i] = run; run += v; }
  }
  __syncthreads();
  int run = part[tid];
  for (int i = lo; i < hi; i++) { r[i] = run; tm[i] = run; run += c[i] + 1; }
  if (lo < NN && hi == NN) r[NN] = run;
}

__global__ void k_fill(const int* __restrict__ e0, const int* __restrict__ e1,
                       const int* __restrict__ e2, const int* __restrict__ e3,
                       int* __restrict__ tmp, int* __restrict__ col) {
  int i = blockIdx.x * blockDim.x + threadIdx.x;
  if (i >= 4 * EPN) return;
  int t = i / EPN, j = i - t * EPN;
  const int* eb = t == 0 ? e0 : t == 1 ? e1 : t == 2 ? e2 : e3;
  int s, d;
  if (j < NE) { s = eb[j]; d = eb[NE + j]; } else { s = d = j - NE; }
  int pos = atomicAdd(&tmp[t * NN + d], 1);
  col[(size_t)t * EPN + pos] = s;
}

// ---------------- prep: PT[slot][k] = sum_c W[t][k][h*64+c]*a[t][h][c]; bmean ----
__global__ void k_prep(const float* __restrict__ W0, const float* __restrict__ as0,
                       const float* __restrict__ ad0, const float* __restrict__ b0,
                       const float* __restrict__ W1, const float* __restrict__ as1,
                       const float* __restrict__ ad1, const float* __restrict__ b1,
                       float* __restrict__ PT0, float* __restrict__ PT1,
                       float* __restrict__ bmean) {
  int i = blockIdx.x * blockDim.x + threadIdx.x;
  if (i < 4096) {
    int r = i >> 7, k = i & 127;
    int sd = r >> 4, t = (r >> 2) & 3, h = r & 3;
    const float* a = (sd ? ad0 : as0) + (t * 4 + h) * 64;
    const float* wr = W0 + ((size_t)t * 128 + k) * 256 + h * 64;
    float s = 0.f;
    for (int c = 0; c < 64; c++) s = fmaf(wr[c], a[c], s);
    PT0[r * 128 + k] = s;
  } else if (i < 6144) {
    int j = i - 4096;
    int r = j >> 6, k = j & 63;
    int sd = r >> 4, t = (r >> 2) & 3, h = r & 3;
    const float* a = (sd ? ad1 : as1) + (t * 4 + h) * 64;
    const float* wr = W1 + ((size_t)t * 64 + k) * 256 + h * 64;
    float s = 0.f;
    for (int c = 0; c < 64; c++) s = fmaf(wr[c], a[c], s);
    PT1[r * 64 + k] = s;
  } else if (i < 6272) {
    int j = i - 6144;
    int l = j >> 6, c = j & 63;
    const float* b = l ? b1 : b0;
    bmean[j] = 0.25f * (b[c] + b[64 + c] + b[128 + c] + b[192 + c]);
  }
}

// ---------------- coefficients: asrc/adst[v][16] = x[v] @ PT^T ----------------
template <int K>
__global__ __launch_bounds__(256) void k_coef(const float* __restrict__ xin,
                                              const float* __restrict__ PT,
                                              float* __restrict__ asrc,
                                              float* __restrict__ adst) {
  __shared__ float PTs[32][K + 4];
  __shared__ float Xs[4][K];
  int tid = threadIdx.x;
#pragma unroll
  for (int j = 0; j < (32 * K) / 1024; j++) {
    int f4 = tid + j * 256;
    int r = f4 / (K / 4), c4 = (f4 % (K / 4)) * 4;
    *(float4*)&PTs[r][c4] = *(const float4*)(PT + r * K + c4);
  }
  int w = tid >> 6, lane = tid & 63;
  int v = blockIdx.x * 4 + w;
  if (lane * 2 < K)
    *(float2*)&Xs[w][lane * 2] = *(const float2*)(xin + (size_t)v * K + lane * 2);
  __syncthreads();
  int s = lane & 31, h2 = lane >> 5;
  float acc = 0.f;
#pragma unroll
  for (int i = 0; i < K / 8; i++) {
    int k = h2 * (K / 2) + i * 4;
    float4 p = *(const float4*)&PTs[s][k];
    float4 xv = *(const float4*)&Xs[w][k];
    acc = fmaf(p.x, xv.x, fmaf(p.y, xv.y, fmaf(p.z, xv.z, fmaf(p.w, xv.w, acc))));
  }
  acc += __shfl_xor(acc, 32);
  if (lane < 16) asrc[(size_t)v * 16 + lane] = acc;
  else if (lane < 32) adst[(size_t)v * 16 + (lane - 16)] = acc;
}

// ------- x-space aggregation (R9 structure): block = 1 node, wave = 1 type ----
// Pass1: edge-per-lane, asrc gathered once, e->LDS, fmax tree; exp LDS-local.
// Pass2: pure gather. y (bf16) [v][t*4K + h*K + k].
template <int K>
__global__ __launch_bounds__(256) void k_aggx3(
    const int* __restrict__ rp, const int* __restrict__ col,
    const float* __restrict__ asrc, const float* __restrict__ adst,
    const float* __restrict__ x, unsigned short* __restrict__ y) {
  constexpr int GL = K / 4;    // lanes per group (32 / 16)
  constexpr int G = 64 / GL;   // edge groups per wave (2 / 4)
  __shared__ float wl[4][DCAP * 4];
  __shared__ int scol[4][DCAP];
  int t = threadIdx.x >> 6, lane = threadIdx.x & 63;
  int v = blockIdx.x;
  int beg = rp[t * RP_STRIDE + v], deg = rp[t * RP_STRIDE + v + 1] - beg;
  const int* colt = col + (size_t)t * EPN + beg;
  float4 adv = *(const float4*)(adst + (size_t)v * 16 + t * 4);
  int g = lane / GL, c4 = (lane % GL) * 4;
  float acc[4][4] = {};
  float rz[4];

  if (deg <= DCAP) {
    float m0 = -1e30f, m1 = -1e30f, m2 = -1e30f, m3 = -1e30f;
    for (int i = lane; i < deg; i += 64) {
      int s = colt[i];
      scol[t][i] = s;
      float4 a = *(const float4*)(asrc + (size_t)s * 16 + t * 4);
      float e0 = LRELU(a.x + adv.x), e1 = LRELU(a.y + adv.y);
      float e2 = LRELU(a.z + adv.z), e3 = LRELU(a.w + adv.w);
      *(float4*)&wl[t][i * 4] = make_float4(e0, e1, e2, e3);
      m0 = fmaxf(m0, e0); m1 = fmaxf(m1, e1);
      m2 = fmaxf(m2, e2); m3 = fmaxf(m3, e3);
    }
#pragma unroll
    for (int st = 1; st < 64; st <<= 1) {
      m0 = fmaxf(m0, __shfl_xor(m0, st)); m1 = fmaxf(m1, __shfl_xor(m1, st));
      m2 = fmaxf(m2, __shfl_xor(m2, st)); m3 = fmaxf(m3, __shfl_xor(m3, st));
    }
    float z0 = 0.f, z1 = 0.f, z2 = 0.f, z3 = 0.f;
    for (int i = lane; i < deg; i += 64) {
      float4 e = *(const float4*)&wl[t][i * 4];
      e.x = __expf(e.x - m0); e.y = __expf(e.y - m1);
      e.z = __expf(e.z - m2); e.w = __expf(e.w - m3);
      *(float4*)&wl[t][i * 4] = e;
      z0 += e.x; z1 += e.y; z2 += e.z; z3 += e.w;
    }
#pragma unroll
    for (int st = 1; st < 64; st <<= 1) {
      z0 += __shfl_xor(z0, st); z1 += __shfl_xor(z1, st);
      z2 += __shfl_xor(z2, st); z3 += __shfl_xor(z3, st);
    }
    rz[0] = 1.f / z0; rz[1] = 1.f / z1; rz[2] = 1.f / z2; rz[3] = 1.f / z3;
    for (int i = g; i < deg; i += G) {
      float4 wv = *(const float4*)&wl[t][i * 4];
      float4 xv = *(const float4*)(x + (size_t)scol[t][i] * K + c4);
      acc[0][0] = fmaf(wv.x, xv.x, acc[0][0]); acc[0][1] = fmaf(wv.x, xv.y, acc[0][1]);
      acc[0][2] = fmaf(wv.x, xv.z, acc[0][2]); acc[0][3] = fmaf(wv.x, xv.w, acc[0][3]);
      acc[1][0] = fmaf(wv.y, xv.x, acc[1][0]); acc[1][1] = fmaf(wv.y, xv.y, acc[1][1]);
      acc[1][2] = fmaf(wv.y, xv.z, acc[1][2]); acc[1][3] = fmaf(wv.y, xv.w, acc[1][3]);
      acc[2][0] = fmaf(wv.z, xv.x, acc[2][0]); acc[2][1] = fmaf(wv.z, xv.y, acc[2][1]);
      acc[2][2] = fmaf(wv.z, xv.z, acc[2][2]); acc[2][3] = fmaf(wv.z, xv.w, acc[2][3]);
      acc[3][0] = fmaf(wv.w, xv.x, acc[3][0]); acc[3][1] = fmaf(wv.w, xv.y, acc[3][1]);
      acc[3][2] = fmaf(wv.w, xv.z, acc[3][2]); acc[3][3] = fmaf(wv.w, xv.w, acc[3][3]);
    }
  } else {
    // fallback: online softmax (deg unbounded)
    float m[4] = {-1e30f, -1e30f, -1e30f, -1e30f};
    float z[4] = {0.f, 0.f, 0.f, 0.f};
    float advv[4] = {adv.x, adv.y, adv.z, adv.w};
    for (int i = g; i < deg; i += G) {
      int s = colt[i];
      float4 a = *(const float4*)(asrc + (size_t)s * 16 + t * 4);
      float av[4] = {a.x, a.y, a.z, a.w};
#pragma unroll
      for (int h = 0; h < 4; h++) {
        float e = LRELU(av[h] + advv[h]);
        float nm = fmaxf(m[h], e);
        z[h] = z[h] * __expf(m[h] - nm) + __expf(e - nm);
        m[h] = nm;
      }
    }
#pragma unroll
    for (int st = GL; st < 64; st <<= 1)
#pragma unroll
      for (int h = 0; h < 4; h++) {
        float m2_ = __shfl_xor(m[h], st);
        float z2_ = __shfl_xor(z[h], st);
        float nm = fmaxf(m[h], m2_);
        z[h] = z[h] * __expf(m[h] - nm) + z2_ * __expf(m2_ - nm);
        m[h] = nm;
      }
#pragma unroll
    for (int h = 0; h < 4; h++) rz[h] = 1.f / z[h];
    for (int i = g; i < deg; i += G) {
      int s = colt[i];
      float4 a = *(const float4*)(asrc + (size_t)s * 16 + t * 4);
      float4 xv = *(const float4*)(x + (size_t)s * K + c4);
      float av[4] = {a.x, a.y, a.z, a.w};
#pragma unroll
      for (int h = 0; h < 4; h++) {
        float e = LRELU(av[h] + advv[h]);
        float ww = __expf(e - m[h]);
        acc[h][0] = fmaf(ww, xv.x, acc[h][0]);
        acc[h][1] = fmaf(ww, xv.y, acc[h][1]);
        acc[h][2] = fmaf(ww, xv.z, acc[h][2]);
        acc[h][3] = fmaf(ww, xv.w, acc[h][3]);
      }
    }
  }
#pragma unroll
  for (int st = GL; st < 64; st <<= 1)
#pragma unroll
    for (int h = 0; h < 4; h++) {
      acc[h][0] += __shfl_xor(acc[h][0], st);
      acc[h][1] += __shfl_xor(acc[h][1], st);
      acc[h][2] += __shfl_xor(acc[h][2], st);
      acc[h][3] += __shfl_xor(acc[h][3], st);
    }
  if (lane < GL) {
#pragma unroll
    for (int h = 0; h < 4; h++) {
      ushort4 o;
      o.x = bf16r(acc[h][0] * rz[h]);
      o.y = bf16r(acc[h][1] * rz[h]);
      o.z = bf16r(acc[h][2] * rz[h]);
      o.w = bf16r(acc[h][3] * rz[h]);
      *(ushort4*)(y + (size_t)v * (16 * K) + (size_t)(t * 4 + h) * K + c4) = o;
    }
  }
}

// ------- split-K output GEMM: part[ks] = y(bf16)[:, chunk] @ B[chunk, :] -------
template <int K>
__global__ __launch_bounds__(256) void k_out_s(const unsigned short* __restrict__ y,
                                               const float* __restrict__ W,
                                               float* __restrict__ part) {
  constexpr int KT = 16 * K;
  constexpr int CHUNK = KT / KSPLIT;
  __shared__ float As[32][65];
  __shared__ float Bs[32][68];
  int tid = threadIdx.x;
  int row0 = blockIdx.x * 64;
  int ks = blockIdx.y;
  int tx = tid & 15, ty = tid >> 4;
  int r_a = tid >> 2, k8 = (tid & 3) * 8;   // A staging: 64 rows x 32 k of bf16
  float acc[4][4] = {};
  for (int kb = ks * CHUNK; kb < (ks + 1) * CHUNK; kb += 32) {
    int tt = kb / (4 * K), hh = (kb / K) & 3, kk0 = kb % K;
    uint4 raw = make_uint4(0u, 0u, 0u, 0u);
    if (row0 + r_a < NN)
      raw = *(const uint4*)(y + (size_t)(row0 + r_a) * KT + kb + k8);
#pragma unroll
    for (int j = 0; j < 2; j++) {
      int idx = tid + j * 256;
      int kk = idx >> 4, cc4 = (idx & 15) * 4;
      *(float4*)&Bs[kk][cc4] =
          *(const float4*)(W + ((size_t)tt * K + kk0 + kk) * 256 + hh * 64 + cc4);
    }
    __syncthreads();
    As[k8 + 0][r_a] = bflo(raw.x); As[k8 + 1][r_a] = bfhi(raw.x);
    As[k8 + 2][r_a] = bflo(raw.y); As[k8 + 3][r_a] = bfhi(raw.y);
    As[k8 + 4][r_a] = bflo(raw.z); As[k8 + 5][r_a] = bfhi(raw.z);
    As[k8 + 6][r_a] = bflo(raw.w); As[k8 + 7][r_a] = bfhi(raw.w);
    __syncthreads();
#pragma unroll 4
    for (int kk = 0; kk < 32; kk++) {
      float4 a4 = *(const float4*)&As[kk][ty * 4];
      float4 b4 = *(const float4*)&Bs[kk][tx * 4];
      float aa[4] = {a4.x, a4.y, a4.z, a4.w};
      float bb[4] = {b4.x, b4.y, b4.z, b4.w};
#pragma unroll
      for (int i = 0; i < 4; i++)
#pragma unroll
        for (int j = 0; j < 4; j++) acc[i][j] = fmaf(aa[i], bb[j], acc[i][j]);
    }
    __syncthreads();
  }
#pragma unroll
  for (int i = 0; i < 4; i++) {
    int gr = row0 + ty * 4 + i;
    if (gr < NN)
      *(float4*)(part + (size_t)ks * NN * 64 + (size_t)gr * 64 + tx * 4) =
          make_float4(acc[i][0], acc[i][1], acc[i][2], acc[i][3]);
  }
}

// reduce KSPLIT partials: xout = relu(1/16*sum + bmean)   (layer 0)
__global__ void k_red(const float* __restrict__ part, const float* __restrict__ bm,
                      float* __restrict__ xout) {
  int i = blockIdx.x * blockDim.x + threadIdx.x;   // float4 index
  if (i >= NN * 16) return;
  float4 s = make_float4(0.f, 0.f, 0.f, 0.f);
#pragma unroll
  for (int ks = 0; ks < KSPLIT; ks++) {
    float4 p = *(const float4*)(part + (size_t)ks * NN * 64 + (size_t)i * 4);
    s.x += p.x; s.y += p.y; s.z += p.z; s.w += p.w;
  }
  float4 b = *(const float4*)(bm + ((i & 15) << 2));
  float4 o;
  o.x = fmaxf(0.0625f * s.x + b.x, 0.f);
  o.y = fmaxf(0.0625f * s.y + b.y, 0.f);
  o.z = fmaxf(0.0625f * s.z + b.z, 0.f);
  o.w = fmaxf(0.0625f * s.w + b.w, 0.f);
  *(float4*)(xout + (size_t)i * 4) = o;
}

// layer-1 reduce fused with final linear: out = relu(1/16*sum+bm) @ linW + linb
__global__ __launch_bounds__(256) void k_red_lin(
    const float* __restrict__ part, const float* __restrict__ bm,
    const float* __restrict__ linW, const float* __restrict__ linb,
    float* __restrict__ out) {
  __shared__ float xv[4][64];
  int n = threadIdx.x >> 6, c = threadIdx.x & 63;
  int v = blockIdx.x * 4 + n;
  float s = 0.f;
#pragma unroll
  for (int ks = 0; ks < KSPLIT; ks++)
    s += part[(size_t)ks * NN * 64 + (size_t)v * 64 + c];
  xv[n][c] = fmaxf(0.0625f * s + bm[c], 0.f);
  __syncthreads();
  if (c < 32) {
    float acc = linb[c];
#pragma unroll
    for (int cc = 0; cc < 64; cc++) acc = fmaf(xv[n][cc], linW[cc * 32 + c], acc);
    out[(size_t)v * 32 + c] = acc;
  }
}

extern "C" void kernel_launch(void* const* d_in, const int* in_sizes, int n_in,
                              void* d_out, int out_size, void* d_ws, size_t ws_size,
                              hipStream_t stream) {
  const float* x = (const float*)d_in[0];
  const int* e0 = (const int*)d_in[1];
  const int* e1 = (const int*)d_in[2];
  const int* e2 = (const int*)d_in[3];
  const int* e3 = (const int*)d_in[4];
  const float* W0 = (const float*)d_in[5];
  const float* as0 = (const float*)d_in[6];
  const float* ad0 = (const float*)d_in[7];
  const float* b0 = (const float*)d_in[8];
  const float* W1 = (const float*)d_in[9];
  const float* as1 = (const float*)d_in[10];
  const float* ad1 = (const float*)d_in[11];
  const float* b1 = (const float*)d_in[12];
  const float* linW = (const float*)d_in[13];
  const float* linb = (const float*)d_in[14];
  float* out = (float*)d_out;
  (void)in_sizes; (void)n_in; (void)out_size; (void)ws_size;

  char* wsb = (char*)d_ws;
  size_t off = 0;
  auto carve = [&](size_t bytes) -> char* {
    off = (off + 255) & ~(size_t)255;
    char* p = wsb + off;
    off += bytes;
    return p;
  };
  int* cnt     = (int*)carve((size_t)4 * NN * sizeof(int));
  int* tmp     = (int*)carve((size_t)4 * NN * sizeof(int));
  int* rp      = (int*)carve((size_t)4 * RP_STRIDE * sizeof(int));
  int* col     = (int*)carve((size_t)4 * EPN * sizeof(int));
  float* asrc  = (float*)carve((size_t)NN * 16 * sizeof(float));
  float* adst  = (float*)carve((size_t)NN * 16 * sizeof(float));
  float* PT0   = (float*)carve((size_t)32 * 128 * sizeof(float));
  float* PT1   = (float*)carve((size_t)32 * 64 * sizeof(float));
  float* bmean = (float*)carve((size_t)128 * sizeof(float));
  float* xmid  = (float*)carve((size_t)NN * 64 * sizeof(float));
  unsigned short* y = (unsigned short*)carve((size_t)NN * 2048 * sizeof(unsigned short));
  float* part  = (float*)carve((size_t)KSPLIT * NN * 64 * sizeof(float));

  // CSR build (proven R9 path)
  hipMemsetAsync(cnt, 0, (size_t)4 * NN * sizeof(int), stream);
  k_count<<<(4 * NE + 255) / 256, 256, 0, stream>>>(e0 + NE, e1 + NE, e2 + NE, e3 + NE, cnt);
  k_scan<<<4, 256, 0, stream>>>(cnt, rp, tmp);
  k_fill<<<(4 * EPN + 255) / 256, 256, 0, stream>>>(e0, e1, e2, e3, tmp, col);

  k_prep<<<25, 256, 0, stream>>>(W0, as0, ad0, b0, W1, as1, ad1, b1, PT0, PT1, bmean);

  // ---- layer 0 (K=128, KT=2048) ----
  k_coef<128><<<5000, 256, 0, stream>>>(x, PT0, asrc, adst);
  k_aggx3<128><<<NN, 256, 0, stream>>>(rp, col, asrc, adst, x, y);
  k_out_s<128><<<dim3(313, KSPLIT), 256, 0, stream>>>(y, W0, part);
  k_red<<<(NN * 16 + 255) / 256, 256, 0, stream>>>(part, bmean, xmid);

  // ---- layer 1 (K=64, KT=1024) ----
  k_coef<64><<<5000, 256, 0, stream>>>(xmid, PT1, asrc, adst);
  k_aggx3<64><<<NN, 256, 0, stream>>>(rp, col, asrc, adst, xmid, y);
  k_out_s<64><<<dim3(313, KSPLIT), 256, 0, stream>>>(y, W1, part);
  k_red_lin<<<NN / 4, 256, 0, stream>>>(part, bmean + 64, linW, linb, out);
}

// Round 13
// 485.242 us; speedup vs baseline: 1.2091x; 1.0257x over previous
//
#include <hip/hip_runtime.h>

#define NN 20000
#define NE 320000
#define EPN (NE + NN)   // edges + self loops = 340000
#define RP_STRIDE 20004
#define DCAP 96
#define KSPLIT 4

#define LRELU(e) ((e) > 0.f ? (e) : 0.2f * (e))

// round-to-nearest-even fp32 -> bf16
__device__ __forceinline__ unsigned short bf16r(float f) {
  union { float f; unsigned int u; } c;
  c.f = f;
  unsigned int r = (c.u + 0x7FFFu + ((c.u >> 16) & 1u)) >> 16;
  return (unsigned short)r;
}
__device__ __forceinline__ float bflo(unsigned int u) {
  return __uint_as_float(u << 16);
}
__device__ __forceinline__ float bfhi(unsigned int u) {
  return __uint_as_float(u & 0xFFFF0000u);
}
__device__ __forceinline__ float bfu(unsigned short u) {
  return __uint_as_float((unsigned int)u << 16);
}

// ---------------- fp32 -> bf16 array convert ----------------
__global__ void k_tobf16(const float4* __restrict__ in, ushort4* __restrict__ outp,
                         int n4) {
  int i = blockIdx.x * blockDim.x + threadIdx.x;
  if (i >= n4) return;
  float4 v = in[i];
  ushort4 o;
  o.x = bf16r(v.x); o.y = bf16r(v.y); o.z = bf16r(v.z); o.w = bf16r(v.w);
  outp[i] = o;
}

// ---------------- CSR build ----------------
__global__ void k_count(const int* __restrict__ d0, const int* __restrict__ d1,
                        const int* __restrict__ d2, const int* __restrict__ d3,
                        int* __restrict__ cnt) {
  int i = blockIdx.x * blockDim.x + threadIdx.x;
  if (i >= 4 * NE) return;
  int t = i / NE, e = i - t * NE;
  const int* d = t == 0 ? d0 : t == 1 ? d1 : t == 2 ? d2 : d3;
  atomicAdd(&cnt[t * NN + d[e]], 1);
}

// self-loop (+1 per node) folded into the scan
__global__ void k_scan(const int* __restrict__ cnt, int* __restrict__ rp, int* __restrict__ tmp) {
  int t = blockIdx.x;
  const int* c = cnt + t * NN;
  int* r = rp + t * RP_STRIDE;
  int* tm = tmp + t * NN;
  __shared__ int part[256];
  int tid = threadIdx.x;
  const int CH = (NN + 255) / 256;
  int lo = tid * CH, hi = min(lo + CH, NN);
  int s = 0;
  for (int i = lo; i < hi; i++) s += c[i] + 1;
  part[tid] = s;
  __syncthreads();
  if (tid == 0) {
    int run = 0;
    for (int i = 0; i < 256; i++) { int v = part[i]; part[i] = run; run += v; }
  }
  __syncthreads();
  int run = part[tid];
  for (int i = lo; i < hi; i++) { r[i] = run; tm[i] = run; run += c[i] + 1; }
  if (lo < NN && hi == NN) r[NN] = run;
}

// dst-partitioned fill: blockIdx.x = partition (consecutive ids -> distinct XCDs),
// so each partition's col range is written from one XCD's L2 (no line ping-pong).
#define FCHUNK 4096
__global__ __launch_bounds__(256) void k_fill(
    const int* __restrict__ e0, const int* __restrict__ e1,
    const int* __restrict__ e2, const int* __restrict__ e3,
    int* __restrict__ tmp, int* __restrict__ col) {
  int p = blockIdx.x;
  int dlo = p * (NN / 8), dhi = dlo + (NN / 8);
  int base = blockIdx.y * FCHUNK;
  for (int o = threadIdx.x; o < FCHUNK; o += 256) {
    int i = base + o;
    if (i >= 4 * EPN) return;
    int t = i / EPN, j = i - t * EPN;
    int s, d;
    if (j < NE) {
      const int* eb = t == 0 ? e0 : t == 1 ? e1 : t == 2 ? e2 : e3;
      d = eb[NE + j];
      if (d < dlo || d >= dhi) continue;
      s = eb[j];
    } else {
      s = d = j - NE;
      if (d < dlo || d >= dhi) continue;
    }
    int pos = atomicAdd(&tmp[t * NN + d], 1);
    col[(size_t)t * EPN + pos] = s;
  }
}

// ---------------- prep: PT[slot][k] = sum_c W[t][k][h*64+c]*a[t][h][c]; bmean ----
__global__ void k_prep(const float* __restrict__ W0, const float* __restrict__ as0,
                       const float* __restrict__ ad0, const float* __restrict__ b0,
                       const float* __restrict__ W1, const float* __restrict__ as1,
                       const float* __restrict__ ad1, const float* __restrict__ b1,
                       float* __restrict__ PT0, float* __restrict__ PT1,
                       float* __restrict__ bmean) {
  int i = blockIdx.x * blockDim.x + threadIdx.x;
  if (i < 4096) {
    int r = i >> 7, k = i & 127;
    int sd = r >> 4, t = (r >> 2) & 3, h = r & 3;
    const float* a = (sd ? ad0 : as0) + (t * 4 + h) * 64;
    const float* wr = W0 + ((size_t)t * 128 + k) * 256 + h * 64;
    float s = 0.f;
    for (int c = 0; c < 64; c++) s = fmaf(wr[c], a[c], s);
    PT0[r * 128 + k] = s;
  } else if (i < 6144) {
    int j = i - 4096;
    int r = j >> 6, k = j & 63;
    int sd = r >> 4, t = (r >> 2) & 3, h = r & 3;
    const float* a = (sd ? ad1 : as1) + (t * 4 + h) * 64;
    const float* wr = W1 + ((size_t)t * 64 + k) * 256 + h * 64;
    float s = 0.f;
    for (int c = 0; c < 64; c++) s = fmaf(wr[c], a[c], s);
    PT1[r * 64 + k] = s;
  } else if (i < 6272) {
    int j = i - 6144;
    int l = j >> 6, c = j & 63;
    const float* b = l ? b1 : b0;
    bmean[j] = 0.25f * (b[c] + b[64 + c] + b[128 + c] + b[192 + c]);
  }
}

// ---------------- coefficients: asrc/adst[v][16] = x[v] @ PT^T  (fp32 x) -------
template <int K>
__global__ __launch_bounds__(256) void k_coef(const float* __restrict__ xin,
                                              const float* __restrict__ PT,
                                              float* __restrict__ asrc,
                                              float* __restrict__ adst) {
  __shared__ float PTs[32][K + 4];
  __shared__ float Xs[4][K];
  int tid = threadIdx.x;
#pragma unroll
  for (int j = 0; j < (32 * K) / 1024; j++) {
    int f4 = tid + j * 256;
    int r = f4 / (K / 4), c4 = (f4 % (K / 4)) * 4;
    *(float4*)&PTs[r][c4] = *(const float4*)(PT + r * K + c4);
  }
  int w = tid >> 6, lane = tid & 63;
  int v = blockIdx.x * 4 + w;
  if (lane * 2 < K)
    *(float2*)&Xs[w][lane * 2] = *(const float2*)(xin + (size_t)v * K + lane * 2);
  __syncthreads();
  int s = lane & 31, h2 = lane >> 5;
  float acc = 0.f;
#pragma unroll
  for (int i = 0; i < K / 8; i++) {
    int k = h2 * (K / 2) + i * 4;
    float4 p = *(const float4*)&PTs[s][k];
    float4 xv = *(const float4*)&Xs[w][k];
    acc = fmaf(p.x, xv.x, fmaf(p.y, xv.y, fmaf(p.z, xv.z, fmaf(p.w, xv.w, acc))));
  }
  acc += __shfl_xor(acc, 32);
  if (lane < 16) asrc[(size_t)v * 16 + lane] = acc;
  else if (lane < 32) adst[(size_t)v * 16 + (lane - 16)] = acc;
}

// ------- x-space aggregation: block = 1 node, wave = 1 type; x gathered bf16 ---
template <int K>
__global__ __launch_bounds__(256) void k_aggx3(
    const int* __restrict__ rp, const int* __restrict__ col,
    const float* __restrict__ asrc, const float* __restrict__ adst,
    const unsigned short* __restrict__ xb, unsigned short* __restrict__ y) {
  constexpr int GL = K / 4;    // lanes per group (32 / 16)
  constexpr int G = 64 / GL;   // edge groups per wave (2 / 4)
  __shared__ float wl[4][DCAP * 4];
  __shared__ int scol[4][DCAP];
  int t = threadIdx.x >> 6, lane = threadIdx.x & 63;
  int v = blockIdx.x;
  int beg = rp[t * RP_STRIDE + v], deg = rp[t * RP_STRIDE + v + 1] - beg;
  const int* colt = col + (size_t)t * EPN + beg;
  float4 adv = *(const float4*)(adst + (size_t)v * 16 + t * 4);
  int g = lane / GL, c4 = (lane % GL) * 4;
  float acc[4][4] = {};
  float rz[4];

  if (deg <= DCAP) {
    float m0 = -1e30f, m1 = -1e30f, m2 = -1e30f, m3 = -1e30f;
    for (int i = lane; i < deg; i += 64) {
      int s = colt[i];
      scol[t][i] = s;
      float4 a = *(const float4*)(asrc + (size_t)s * 16 + t * 4);
      float e0 = LRELU(a.x + adv.x), e1 = LRELU(a.y + adv.y);
      float e2 = LRELU(a.z + adv.z), e3 = LRELU(a.w + adv.w);
      *(float4*)&wl[t][i * 4] = make_float4(e0, e1, e2, e3);
      m0 = fmaxf(m0, e0); m1 = fmaxf(m1, e1);
      m2 = fmaxf(m2, e2); m3 = fmaxf(m3, e3);
    }
#pragma unroll
    for (int st = 1; st < 64; st <<= 1) {
      m0 = fmaxf(m0, __shfl_xor(m0, st)); m1 = fmaxf(m1, __shfl_xor(m1, st));
      m2 = fmaxf(m2, __shfl_xor(m2, st)); m3 = fmaxf(m3, __shfl_xor(m3, st));
    }
    float z0 = 0.f, z1 = 0.f, z2 = 0.f, z3 = 0.f;
    for (int i = lane; i < deg; i += 64) {
      float4 e = *(const float4*)&wl[t][i * 4];
      e.x = __expf(e.x - m0); e.y = __expf(e.y - m1);
      e.z = __expf(e.z - m2); e.w = __expf(e.w - m3);
      *(float4*)&wl[t][i * 4] = e;
      z0 += e.x; z1 += e.y; z2 += e.z; z3 += e.w;
    }
#pragma unroll
    for (int st = 1; st < 64; st <<= 1) {
      z0 += __shfl_xor(z0, st); z1 += __shfl_xor(z1, st);
      z2 += __shfl_xor(z2, st); z3 += __shfl_xor(z3, st);
    }
    rz[0] = 1.f / z0; rz[1] = 1.f / z1; rz[2] = 1.f / z2; rz[3] = 1.f / z3;
    for (int i = g; i < deg; i += G) {
      float4 wv = *(const float4*)&wl[t][i * 4];
      ushort4 raw = *(const ushort4*)(xb + (size_t)scol[t][i] * K + c4);
      float4 xv = make_float4(bfu(raw.x), bfu(raw.y), bfu(raw.z), bfu(raw.w));
      acc[0][0] = fmaf(wv.x, xv.x, acc[0][0]); acc[0][1] = fmaf(wv.x, xv.y, acc[0][1]);
      acc[0][2] = fmaf(wv.x, xv.z, acc[0][2]); acc[0][3] = fmaf(wv.x, xv.w, acc[0][3]);
      acc[1][0] = fmaf(wv.y, xv.x, acc[1][0]); acc[1][1] = fmaf(wv.y, xv.y, acc[1][1]);
      acc[1][2] = fmaf(wv.y, xv.z, acc[1][2]); acc[1][3] = fmaf(wv.y, xv.w, acc[1][3]);
      acc[2][0] = fmaf(wv.z, xv.x, acc[2][0]); acc[2][1] = fmaf(wv.z, xv.y, acc[2][1]);
      acc[2][2] = fmaf(wv.z, xv.z, acc[2][2]); acc[2][3] = fmaf(wv.z, xv.w, acc[2][3]);
      acc[3][0] = fmaf(wv.w, xv.x, acc[3][0]); acc[3][1] = fmaf(wv.w, xv.y, acc[3][1]);
      acc[3][2] = fmaf(wv.w, xv.z, acc[3][2]); acc[3][3] = fmaf(wv.w, xv.w, acc[3][3]);
    }
  } else {
    // fallback: online softmax (deg unbounded)
    float m[4] = {-1e30f, -1e30f, -1e30f, -1e30f};
    float z[4] = {0.f, 0.f, 0.f, 0.f};
    float advv[4] = {adv.x, adv.y, adv.z, adv.w};
    for (int i = g; i < deg; i += G) {
      int s = colt[i];
      float4 a = *(const float4*)(asrc + (size_t)s * 16 + t * 4);
      float av[4] = {a.x, a.y, a.z, a.w};
#pragma unroll
      for (int h = 0; h < 4; h++) {
        float e = LRELU(av[h] + advv[h]);
        float nm = fmaxf(m[h], e);
        z[h] = z[h] * __expf(m[h] - nm) + __expf(e - nm);
        m[h] = nm;
      }
    }
#pragma unroll
    for (int st = GL; st < 64; st <<= 1)
#pragma unroll
      for (int h = 0; h < 4; h++) {
        float m2_ = __shfl_xor(m[h], st);
        float z2_ = __shfl_xor(z[h], st);
        float nm = fmaxf(m[h], m2_);
        z[h] = z[h] * __expf(m[h] - nm) + z2_ * __expf(m2_ - nm);
        m[h] = nm;
      }
#pragma unroll
    for (int h = 0; h < 4; h++) rz[h] = 1.f / z[h];
    for (int i = g; i < deg; i += G) {
      int s = colt[i];
      float4 a = *(const float4*)(asrc + (size_t)s * 16 + t * 4);
      ushort4 raw = *(const ushort4*)(xb + (size_t)s * K + c4);
      float4 xv = make_float4(bfu(raw.x), bfu(raw.y), bfu(raw.z), bfu(raw.w));
      float av[4] = {a.x, a.y, a.z, a.w};
#pragma unroll
      for (int h = 0; h < 4; h++) {
        float e = LRELU(av[h] + advv[h]);
        float ww = __expf(e - m[h]);
        acc[h][0] = fmaf(ww, xv.x, acc[h][0]);
        acc[h][1] = fmaf(ww, xv.y, acc[h][1]);
        acc[h][2] = fmaf(ww, xv.z, acc[h][2]);
        acc[h][3] = fmaf(ww, xv.w, acc[h][3]);
      }
    }
  }
#pragma unroll
  for (int st = GL; st < 64; st <<= 1)
#pragma unroll
    for (int h = 0; h < 4; h++) {
      acc[h][0] += __shfl_xor(acc[h][0], st);
      acc[h][1] += __shfl_xor(acc[h][1], st);
      acc[h][2] += __shfl_xor(acc[h][2], st);
      acc[h][3] += __shfl_xor(acc[h][3], st);
    }
  if (lane < GL) {
#pragma unroll
    for (int h = 0; h < 4; h++) {
      ushort4 o;
      o.x = bf16r(acc[h][0] * rz[h]);
      o.y = bf16r(acc[h][1] * rz[h]);
      o.z = bf16r(acc[h][2] * rz[h]);
      o.w = bf16r(acc[h][3] * rz[h]);
      *(ushort4*)(y + (size_t)v * (16 * K) + (size_t)(t * 4 + h) * K + c4) = o;
    }
  }
}

// ------- split-K output GEMM: part[ks] = y(bf16)[:, chunk] @ B[chunk, :] -------
template <int K>
__global__ __launch_bounds__(256) void k_out_s(const unsigned short* __restrict__ y,
                                               const float* __restrict__ W,
                                               float* __restrict__ part) {
  constexpr int KT = 16 * K;
  constexpr int CHUNK = KT / KSPLIT;
  __shared__ float As[32][65];
  __shared__ float Bs[32][68];
  int tid = threadIdx.x;
  int row0 = blockIdx.x * 64;
  int ks = blockIdx.y;
  int tx = tid & 15, ty = tid >> 4;
  int r_a = tid >> 2, k8 = (tid & 3) * 8;   // A staging: 64 rows x 32 k of bf16
  float acc[4][4] = {};
  for (int kb = ks * CHUNK; kb < (ks + 1) * CHUNK; kb += 32) {
    int tt = kb / (4 * K), hh = (kb / K) & 3, kk0 = kb % K;
    uint4 raw = make_uint4(0u, 0u, 0u, 0u);
    if (row0 + r_a < NN)
      raw = *(const uint4*)(y + (size_t)(row0 + r_a) * KT + kb + k8);
#pragma unroll
    for (int j = 0; j < 2; j++) {
      int idx = tid + j * 256;
      int kk = idx >> 4, cc4 = (idx & 15) * 4;
      *(float4*)&Bs[kk][cc4] =
          *(const float4*)(W + ((size_t)tt * K + kk0 + kk) * 256 + hh * 64 + cc4);
    }
    __syncthreads();
    As[k8 + 0][r_a] = bflo(raw.x); As[k8 + 1][r_a] = bfhi(raw.x);
    As[k8 + 2][r_a] = bflo(raw.y); As[k8 + 3][r_a] = bfhi(raw.y);
    As[k8 + 4][r_a] = bflo(raw.z); As[k8 + 5][r_a] = bfhi(raw.z);
    As[k8 + 6][r_a] = bflo(raw.w); As[k8 + 7][r_a] = bfhi(raw.w);
    __syncthreads();
#pragma unroll 4
    for (int kk = 0; kk < 32; kk++) {
      float4 a4 = *(const float4*)&As[kk][ty * 4];
      float4 b4 = *(const float4*)&Bs[kk][tx * 4];
      float aa[4] = {a4.x, a4.y, a4.z, a4.w};
      float bb[4] = {b4.x, b4.y, b4.z, b4.w};
#pragma unroll
      for (int i = 0; i < 4; i++)
#pragma unroll
        for (int j = 0; j < 4; j++) acc[i][j] = fmaf(aa[i], bb[j], acc[i][j]);
    }
    __syncthreads();
  }
#pragma unroll
  for (int i = 0; i < 4; i++) {
    int gr = row0 + ty * 4 + i;
    if (gr < NN)
      *(float4*)(part + (size_t)ks * NN * 64 + (size_t)gr * 64 + tx * 4) =
          make_float4(acc[i][0], acc[i][1], acc[i][2], acc[i][3]);
  }
}

// layer-0 reduce: xmid (fp32 for coef) + xmid16 (bf16 for gather)
__global__ void k_red(const float* __restrict__ part, const float* __restrict__ bm,
                      float* __restrict__ xout, unsigned short* __restrict__ xout16) {
  int i = blockIdx.x * blockDim.x + threadIdx.x;   // float4 index
  if (i >= NN * 16) return;
  float4 s = make_float4(0.f, 0.f, 0.f, 0.f);
#pragma unroll
  for (int ks = 0; ks < KSPLIT; ks++) {
    float4 p = *(const float4*)(part + (size_t)ks * NN * 64 + (size_t)i * 4);
    s.x += p.x; s.y += p.y; s.z += p.z; s.w += p.w;
  }
  float4 b = *(const float4*)(bm + ((i & 15) << 2));
  float4 o;
  o.x = fmaxf(0.0625f * s.x + b.x, 0.f);
  o.y = fmaxf(0.0625f * s.y + b.y, 0.f);
  o.z = fmaxf(0.0625f * s.z + b.z, 0.f);
  o.w = fmaxf(0.0625f * s.w + b.w, 0.f);
  *(float4*)(xout + (size_t)i * 4) = o;
  ushort4 q;
  q.x = bf16r(o.x); q.y = bf16r(o.y); q.z = bf16r(o.z); q.w = bf16r(o.w);
  *(ushort4*)(xout16 + (size_t)i * 4) = q;
}

// layer-1 reduce fused with final linear: out = relu(1/16*sum+bm) @ linW + linb
__global__ __launch_bounds__(256) void k_red_lin(
    const float* __restrict__ part, const float* __restrict__ bm,
    const float* __restrict__ linW, const float* __restrict__ linb,
    float* __restrict__ out) {
  __shared__ float xv[4][64];
  int n = threadIdx.x >> 6, c = threadIdx.x & 63;
  int v = blockIdx.x * 4 + n;
  float s = 0.f;
#pragma unroll
  for (int ks = 0; ks < KSPLIT; ks++)
    s += part[(size_t)ks * NN * 64 + (size_t)v * 64 + c];
  xv[n][c] = fmaxf(0.0625f * s + bm[c], 0.f);
  __syncthreads();
  if (c < 32) {
    float acc = linb[c];
#pragma unroll
    for (int cc = 0; cc < 64; cc++) acc = fmaf(xv[n][cc], linW[cc * 32 + c], acc);
    out[(size_t)v * 32 + c] = acc;
  }
}

extern "C" void kernel_launch(void* const* d_in, const int* in_sizes, int n_in,
                              void* d_out, int out_size, void* d_ws, size_t ws_size,
                              hipStream_t stream) {
  const float* x = (const float*)d_in[0];
  const int* e0 = (const int*)d_in[1];
  const int* e1 = (const int*)d_in[2];
  const int* e2 = (const int*)d_in[3];
  const int* e3 = (const int*)d_in[4];
  const float* W0 = (const float*)d_in[5];
  const float* as0 = (const float*)d_in[6];
  const float* ad0 = (const float*)d_in[7];
  const float* b0 = (const float*)d_in[8];
  const float* W1 = (const float*)d_in[9];
  const float* as1 = (const float*)d_in[10];
  const float* ad1 = (const float*)d_in[11];
  const float* b1 = (const float*)d_in[12];
  const float* linW = (const float*)d_in[13];
  const float* linb = (const float*)d_in[14];
  float* out = (float*)d_out;
  (void)in_sizes; (void)n_in; (void)out_size; (void)ws_size;

  char* wsb = (char*)d_ws;
  size_t off = 0;
  auto carve = [&](size_t bytes) -> char* {
    off = (off + 255) & ~(size_t)255;
    char* p = wsb + off;
    off += bytes;
    return p;
  };
  int* cnt     = (int*)carve((size_t)4 * NN * sizeof(int));
  int* tmp     = (int*)carve((size_t)4 * NN * sizeof(int));
  int* rp      = (int*)carve((size_t)4 * RP_STRIDE * sizeof(int));
  int* col     = (int*)carve((size_t)4 * EPN * sizeof(int));
  float* asrc  = (float*)carve((size_t)NN * 16 * sizeof(float));
  float* adst  = (float*)carve((size_t)NN * 16 * sizeof(float));
  float* PT0   = (float*)carve((size_t)32 * 128 * sizeof(float));
  float* PT1   = (float*)carve((size_t)32 * 64 * sizeof(float));
  float* bmean = (float*)carve((size_t)128 * sizeof(float));
  float* xmid  = (float*)carve((size_t)NN * 64 * sizeof(float));
  unsigned short* xb0 = (unsigned short*)carve((size_t)NN * 128 * sizeof(unsigned short));
  unsigned short* xb1 = (unsigned short*)carve((size_t)NN * 64 * sizeof(unsigned short));
  unsigned short* y = (unsigned short*)carve((size_t)NN * 2048 * sizeof(unsigned short));
  float* part  = (float*)carve((size_t)KSPLIT * NN * 64 * sizeof(float));

  // CSR build
  hipMemsetAsync(cnt, 0, (size_t)4 * NN * sizeof(int), stream);
  k_count<<<(4 * NE + 255) / 256, 256, 0, stream>>>(e0 + NE, e1 + NE, e2 + NE, e3 + NE, cnt);
  k_scan<<<4, 256, 0, stream>>>(cnt, rp, tmp);
  k_fill<<<dim3(8, (4 * EPN + FCHUNK - 1) / FCHUNK), 256, 0, stream>>>(
      e0, e1, e2, e3, tmp, col);

  k_prep<<<25, 256, 0, stream>>>(W0, as0, ad0, b0, W1, as1, ad1, b1, PT0, PT1, bmean);
  k_tobf16<<<(NN * 32 + 255) / 256, 256, 0, stream>>>(
      (const float4*)x, (ushort4*)xb0, NN * 32);

  // ---- layer 0 (K=128, KT=2048) ----
  k_coef<128><<<5000, 256, 0, stream>>>(x, PT0, asrc, adst);
  k_aggx3<128><<<NN, 256, 0, stream>>>(rp, col, asrc, adst, xb0, y);
  k_out_s<128><<<dim3(313, KSPLIT), 256, 0, stream>>>(y, W0, part);
  k_red<<<(NN * 16 + 255) / 256, 256, 0, stream>>>(part, bmean, xmid, xb1);

  // ---- layer 1 (K=64, KT=1024) ----
  k_coef<64><<<5000, 256, 0, stream>>>(xmid, PT1, asrc, adst);
  k_aggx3<64><<<NN, 256, 0, stream>>>(rp, col, asrc, adst, xb1, y);
  k_out_s<64><<<dim3(313, KSPLIT), 256, 0, stream>>>(y, W1, part);
  k_red_lin<<<NN / 4, 256, 0, stream>>>(part, bmean + 64, linW, linb, out);
}

// Round 14
// 443.378 us; speedup vs baseline: 1.3233x; 1.0944x over previous
//
#include <hip/hip_runtime.h>

#define NN 20000
#define NE 320000
#define EPN (NE + NN)   // edges + self loops = 340000
#define RP_STRIDE 20004
#define DCAP 96
#define KSPLIT 4

#define LRELU(e) ((e) > 0.f ? (e) : 0.2f * (e))

typedef __attribute__((ext_vector_type(8))) short bf16x8;
typedef __attribute__((ext_vector_type(4))) float f32x4;

// round-to-nearest-even fp32 -> bf16
__device__ __forceinline__ unsigned short bf16r(float f) {
  union { float f; unsigned int u; } c;
  c.f = f;
  unsigned int r = (c.u + 0x7FFFu + ((c.u >> 16) & 1u)) >> 16;
  return (unsigned short)r;
}
__device__ __forceinline__ float bflo(unsigned int u) {
  return __uint_as_float(u << 16);
}
__device__ __forceinline__ float bfhi(unsigned int u) {
  return __uint_as_float(u & 0xFFFF0000u);
}

__device__ __forceinline__ void accum16(float acc[4][4], const float4& wv, uint2 raw) {
  float x0 = bflo(raw.x), x1 = bfhi(raw.x);
  float x2 = bflo(raw.y), x3 = bfhi(raw.y);
  acc[0][0] = fmaf(wv.x, x0, acc[0][0]); acc[0][1] = fmaf(wv.x, x1, acc[0][1]);
  acc[0][2] = fmaf(wv.x, x2, acc[0][2]); acc[0][3] = fmaf(wv.x, x3, acc[0][3]);
  acc[1][0] = fmaf(wv.y, x0, acc[1][0]); acc[1][1] = fmaf(wv.y, x1, acc[1][1]);
  acc[1][2] = fmaf(wv.y, x2, acc[1][2]); acc[1][3] = fmaf(wv.y, x3, acc[1][3]);
  acc[2][0] = fmaf(wv.z, x0, acc[2][0]); acc[2][1] = fmaf(wv.z, x1, acc[2][1]);
  acc[2][2] = fmaf(wv.z, x2, acc[2][2]); acc[2][3] = fmaf(wv.z, x3, acc[2][3]);
  acc[3][0] = fmaf(wv.w, x0, acc[3][0]); acc[3][1] = fmaf(wv.w, x1, acc[3][1]);
  acc[3][2] = fmaf(wv.w, x2, acc[3][2]); acc[3][3] = fmaf(wv.w, x3, acc[3][3]);
}

// ---------------- fp32 -> bf16 array convert ----------------
__global__ void k_tobf16(const float4* __restrict__ in, ushort4* __restrict__ outp,
                         int n4) {
  int i = blockIdx.x * blockDim.x + threadIdx.x;
  if (i >= n4) return;
  float4 v = in[i];
  ushort4 o;
  o.x = bf16r(v.x); o.y = bf16r(v.y); o.z = bf16r(v.z); o.w = bf16r(v.w);
  outp[i] = o;
}

// ---------------- CSR build ----------------
__global__ void k_count(const int* __restrict__ d0, const int* __restrict__ d1,
                        const int* __restrict__ d2, const int* __restrict__ d3,
                        int* __restrict__ cnt) {
  int i = blockIdx.x * blockDim.x + threadIdx.x;
  if (i >= 4 * NE) return;
  int t = i / NE, e = i - t * NE;
  const int* d = t == 0 ? d0 : t == 1 ? d1 : t == 2 ? d2 : d3;
  atomicAdd(&cnt[t * NN + d[e]], 1);
}

// self-loop (+1 per node) folded into the scan
__global__ void k_scan(const int* __restrict__ cnt, int* __restrict__ rp, int* __restrict__ tmp) {
  int t = blockIdx.x;
  const int* c = cnt + t * NN;
  int* r = rp + t * RP_STRIDE;
  int* tm = tmp + t * NN;
  __shared__ int part[256];
  int tid = threadIdx.x;
  const int CH = (NN + 255) / 256;
  int lo = tid * CH, hi = min(lo + CH, NN);
  int s = 0;
  for (int i = lo; i < hi; i++) s += c[i] + 1;
  part[tid] = s;
  __syncthreads();
  if (tid == 0) {
    int run = 0;
    for (int i = 0; i < 256; i++) { int v = part[i]; part[i] = run; run += v; }
  }
  __syncthreads();
  int run = part[tid];
  for (int i = lo; i < hi; i++) { r[i] = run; tm[i] = run; run += c[i] + 1; }
  if (lo < NN && hi == NN) r[NN] = run;
}

// dst-partitioned fill
#define FCHUNK 4096
__global__ __launch_bounds__(256) void k_fill(
    const int* __restrict__ e0, const int* __restrict__ e1,
    const int* __restrict__ e2, const int* __restrict__ e3,
    int* __restrict__ tmp, int* __restrict__ col) {
  int p = blockIdx.x;
  int dlo = p * (NN / 8), dhi = dlo + (NN / 8);
  int base = blockIdx.y * FCHUNK;
  for (int o = threadIdx.x; o < FCHUNK; o += 256) {
    int i = base + o;
    if (i >= 4 * EPN) return;
    int t = i / EPN, j = i - t * EPN;
    int s, d;
    if (j < NE) {
      const int* eb = t == 0 ? e0 : t == 1 ? e1 : t == 2 ? e2 : e3;
      d = eb[NE + j];
      if (d < dlo || d >= dhi) continue;
      s = eb[j];
    } else {
      s = d = j - NE;
      if (d < dlo || d >= dhi) continue;
    }
    int pos = atomicAdd(&tmp[t * NN + d], 1);
    col[(size_t)t * EPN + pos] = s;
  }
}

// -------- prep: PT tables, bmean, and bf16-transposed weights WbT[64][KT] -----
__global__ void k_prep(const float* __restrict__ W0, const float* __restrict__ as0,
                       const float* __restrict__ ad0, const float* __restrict__ b0,
                       const float* __restrict__ W1, const float* __restrict__ as1,
                       const float* __restrict__ ad1, const float* __restrict__ b1,
                       float* __restrict__ PT0, float* __restrict__ PT1,
                       float* __restrict__ bmean,
                       unsigned short* __restrict__ WbT0,
                       unsigned short* __restrict__ WbT1) {
  int i = blockIdx.x * blockDim.x + threadIdx.x;
  if (i < 4096) {
    int r = i >> 7, k = i & 127;
    int sd = r >> 4, t = (r >> 2) & 3, h = r & 3;
    const float* a = (sd ? ad0 : as0) + (t * 4 + h) * 64;
    const float* wr = W0 + ((size_t)t * 128 + k) * 256 + h * 64;
    float s = 0.f;
    for (int c = 0; c < 64; c++) s = fmaf(wr[c], a[c], s);
    PT0[r * 128 + k] = s;
  } else if (i < 6144) {
    int j = i - 4096;
    int r = j >> 6, k = j & 63;
    int sd = r >> 4, t = (r >> 2) & 3, h = r & 3;
    const float* a = (sd ? ad1 : as1) + (t * 4 + h) * 64;
    const float* wr = W1 + ((size_t)t * 64 + k) * 256 + h * 64;
    float s = 0.f;
    for (int c = 0; c < 64; c++) s = fmaf(wr[c], a[c], s);
    PT1[r * 64 + k] = s;
  } else if (i < 6272) {
    int j = i - 6144;
    int l = j >> 6, c = j & 63;
    const float* b = l ? b1 : b0;
    bmean[j] = 0.25f * (b[c] + b[64 + c] + b[128 + c] + b[192 + c]);
  } else if (i < 6272 + 64 * 2048) {
    int j = i - 6272;
    int c = j >> 11, kt = j & 2047;            // kt = (t*4+h)*128 + k
    int t = kt >> 9, h = (kt >> 7) & 3, k = kt & 127;
    WbT0[(size_t)c * 2048 + kt] = bf16r(W0[((size_t)t * 128 + k) * 256 + h * 64 + c]);
  } else if (i < 6272 + 64 * 2048 + 64 * 1024) {
    int j = i - 6272 - 64 * 2048;
    int c = j >> 10, kt = j & 1023;            // kt = (t*4+h)*64 + k
    int t = kt >> 8, h = (kt >> 6) & 3, k = kt & 63;
    WbT1[(size_t)c * 1024 + kt] = bf16r(W1[((size_t)t * 64 + k) * 256 + h * 64 + c]);
  }
}

// ---------------- coefficients: asrc/adst[v][16] = x[v] @ PT^T  (fp32 x) -------
template <int K>
__global__ __launch_bounds__(256) void k_coef(const float* __restrict__ xin,
                                              const float* __restrict__ PT,
                                              float* __restrict__ asrc,
                                              float* __restrict__ adst) {
  __shared__ float PTs[32][K + 4];
  __shared__ float Xs[4][K];
  int tid = threadIdx.x;
#pragma unroll
  for (int j = 0; j < (32 * K) / 1024; j++) {
    int f4 = tid + j * 256;
    int r = f4 / (K / 4), c4 = (f4 % (K / 4)) * 4;
    *(float4*)&PTs[r][c4] = *(const float4*)(PT + r * K + c4);
  }
  int w = tid >> 6, lane = tid & 63;
  int v = blockIdx.x * 4 + w;
  if (lane * 2 < K)
    *(float2*)&Xs[w][lane * 2] = *(const float2*)(xin + (size_t)v * K + lane * 2);
  __syncthreads();
  int s = lane & 31, h2 = lane >> 5;
  float acc = 0.f;
#pragma unroll
  for (int i = 0; i < K / 8; i++) {
    int k = h2 * (K / 2) + i * 4;
    float4 p = *(const float4*)&PTs[s][k];
    float4 xv = *(const float4*)&Xs[w][k];
    acc = fmaf(p.x, xv.x, fmaf(p.y, xv.y, fmaf(p.z, xv.z, fmaf(p.w, xv.w, acc))));
  }
  acc += __shfl_xor(acc, 32);
  if (lane < 16) asrc[(size_t)v * 16 + lane] = acc;
  else if (lane < 32) adst[(size_t)v * 16 + (lane - 16)] = acc;
}

// ------- x-space aggregation: block = 1 node, wave = 1 type; x gathered bf16 ---
template <int K>
__global__ __launch_bounds__(256) void k_aggx3(
    const int* __restrict__ rp, const int* __restrict__ col,
    const float* __restrict__ asrc, const float* __restrict__ adst,
    const unsigned short* __restrict__ xb, unsigned short* __restrict__ y) {
  constexpr int GL = K / 4;    // lanes per group (32 / 16)
  constexpr int G = 64 / GL;   // edge groups per wave (2 / 4)
  __shared__ float wl[4][DCAP * 4];
  __shared__ int scol[4][DCAP];   // stores s*K (pre-multiplied)
  int t = threadIdx.x >> 6, lane = threadIdx.x & 63;
  int v = blockIdx.x;
  int beg = rp[t * RP_STRIDE + v], deg = rp[t * RP_STRIDE + v + 1] - beg;
  const int* colt = col + (size_t)t * EPN + beg;
  float4 adv = *(const float4*)(adst + (size_t)v * 16 + t * 4);
  int g = lane / GL, c4 = (lane % GL) * 4;
  float acc[4][4] = {};
  float rz[4];

  if (deg <= DCAP) {
    float m0 = -1e30f, m1 = -1e30f, m2 = -1e30f, m3 = -1e30f;
    for (int i = lane; i < deg; i += 64) {
      int s = colt[i];
      scol[t][i] = s * K;
      float4 a = *(const float4*)(asrc + (size_t)s * 16 + t * 4);
      float e0 = LRELU(a.x + adv.x), e1 = LRELU(a.y + adv.y);
      float e2 = LRELU(a.z + adv.z), e3 = LRELU(a.w + adv.w);
      *(float4*)&wl[t][i * 4] = make_float4(e0, e1, e2, e3);
      m0 = fmaxf(m0, e0); m1 = fmaxf(m1, e1);
      m2 = fmaxf(m2, e2); m3 = fmaxf(m3, e3);
    }
#pragma unroll
    for (int st = 1; st < 64; st <<= 1) {
      m0 = fmaxf(m0, __shfl_xor(m0, st)); m1 = fmaxf(m1, __shfl_xor(m1, st));
      m2 = fmaxf(m2, __shfl_xor(m2, st)); m3 = fmaxf(m3, __shfl_xor(m3, st));
    }
    float z0 = 0.f, z1 = 0.f, z2 = 0.f, z3 = 0.f;
    for (int i = lane; i < deg; i += 64) {
      float4 e = *(const float4*)&wl[t][i * 4];
      e.x = __expf(e.x - m0); e.y = __expf(e.y - m1);
      e.z = __expf(e.z - m2); e.w = __expf(e.w - m3);
      *(float4*)&wl[t][i * 4] = e;
      z0 += e.x; z1 += e.y; z2 += e.z; z3 += e.w;
    }
#pragma unroll
    for (int st = 1; st < 64; st <<= 1) {
      z0 += __shfl_xor(z0, st); z1 += __shfl_xor(z1, st);
      z2 += __shfl_xor(z2, st); z3 += __shfl_xor(z3, st);
    }
    rz[0] = 1.f / z0; rz[1] = 1.f / z1; rz[2] = 1.f / z2; rz[3] = 1.f / z3;
    const unsigned short* xc = xb + c4;
    int i = g;
    for (; i + G < deg; i += 2 * G) {
      float4 wv0 = *(const float4*)&wl[t][i * 4];
      float4 wv1 = *(const float4*)&wl[t][(i + G) * 4];
      uint2 r0 = *(const uint2*)(xc + scol[t][i]);
      uint2 r1 = *(const uint2*)(xc + scol[t][i + G]);
      accum16(acc, wv0, r0);
      accum16(acc, wv1, r1);
    }
    if (i < deg) {
      float4 wv0 = *(const float4*)&wl[t][i * 4];
      uint2 r0 = *(const uint2*)(xc + scol[t][i]);
      accum16(acc, wv0, r0);
    }
  } else {
    // fallback: online softmax (deg unbounded)
    float m[4] = {-1e30f, -1e30f, -1e30f, -1e30f};
    float z[4] = {0.f, 0.f, 0.f, 0.f};
    float advv[4] = {adv.x, adv.y, adv.z, adv.w};
    for (int i = g; i < deg; i += G) {
      int s = colt[i];
      float4 a = *(const float4*)(asrc + (size_t)s * 16 + t * 4);
      float av[4] = {a.x, a.y, a.z, a.w};
#pragma unroll
      for (int h = 0; h < 4; h++) {
        float e = LRELU(av[h] + advv[h]);
        float nm = fmaxf(m[h], e);
        z[h] = z[h] * __expf(m[h] - nm) + __expf(e - nm);
        m[h] = nm;
      }
    }
#pragma unroll
    for (int st = GL; st < 64; st <<= 1)
#pragma unroll
      for (int h = 0; h < 4; h++) {
        float m2_ = __shfl_xor(m[h], st);
        float z2_ = __shfl_xor(z[h], st);
        float nm = fmaxf(m[h], m2_);
        z[h] = z[h] * __expf(m[h] - nm) + z2_ * __expf(m2_ - nm);
        m[h] = nm;
      }
#pragma unroll
    for (int h = 0; h < 4; h++) rz[h] = 1.f / z[h];
    for (int i = g; i < deg; i += G) {
      int s = colt[i];
      float4 a = *(const float4*)(asrc + (size_t)s * 16 + t * 4);
      uint2 raw = *(const uint2*)(xb + (size_t)s * K + c4);
      float xv[4] = {bflo(raw.x), bfhi(raw.x), bflo(raw.y), bfhi(raw.y)};
      float av[4] = {a.x, a.y, a.z, a.w};
#pragma unroll
      for (int h = 0; h < 4; h++) {
        float e = LRELU(av[h] + advv[h]);
        float ww = __expf(e - m[h]);
        acc[h][0] = fmaf(ww, xv[0], acc[h][0]);
        acc[h][1] = fmaf(ww, xv[1], acc[h][1]);
        acc[h][2] = fmaf(ww, xv[2], acc[h][2]);
        acc[h][3] = fmaf(ww, xv[3], acc[h][3]);
      }
    }
  }
#pragma unroll
  for (int st = GL; st < 64; st <<= 1)
#pragma unroll
    for (int h = 0; h < 4; h++) {
      acc[h][0] += __shfl_xor(acc[h][0], st);
      acc[h][1] += __shfl_xor(acc[h][1], st);
      acc[h][2] += __shfl_xor(acc[h][2], st);
      acc[h][3] += __shfl_xor(acc[h][3], st);
    }
  if (lane < GL) {
#pragma unroll
    for (int h = 0; h < 4; h++) {
      ushort4 o;
      o.x = bf16r(acc[h][0] * rz[h]);
      o.y = bf16r(acc[h][1] * rz[h]);
      o.z = bf16r(acc[h][2] * rz[h]);
      o.w = bf16r(acc[h][3] * rz[h]);
      *(ushort4*)(y + (size_t)v * (16 * K) + (size_t)(t * 4 + h) * K + c4) = o;
    }
  }
}

// ---- MFMA split-K output GEMM: part[ks] = y(bf16) @ WbT(bf16)^T chunk ----
// A frag: lane l holds y[row0+w*16+(l&15)][kb+(l>>4)*8 .. +8]
// B frag: lane l holds WbT[f*16+(l&15)][kb+(l>>4)*8 .. +8]
// C/D:    col = l&15, row = (l>>4)*4 + j   [guide §3, m89-verified]
template <int K>
__global__ __launch_bounds__(256) void k_out_mfma(
    const unsigned short* __restrict__ y, const unsigned short* __restrict__ WbT,
    float* __restrict__ part) {
  constexpr int KT = 16 * K;
  constexpr int CHUNK = KT / KSPLIT;
  int w = threadIdx.x >> 6, l = threadIdx.x & 63;
  int row0 = blockIdx.x * 64 + w * 16;
  int ks = blockIdx.y;
  int lr = l & 15, kg = l >> 4;
  int arow = row0 + lr;
  bool rowok = arow < NN;
  const unsigned short* yb = y + (size_t)arow * KT + ks * CHUNK + kg * 8;
  const unsigned short* wb = WbT + (size_t)lr * KT + ks * CHUNK + kg * 8;
  f32x4 a0 = {0.f, 0.f, 0.f, 0.f}, a1 = a0, a2 = a0, a3 = a0;
  for (int kk = 0; kk < CHUNK; kk += 32) {
    bf16x8 av = {};
    if (rowok) av = *(const bf16x8*)(yb + kk);
    bf16x8 b0 = *(const bf16x8*)(wb + kk);
    bf16x8 b1 = *(const bf16x8*)(wb + 16 * KT + kk);
    bf16x8 b2 = *(const bf16x8*)(wb + 32 * KT + kk);
    bf16x8 b3 = *(const bf16x8*)(wb + 48 * KT + kk);
    a0 = __builtin_amdgcn_mfma_f32_16x16x32_bf16(av, b0, a0, 0, 0, 0);
    a1 = __builtin_amdgcn_mfma_f32_16x16x32_bf16(av, b1, a1, 0, 0, 0);
    a2 = __builtin_amdgcn_mfma_f32_16x16x32_bf16(av, b2, a2, 0, 0, 0);
    a3 = __builtin_amdgcn_mfma_f32_16x16x32_bf16(av, b3, a3, 0, 0, 0);
  }
  int orow = row0 + kg * 4;
  float* pb = part + (size_t)ks * NN * 64 + (size_t)orow * 64 + lr;
#pragma unroll
  for (int j = 0; j < 4; j++) {
    if (orow + j < NN) {
      pb[(size_t)j * 64 + 0]  = a0[j];
      pb[(size_t)j * 64 + 16] = a1[j];
      pb[(size_t)j * 64 + 32] = a2[j];
      pb[(size_t)j * 64 + 48] = a3[j];
    }
  }
}

// layer-0 reduce: xmid (fp32 for coef) + xmid16 (bf16 for gather)
__global__ void k_red(const float* __restrict__ part, const float* __restrict__ bm,
                      float* __restrict__ xout, unsigned short* __restrict__ xout16) {
  int i = blockIdx.x * blockDim.x + threadIdx.x;   // float4 index
  if (i >= NN * 16) return;
  float4 s = make_float4(0.f, 0.f, 0.f, 0.f);
#pragma unroll
  for (int ks = 0; ks < KSPLIT; ks++) {
    float4 p = *(const float4*)(part + (size_t)ks * NN * 64 + (size_t)i * 4);
    s.x += p.x; s.y += p.y; s.z += p.z; s.w += p.w;
  }
  float4 b = *(const float4*)(bm + ((i & 15) << 2));
  float4 o;
  o.x = fmaxf(0.0625f * s.x + b.x, 0.f);
  o.y = fmaxf(0.0625f * s.y + b.y, 0.f);
  o.z = fmaxf(0.0625f * s.z + b.z, 0.f);
  o.w = fmaxf(0.0625f * s.w + b.w, 0.f);
  *(float4*)(xout + (size_t)i * 4) = o;
  ushort4 q;
  q.x = bf16r(o.x); q.y = bf16r(o.y); q.z = bf16r(o.z); q.w = bf16r(o.w);
  *(ushort4*)(xout16 + (size_t)i * 4) = q;
}

// layer-1 reduce fused with final linear
__global__ __launch_bounds__(256) void k_red_lin(
    const float* __restrict__ part, const float* __restrict__ bm,
    const float* __restrict__ linW, const float* __restrict__ linb,
    float* __restrict__ out) {
  __shared__ float xv[4][64];
  int n = threadIdx.x >> 6, c = threadIdx.x & 63;
  int v = blockIdx.x * 4 + n;
  float s = 0.f;
#pragma unroll
  for (int ks = 0; ks < KSPLIT; ks++)
    s += part[(size_t)ks * NN * 64 + (size_t)v * 64 + c];
  xv[n][c] = fmaxf(0.0625f * s + bm[c], 0.f);
  __syncthreads();
  if (c < 32) {
    float acc = linb[c];
#pragma unroll
    for (int cc = 0; cc < 64; cc++) acc = fmaf(xv[n][cc], linW[cc * 32 + c], acc);
    out[(size_t)v * 32 + c] = acc;
  }
}

extern "C" void kernel_launch(void* const* d_in, const int* in_sizes, int n_in,
                              void* d_out, int out_size, void* d_ws, size_t ws_size,
                              hipStream_t stream) {
  const float* x = (const float*)d_in[0];
  const int* e0 = (const int*)d_in[1];
  const int* e1 = (const int*)d_in[2];
  const int* e2 = (const int*)d_in[3];
  const int* e3 = (const int*)d_in[4];
  const float* W0 = (const float*)d_in[5];
  const float* as0 = (const float*)d_in[6];
  const float* ad0 = (const float*)d_in[7];
  const float* b0 = (const float*)d_in[8];
  const float* W1 = (const float*)d_in[9];
  const float* as1 = (const float*)d_in[10];
  const float* ad1 = (const float*)d_in[11];
  const float* b1 = (const float*)d_in[12];
  const float* linW = (const float*)d_in[13];
  const float* linb = (const float*)d_in[14];
  float* out = (float*)d_out;
  (void)in_sizes; (void)n_in; (void)out_size; (void)ws_size;

  char* wsb = (char*)d_ws;
  size_t off = 0;
  auto carve = [&](size_t bytes) -> char* {
    off = (off + 255) & ~(size_t)255;
    char* p = wsb + off;
    off += bytes;
    return p;
  };
  int* cnt     = (int*)carve((size_t)4 * NN * sizeof(int));
  int* tmp     = (int*)carve((size_t)4 * NN * sizeof(int));
  int* rp      = (int*)carve((size_t)4 * RP_STRIDE * sizeof(int));
  int* col     = (int*)carve((size_t)4 * EPN * sizeof(int));
  float* asrc  = (float*)carve((size_t)NN * 16 * sizeof(float));
  float* adst  = (float*)carve((size_t)NN * 16 * sizeof(float));
  float* PT0   = (float*)carve((size_t)32 * 128 * sizeof(float));
  float* PT1   = (float*)carve((size_t)32 * 64 * sizeof(float));
  float* bmean = (float*)carve((size_t)128 * sizeof(float));
  unsigned short* WbT0 = (unsigned short*)carve((size_t)64 * 2048 * sizeof(unsigned short));
  unsigned short* WbT1 = (unsigned short*)carve((size_t)64 * 1024 * sizeof(unsigned short));
  float* xmid  = (float*)carve((size_t)NN * 64 * sizeof(float));
  unsigned short* xb0 = (unsigned short*)carve((size_t)NN * 128 * sizeof(unsigned short));
  unsigned short* xb1 = (unsigned short*)carve((size_t)NN * 64 * sizeof(unsigned short));
  unsigned short* y = (unsigned short*)carve((size_t)NN * 2048 * sizeof(unsigned short));
  float* part  = (float*)carve((size_t)KSPLIT * NN * 64 * sizeof(float));

  // CSR build
  hipMemsetAsync(cnt, 0, (size_t)4 * NN * sizeof(int), stream);
  k_count<<<(4 * NE + 255) / 256, 256, 0, stream>>>(e0 + NE, e1 + NE, e2 + NE, e3 + NE, cnt);
  k_scan<<<4, 256, 0, stream>>>(cnt, rp, tmp);
  k_fill<<<dim3(8, (4 * EPN + FCHUNK - 1) / FCHUNK), 256, 0, stream>>>(
      e0, e1, e2, e3, tmp, col);

  const int PREP_N = 6272 + 64 * 2048 + 64 * 1024;
  k_prep<<<(PREP_N + 255) / 256, 256, 0, stream>>>(
      W0, as0, ad0, b0, W1, as1, ad1, b1, PT0, PT1, bmean, WbT0, WbT1);
  k_tobf16<<<(NN * 32 + 255) / 256, 256, 0, stream>>>(
      (const float4*)x, (ushort4*)xb0, NN * 32);

  // ---- layer 0 (K=128, KT=2048) ----
  k_coef<128><<<5000, 256, 0, stream>>>(x, PT0, asrc, adst);
  k_aggx3<128><<<NN, 256, 0, stream>>>(rp, col, asrc, adst, xb0, y);
  k_out_mfma<128><<<dim3(313, KSPLIT), 256, 0, stream>>>(y, WbT0, part);
  k_red<<<(NN * 16 + 255) / 256, 256, 0, stream>>>(part, bmean, xmid, xb1);

  // ---- layer 1 (K=64, KT=1024) ----
  k_coef<64><<<5000, 256, 0, stream>>>(xmid, PT1, asrc, adst);
  k_aggx3<64><<<NN, 256, 0, stream>>>(rp, col, asrc, adst, xb1, y);
  k_out_mfma<64><<<dim3(313, KSPLIT), 256, 0, stream>>>(y, WbT1, part);
  k_red_lin<<<NN / 4, 256, 0, stream>>>(part, bmean + 64, linW, linb, out);
}

// Round 15
// 441.212 us; speedup vs baseline: 1.3298x; 1.0049x over previous
//
#include <hip/hip_runtime.h>

#define NN 20000
#define NE 320000
#define EPN (NE + NN)   // edges + self loops = 340000
#define RP_STRIDE 20004
#define DCAP 96
#define KSPLIT 4

#define LRELU(e) ((e) > 0.f ? (e) : 0.2f * (e))

typedef __attribute__((ext_vector_type(8))) short bf16x8;
typedef __attribute__((ext_vector_type(4))) float f32x4;
typedef __attribute__((ext_vector_type(2))) float f32x2;

// round-to-nearest-even fp32 -> bf16
__device__ __forceinline__ unsigned short bf16r(float f) {
  union { float f; unsigned int u; } c;
  c.f = f;
  unsigned int r = (c.u + 0x7FFFu + ((c.u >> 16) & 1u)) >> 16;
  return (unsigned short)r;
}
__device__ __forceinline__ float bflo(unsigned int u) {
  return __uint_as_float(u << 16);
}
__device__ __forceinline__ float bfhi(unsigned int u) {
  return __uint_as_float(u & 0xFFFF0000u);
}

// packed accumulate: acc[c][p] covers (head p*2, head p*2+1) at column c.
// wl float4 halves (x,y),(z,w) are register-adjacent -> v_pk_fma_f32 operands.
__device__ __forceinline__ void accumpk(f32x2 acc[4][2], const float4& wv, uint2 raw) {
  f32x2 wlo = {wv.x, wv.y};
  f32x2 whi = {wv.z, wv.w};
  float x0 = bflo(raw.x), x1 = bfhi(raw.x);
  float x2 = bflo(raw.y), x3 = bfhi(raw.y);
  f32x2 s0 = {x0, x0}, s1 = {x1, x1}, s2 = {x2, x2}, s3 = {x3, x3};
  acc[0][0] = __builtin_elementwise_fma(wlo, s0, acc[0][0]);
  acc[0][1] = __builtin_elementwise_fma(whi, s0, acc[0][1]);
  acc[1][0] = __builtin_elementwise_fma(wlo, s1, acc[1][0]);
  acc[1][1] = __builtin_elementwise_fma(whi, s1, acc[1][1]);
  acc[2][0] = __builtin_elementwise_fma(wlo, s2, acc[2][0]);
  acc[2][1] = __builtin_elementwise_fma(whi, s2, acc[2][1]);
  acc[3][0] = __builtin_elementwise_fma(wlo, s3, acc[3][0]);
  acc[3][1] = __builtin_elementwise_fma(whi, s3, acc[3][1]);
}

// ---------------- CSR build ----------------
__global__ void k_count(const int* __restrict__ d0, const int* __restrict__ d1,
                        const int* __restrict__ d2, const int* __restrict__ d3,
                        int* __restrict__ cnt) {
  int i = blockIdx.x * blockDim.x + threadIdx.x;
  if (i >= 4 * NE) return;
  int t = i / NE, e = i - t * NE;
  const int* d = t == 0 ? d0 : t == 1 ? d1 : t == 2 ? d2 : d3;
  atomicAdd(&cnt[t * NN + d[e]], 1);
}

// self-loop (+1 per node) folded into the scan
__global__ void k_scan(const int* __restrict__ cnt, int* __restrict__ rp, int* __restrict__ tmp) {
  int t = blockIdx.x;
  const int* c = cnt + t * NN;
  int* r = rp + t * RP_STRIDE;
  int* tm = tmp + t * NN;
  __shared__ int part[256];
  int tid = threadIdx.x;
  const int CH = (NN + 255) / 256;
  int lo = tid * CH, hi = min(lo + CH, NN);
  int s = 0;
  for (int i = lo; i < hi; i++) s += c[i] + 1;
  part[tid] = s;
  __syncthreads();
  if (tid == 0) {
    int run = 0;
    for (int i = 0; i < 256; i++) { int v = part[i]; part[i] = run; run += v; }
  }
  __syncthreads();
  int run = part[tid];
  for (int i = lo; i < hi; i++) { r[i] = run; tm[i] = run; run += c[i] + 1; }
  if (lo < NN && hi == NN) r[NN] = run;
}

// dst-partitioned fill
#define FCHUNK 4096
__global__ __launch_bounds__(256) void k_fill(
    const int* __restrict__ e0, const int* __restrict__ e1,
    const int* __restrict__ e2, const int* __restrict__ e3,
    int* __restrict__ tmp, int* __restrict__ col) {
  int p = blockIdx.x;
  int dlo = p * (NN / 8), dhi = dlo + (NN / 8);
  int base = blockIdx.y * FCHUNK;
  for (int o = threadIdx.x; o < FCHUNK; o += 256) {
    int i = base + o;
    if (i >= 4 * EPN) return;
    int t = i / EPN, j = i - t * EPN;
    int s, d;
    if (j < NE) {
      const int* eb = t == 0 ? e0 : t == 1 ? e1 : t == 2 ? e2 : e3;
      d = eb[NE + j];
      if (d < dlo || d >= dhi) continue;
      s = eb[j];
    } else {
      s = d = j - NE;
      if (d < dlo || d >= dhi) continue;
    }
    int pos = atomicAdd(&tmp[t * NN + d], 1);
    col[(size_t)t * EPN + pos] = s;
  }
}

// -------- prep: PT tables, bmean, bf16 W^T, and x->bf16 convert (fused) -------
__global__ void k_prep(const float* __restrict__ W0, const float* __restrict__ as0,
                       const float* __restrict__ ad0, const float* __restrict__ b0,
                       const float* __restrict__ W1, const float* __restrict__ as1,
                       const float* __restrict__ ad1, const float* __restrict__ b1,
                       float* __restrict__ PT0, float* __restrict__ PT1,
                       float* __restrict__ bmean,
                       unsigned short* __restrict__ WbT0,
                       unsigned short* __restrict__ WbT1,
                       const float4* __restrict__ xin, ushort4* __restrict__ xb0) {
  int i = blockIdx.x * blockDim.x + threadIdx.x;
  if (i < 4096) {
    int r = i >> 7, k = i & 127;
    int sd = r >> 4, t = (r >> 2) & 3, h = r & 3;
    const float* a = (sd ? ad0 : as0) + (t * 4 + h) * 64;
    const float* wr = W0 + ((size_t)t * 128 + k) * 256 + h * 64;
    float s = 0.f;
    for (int c = 0; c < 64; c++) s = fmaf(wr[c], a[c], s);
    PT0[r * 128 + k] = s;
  } else if (i < 6144) {
    int j = i - 4096;
    int r = j >> 6, k = j & 63;
    int sd = r >> 4, t = (r >> 2) & 3, h = r & 3;
    const float* a = (sd ? ad1 : as1) + (t * 4 + h) * 64;
    const float* wr = W1 + ((size_t)t * 64 + k) * 256 + h * 64;
    float s = 0.f;
    for (int c = 0; c < 64; c++) s = fmaf(wr[c], a[c], s);
    PT1[r * 64 + k] = s;
  } else if (i < 6272) {
    int j = i - 6144;
    int l = j >> 6, c = j & 63;
    const float* b = l ? b1 : b0;
    bmean[j] = 0.25f * (b[c] + b[64 + c] + b[128 + c] + b[192 + c]);
  } else if (i < 6272 + 64 * 2048) {
    int j = i - 6272;
    int c = j >> 11, kt = j & 2047;            // kt = (t*4+h)*128 + k
    int t = kt >> 9, h = (kt >> 7) & 3, k = kt & 127;
    WbT0[(size_t)c * 2048 + kt] = bf16r(W0[((size_t)t * 128 + k) * 256 + h * 64 + c]);
  } else if (i < 6272 + 64 * 2048 + 64 * 1024) {
    int j = i - 6272 - 64 * 2048;
    int c = j >> 10, kt = j & 1023;            // kt = (t*4+h)*64 + k
    int t = kt >> 8, h = (kt >> 6) & 3, k = kt & 63;
    WbT1[(size_t)c * 1024 + kt] = bf16r(W1[((size_t)t * 64 + k) * 256 + h * 64 + c]);
  } else if (i < 6272 + 64 * 2048 + 64 * 1024 + NN * 32) {
    int j = i - (6272 + 64 * 2048 + 64 * 1024);
    float4 v = xin[j];
    ushort4 o;
    o.x = bf16r(v.x); o.y = bf16r(v.y); o.z = bf16r(v.z); o.w = bf16r(v.w);
    xb0[j] = o;
  }
}

// ---------------- coefficients: asrc/adst[v][16] = x[v] @ PT^T  (fp32 x) -------
template <int K>
__global__ __launch_bounds__(256) void k_coef(const float* __restrict__ xin,
                                              const float* __restrict__ PT,
                                              float* __restrict__ asrc,
                                              float* __restrict__ adst) {
  __shared__ float PTs[32][K + 4];
  __shared__ float Xs[4][K];
  int tid = threadIdx.x;
#pragma unroll
  for (int j = 0; j < (32 * K) / 1024; j++) {
    int f4 = tid + j * 256;
    int r = f4 / (K / 4), c4 = (f4 % (K / 4)) * 4;
    *(float4*)&PTs[r][c4] = *(const float4*)(PT + r * K + c4);
  }
  int w = tid >> 6, lane = tid & 63;
  int v = blockIdx.x * 4 + w;
  if (lane * 2 < K)
    *(float2*)&Xs[w][lane * 2] = *(const float2*)(xin + (size_t)v * K + lane * 2);
  __syncthreads();
  int s = lane & 31, h2 = lane >> 5;
  float acc = 0.f;
#pragma unroll
  for (int i = 0; i < K / 8; i++) {
    int k = h2 * (K / 2) + i * 4;
    float4 p = *(const float4*)&PTs[s][k];
    float4 xv = *(const float4*)&Xs[w][k];
    acc = fmaf(p.x, xv.x, fmaf(p.y, xv.y, fmaf(p.z, xv.z, fmaf(p.w, xv.w, acc))));
  }
  acc += __shfl_xor(acc, 32);
  if (lane < 16) asrc[(size_t)v * 16 + lane] = acc;
  else if (lane < 32) adst[(size_t)v * 16 + (lane - 16)] = acc;
}

// ------- x-space aggregation: block = 1 node, wave = 1 type; x gathered bf16 ---
// pass2 uses packed f32 (v_pk_fma_f32) over head-pairs.
template <int K>
__global__ __launch_bounds__(256) void k_aggx3(
    const int* __restrict__ rp, const int* __restrict__ col,
    const float* __restrict__ asrc, const float* __restrict__ adst,
    const unsigned short* __restrict__ xb, unsigned short* __restrict__ y) {
  constexpr int GL = K / 4;    // lanes per group (32 / 16)
  constexpr int G = 64 / GL;   // edge groups per wave (2 / 4)
  __shared__ float wl[4][DCAP * 4];
  __shared__ int scol[4][DCAP];   // stores s*K (pre-multiplied)
  int t = threadIdx.x >> 6, lane = threadIdx.x & 63;
  int v = blockIdx.x;
  int beg = rp[t * RP_STRIDE + v], deg = rp[t * RP_STRIDE + v + 1] - beg;
  const int* colt = col + (size_t)t * EPN + beg;
  float4 adv = *(const float4*)(adst + (size_t)v * 16 + t * 4);
  int g = lane / GL, c4 = (lane % GL) * 4;
  f32x2 acc[4][2] = {};   // [col][head-pair]
  float rz[4];

  if (deg <= DCAP) {
    float m0 = -1e30f, m1 = -1e30f, m2 = -1e30f, m3 = -1e30f;
    for (int i = lane; i < deg; i += 64) {
      int s = colt[i];
      scol[t][i] = s * K;
      float4 a = *(const float4*)(asrc + (size_t)s * 16 + t * 4);
      float e0 = LRELU(a.x + adv.x), e1 = LRELU(a.y + adv.y);
      float e2 = LRELU(a.z + adv.z), e3 = LRELU(a.w + adv.w);
      *(float4*)&wl[t][i * 4] = make_float4(e0, e1, e2, e3);
      m0 = fmaxf(m0, e0); m1 = fmaxf(m1, e1);
      m2 = fmaxf(m2, e2); m3 = fmaxf(m3, e3);
    }
#pragma unroll
    for (int st = 1; st < 64; st <<= 1) {
      m0 = fmaxf(m0, __shfl_xor(m0, st)); m1 = fmaxf(m1, __shfl_xor(m1, st));
      m2 = fmaxf(m2, __shfl_xor(m2, st)); m3 = fmaxf(m3, __shfl_xor(m3, st));
    }
    float z0 = 0.f, z1 = 0.f, z2 = 0.f, z3 = 0.f;
    for (int i = lane; i < deg; i += 64) {
      float4 e = *(const float4*)&wl[t][i * 4];
      e.x = __expf(e.x - m0); e.y = __expf(e.y - m1);
      e.z = __expf(e.z - m2); e.w = __expf(e.w - m3);
      *(float4*)&wl[t][i * 4] = e;
      z0 += e.x; z1 += e.y; z2 += e.z; z3 += e.w;
    }
#pragma unroll
    for (int st = 1; st < 64; st <<= 1) {
      z0 += __shfl_xor(z0, st); z1 += __shfl_xor(z1, st);
      z2 += __shfl_xor(z2, st); z3 += __shfl_xor(z3, st);
    }
    rz[0] = 1.f / z0; rz[1] = 1.f / z1; rz[2] = 1.f / z2; rz[3] = 1.f / z3;
    const unsigned short* xc = xb + c4;
    int i = g;
    for (; i + G < deg; i += 2 * G) {
      float4 wv0 = *(const float4*)&wl[t][i * 4];
      float4 wv1 = *(const float4*)&wl[t][(i + G) * 4];
      uint2 r0 = *(const uint2*)(xc + scol[t][i]);
      uint2 r1 = *(const uint2*)(xc + scol[t][i + G]);
      accumpk(acc, wv0, r0);
      accumpk(acc, wv1, r1);
    }
    if (i < deg) {
      float4 wv0 = *(const float4*)&wl[t][i * 4];
      uint2 r0 = *(const uint2*)(xc + scol[t][i]);
      accumpk(acc, wv0, r0);
    }
  } else {
    // fallback: online softmax (deg unbounded)
    float m[4] = {-1e30f, -1e30f, -1e30f, -1e30f};
    float z[4] = {0.f, 0.f, 0.f, 0.f};
    float advv[4] = {adv.x, adv.y, adv.z, adv.w};
    for (int i = g; i < deg; i += G) {
      int s = colt[i];
      float4 a = *(const float4*)(asrc + (size_t)s * 16 + t * 4);
      float av[4] = {a.x, a.y, a.z, a.w};
#pragma unroll
      for (int h = 0; h < 4; h++) {
        float e = LRELU(av[h] + advv[h]);
        float nm = fmaxf(m[h], e);
        z[h] = z[h] * __expf(m[h] - nm) + __expf(e - nm);
        m[h] = nm;
      }
    }
#pragma unroll
    for (int st = GL; st < 64; st <<= 1)
#pragma unroll
      for (int h = 0; h < 4; h++) {
        float m2_ = __shfl_xor(m[h], st);
        float z2_ = __shfl_xor(z[h], st);
        float nm = fmaxf(m[h], m2_);
        z[h] = z[h] * __expf(m[h] - nm) + z2_ * __expf(m2_ - nm);
        m[h] = nm;
      }
#pragma unroll
    for (int h = 0; h < 4; h++) rz[h] = 1.f / z[h];
    for (int i = g; i < deg; i += G) {
      int s = colt[i];
      float4 a = *(const float4*)(asrc + (size_t)s * 16 + t * 4);
      uint2 raw = *(const uint2*)(xb + (size_t)s * K + c4);
      float av[4] = {a.x, a.y, a.z, a.w};
      float4 wv;
      wv.x = __expf(LRELU(av[0] + advv[0]) - m[0]);
      wv.y = __expf(LRELU(av[1] + advv[1]) - m[1]);
      wv.z = __expf(LRELU(av[2] + advv[2]) - m[2]);
      wv.w = __expf(LRELU(av[3] + advv[3]) - m[3]);
      accumpk(acc, wv, raw);
    }
  }
  // reduce across edge groups (16 scalar lanes)
#pragma unroll
  for (int st = GL; st < 64; st <<= 1)
#pragma unroll
    for (int c = 0; c < 4; c++)
#pragma unroll
      for (int p = 0; p < 2; p++) {
        acc[c][p].x += __shfl_xor(acc[c][p].x, st);
        acc[c][p].y += __shfl_xor(acc[c][p].y, st);
      }
  if (lane < GL) {
#pragma unroll
    for (int h = 0; h < 4; h++) {
      int p = h >> 1, j = h & 1;
      ushort4 o;
      o.x = bf16r((j ? acc[0][p].y : acc[0][p].x) * rz[h]);
      o.y = bf16r((j ? acc[1][p].y : acc[1][p].x) * rz[h]);
      o.z = bf16r((j ? acc[2][p].y : acc[2][p].x) * rz[h]);
      o.w = bf16r((j ? acc[3][p].y : acc[3][p].x) * rz[h]);
      *(ushort4*)(y + (size_t)v * (16 * K) + (size_t)(t * 4 + h) * K + c4) = o;
    }
  }
}

// ---- MFMA split-K output GEMM: part[ks] = y(bf16) @ WbT(bf16)^T chunk ----
template <int K>
__global__ __launch_bounds__(256) void k_out_mfma(
    const unsigned short* __restrict__ y, const unsigned short* __restrict__ WbT,
    float* __restrict__ part) {
  constexpr int KT = 16 * K;
  constexpr int CHUNK = KT / KSPLIT;
  int w = threadIdx.x >> 6, l = threadIdx.x & 63;
  int row0 = blockIdx.x * 64 + w * 16;
  int ks = blockIdx.y;
  int lr = l & 15, kg = l >> 4;
  int arow = row0 + lr;
  bool rowok = arow < NN;
  const unsigned short* yb = y + (size_t)arow * KT + ks * CHUNK + kg * 8;
  const unsigned short* wb = WbT + (size_t)lr * KT + ks * CHUNK + kg * 8;
  f32x4 a0 = {0.f, 0.f, 0.f, 0.f}, a1 = a0, a2 = a0, a3 = a0;
  for (int kk = 0; kk < CHUNK; kk += 32) {
    bf16x8 av = {};
    if (rowok) av = *(const bf16x8*)(yb + kk);
    bf16x8 b0 = *(const bf16x8*)(wb + kk);
    bf16x8 b1 = *(const bf16x8*)(wb + 16 * KT + kk);
    bf16x8 b2 = *(const bf16x8*)(wb + 32 * KT + kk);
    bf16x8 b3 = *(const bf16x8*)(wb + 48 * KT + kk);
    a0 = __builtin_amdgcn_mfma_f32_16x16x32_bf16(av, b0, a0, 0, 0, 0);
    a1 = __builtin_amdgcn_mfma_f32_16x16x32_bf16(av, b1, a1, 0, 0, 0);
    a2 = __builtin_amdgcn_mfma_f32_16x16x32_bf16(av, b2, a2, 0, 0, 0);
    a3 = __builtin_amdgcn_mfma_f32_16x16x32_bf16(av, b3, a3, 0, 0, 0);
  }
  int orow = row0 + kg * 4;
  float* pb = part + (size_t)ks * NN * 64 + (size_t)orow * 64 + lr;
#pragma unroll
  for (int j = 0; j < 4; j++) {
    if (orow + j < NN) {
      pb[(size_t)j * 64 + 0]  = a0[j];
      pb[(size_t)j * 64 + 16] = a1[j];
      pb[(size_t)j * 64 + 32] = a2[j];
      pb[(size_t)j * 64 + 48] = a3[j];
    }
  }
}

// layer-0 reduce: xmid (fp32 for coef) + xmid16 (bf16 for gather)
__global__ void k_red(const float* __restrict__ part, const float* __restrict__ bm,
                      float* __restrict__ xout, unsigned short* __restrict__ xout16) {
  int i = blockIdx.x * blockDim.x + threadIdx.x;   // float4 index
  if (i >= NN * 16) return;
  float4 s = make_float4(0.f, 0.f, 0.f, 0.f);
#pragma unroll
  for (int ks = 0; ks < KSPLIT; ks++) {
    float4 p = *(const float4*)(part + (size_t)ks * NN * 64 + (size_t)i * 4);
    s.x += p.x; s.y += p.y; s.z += p.z; s.w += p.w;
  }
  float4 b = *(const float4*)(bm + ((i & 15) << 2));
  float4 o;
  o.x = fmaxf(0.0625f * s.x + b.x, 0.f);
  o.y = fmaxf(0.0625f * s.y + b.y, 0.f);
  o.z = fmaxf(0.0625f * s.z + b.z, 0.f);
  o.w = fmaxf(0.0625f * s.w + b.w, 0.f);
  *(float4*)(xout + (size_t)i * 4) = o;
  ushort4 q;
  q.x = bf16r(o.x); q.y = bf16r(o.y); q.z = bf16r(o.z); q.w = bf16r(o.w);
  *(ushort4*)(xout16 + (size_t)i * 4) = q;
}

// layer-1 reduce fused with final linear
__global__ __launch_bounds__(256) void k_red_lin(
    const float* __restrict__ part, const float* __restrict__ bm,
    const float* __restrict__ linW, const float* __restrict__ linb,
    float* __restrict__ out) {
  __shared__ float xv[4][64];
  int n = threadIdx.x >> 6, c = threadIdx.x & 63;
  int v = blockIdx.x * 4 + n;
  float s = 0.f;
#pragma unroll
  for (int ks = 0; ks < KSPLIT; ks++)
    s += part[(size_t)ks * NN * 64 + (size_t)v * 64 + c];
  xv[n][c] = fmaxf(0.0625f * s + bm[c], 0.f);
  __syncthreads();
  if (c < 32) {
    float acc = linb[c];
#pragma unroll
    for (int cc = 0; cc < 64; cc++) acc = fmaf(xv[n][cc], linW[cc * 32 + c], acc);
    out[(size_t)v * 32 + c] = acc;
  }
}

extern "C" void kernel_launch(void* const* d_in, const int* in_sizes, int n_in,
                              void* d_out, int out_size, void* d_ws, size_t ws_size,
                              hipStream_t stream) {
  const float* x = (const float*)d_in[0];
  const int* e0 = (const int*)d_in[1];
  const int* e1 = (const int*)d_in[2];
  const int* e2 = (const int*)d_in[3];
  const int* e3 = (const int*)d_in[4];
  const float* W0 = (const float*)d_in[5];
  const float* as0 = (const float*)d_in[6];
  const float* ad0 = (const float*)d_in[7];
  const float* b0 = (const float*)d_in[8];
  const float* W1 = (const float*)d_in[9];
  const float* as1 = (const float*)d_in[10];
  const float* ad1 = (const float*)d_in[11];
  const float* b1 = (const float*)d_in[12];
  const float* linW = (const float*)d_in[13];
  const float* linb = (const float*)d_in[14];
  float* out = (float*)d_out;
  (void)in_sizes; (void)n_in; (void)out_size; (void)ws_size;

  char* wsb = (char*)d_ws;
  size_t off = 0;
  auto carve = [&](size_t bytes) -> char* {
    off = (off + 255) & ~(size_t)255;
    char* p = wsb + off;
    off += bytes;
    return p;
  };
  int* cnt     = (int*)carve((size_t)4 * NN * sizeof(int));
  int* tmp     = (int*)carve((size_t)4 * NN * sizeof(int));
  int* rp      = (int*)carve((size_t)4 * RP_STRIDE * sizeof(int));
  int* col     = (int*)carve((size_t)4 * EPN * sizeof(int));
  float* asrc  = (float*)carve((size_t)NN * 16 * sizeof(float));
  float* adst  = (float*)carve((size_t)NN * 16 * sizeof(float));
  float* PT0   = (float*)carve((size_t)32 * 128 * sizeof(float));
  float* PT1   = (float*)carve((size_t)32 * 64 * sizeof(float));
  float* bmean = (float*)carve((size_t)128 * sizeof(float));
  unsigned short* WbT0 = (unsigned short*)carve((size_t)64 * 2048 * sizeof(unsigned short));
  unsigned short* WbT1 = (unsigned short*)carve((size_t)64 * 1024 * sizeof(unsigned short));
  float* xmid  = (float*)carve((size_t)NN * 64 * sizeof(float));
  unsigned short* xb0 = (unsigned short*)carve((size_t)NN * 128 * sizeof(unsigned short));
  unsigned short* xb1 = (unsigned short*)carve((size_t)NN * 64 * sizeof(unsigned short));
  unsigned short* y = (unsigned short*)carve((size_t)NN * 2048 * sizeof(unsigned short));
  float* part  = (float*)carve((size_t)KSPLIT * NN * 64 * sizeof(float));

  // CSR build
  hipMemsetAsync(cnt, 0, (size_t)4 * NN * sizeof(int), stream);
  k_count<<<(4 * NE + 255) / 256, 256, 0, stream>>>(e0 + NE, e1 + NE, e2 + NE, e3 + NE, cnt);
  k_scan<<<4, 256, 0, stream>>>(cnt, rp, tmp);
  k_fill<<<dim3(8, (4 * EPN + FCHUNK - 1) / FCHUNK), 256, 0, stream>>>(
      e0, e1, e2, e3, tmp, col);

  const int PREP_N = 6272 + 64 * 2048 + 64 * 1024 + NN * 32;
  k_prep<<<(PREP_N + 255) / 256, 256, 0, stream>>>(
      W0, as0, ad0, b0, W1, as1, ad1, b1, PT0, PT1, bmean, WbT0, WbT1,
      (const float4*)x, (ushort4*)xb0);

  // ---- layer 0 (K=128, KT=2048) ----
  k_coef<128><<<5000, 256, 0, stream>>>(x, PT0, asrc, adst);
  k_aggx3<128><<<NN, 256, 0, stream>>>(rp, col, asrc, adst, xb0, y);
  k_out_mfma<128><<<dim3(313, KSPLIT), 256, 0, stream>>>(y, WbT0, part);
  k_red<<<(NN * 16 + 255) / 256, 256, 0, stream>>>(part, bmean, xmid, xb1);

  // ---- layer 1 (K=64, KT=1024) ----
  k_coef<64><<<5000, 256, 0, stream>>>(xmid, PT1, asrc, adst);
  k_aggx3<64><<<NN, 256, 0, stream>>>(rp, col, asrc, adst, xb1, y);
  k_out_mfma<64><<<dim3(313, KSPLIT), 256, 0, stream>>>(y, WbT1, part);
  k_red_lin<<<NN / 4, 256, 0, stream>>>(part, bmean + 64, linW, linb, out);
}

// Round 16
// 412.805 us; speedup vs baseline: 1.4213x; 1.0688x over previous
//
#include <hip/hip_runtime.h>

#define NN 20000
#define NE 320000
#define EPN (NE + NN)   // edges + self loops = 340000
#define RP_STRIDE 20004
#define DCAP 96
#define KSPLIT 4
#define NQ (NE / 4)

#define LRELU(e) ((e) > 0.f ? (e) : 0.2f * (e))

typedef __attribute__((ext_vector_type(8))) short bf16x8;
typedef __attribute__((ext_vector_type(4))) float f32x4;
typedef __attribute__((ext_vector_type(2))) float f32x2;

// round-to-nearest-even fp32 -> bf16
__device__ __forceinline__ unsigned short bf16r(float f) {
  union { float f; unsigned int u; } c;
  c.f = f;
  unsigned int r = (c.u + 0x7FFFu + ((c.u >> 16) & 1u)) >> 16;
  return (unsigned short)r;
}
__device__ __forceinline__ float bflo(unsigned int u) {
  return __uint_as_float(u << 16);
}
__device__ __forceinline__ float bfhi(unsigned int u) {
  return __uint_as_float(u & 0xFFFF0000u);
}

// packed accumulate: acc[c][p] covers (head p*2, head p*2+1) at column c.
__device__ __forceinline__ void accumpk(f32x2 acc[4][2], const float4& wv, uint2 raw) {
  f32x2 wlo = {wv.x, wv.y};
  f32x2 whi = {wv.z, wv.w};
  float x0 = bflo(raw.x), x1 = bfhi(raw.x);
  float x2 = bflo(raw.y), x3 = bfhi(raw.y);
  f32x2 s0 = {x0, x0}, s1 = {x1, x1}, s2 = {x2, x2}, s3 = {x3, x3};
  acc[0][0] = __builtin_elementwise_fma(wlo, s0, acc[0][0]);
  acc[0][1] = __builtin_elementwise_fma(whi, s0, acc[0][1]);
  acc[1][0] = __builtin_elementwise_fma(wlo, s1, acc[1][0]);
  acc[1][1] = __builtin_elementwise_fma(whi, s1, acc[1][1]);
  acc[2][0] = __builtin_elementwise_fma(wlo, s2, acc[2][0]);
  acc[2][1] = __builtin_elementwise_fma(whi, s2, acc[2][1]);
  acc[3][0] = __builtin_elementwise_fma(wlo, s3, acc[3][0]);
  acc[3][1] = __builtin_elementwise_fma(whi, s3, acc[3][1]);
}

// ---------------- CSR build ----------------
__global__ void k_count(const int4* __restrict__ d0, const int4* __restrict__ d1,
                        const int4* __restrict__ d2, const int4* __restrict__ d3,
                        int* __restrict__ cnt) {
  int i = blockIdx.x * blockDim.x + threadIdx.x;
  if (i >= 4 * NQ) return;
  int t = i / NQ, j = i - t * NQ;
  const int4* d = t == 0 ? d0 : t == 1 ? d1 : t == 2 ? d2 : d3;
  int4 v = d[j];
  int* c = cnt + t * NN;
  atomicAdd(&c[v.x], 1); atomicAdd(&c[v.y], 1);
  atomicAdd(&c[v.z], 1); atomicAdd(&c[v.w], 1);
}

// self-loop (+1 per node) folded into the scan
__global__ void k_scan(const int* __restrict__ cnt, int* __restrict__ rp, int* __restrict__ tmp) {
  int t = blockIdx.x;
  const int* c = cnt + t * NN;
  int* r = rp + t * RP_STRIDE;
  int* tm = tmp + t * NN;
  __shared__ int part[256];
  int tid = threadIdx.x;
  const int CH = (NN + 255) / 256;
  int lo = tid * CH, hi = min(lo + CH, NN);
  int s = 0;
  for (int i = lo; i < hi; i++) s += c[i] + 1;
  part[tid] = s;
  __syncthreads();
  if (tid == 0) {
    int run = 0;
    for (int i = 0; i < 256; i++) { int v = part[i]; part[i] = run; run += v; }
  }
  __syncthreads();
  int run = part[tid];
  for (int i = lo; i < hi; i++) { r[i] = run; tm[i] = run; run += c[i] + 1; }
  if (lo < NN && hi == NN) r[NN] = run;
}

// dst-partitioned fill
#define FCHUNK 4096
__global__ __launch_bounds__(256) void k_fill(
    const int* __restrict__ e0, const int* __restrict__ e1,
    const int* __restrict__ e2, const int* __restrict__ e3,
    int* __restrict__ tmp, int* __restrict__ col) {
  int p = blockIdx.x;
  int dlo = p * (NN / 8), dhi = dlo + (NN / 8);
  int base = blockIdx.y * FCHUNK;
  for (int o = threadIdx.x; o < FCHUNK; o += 256) {
    int i = base + o;
    if (i >= 4 * EPN) return;
    int t = i / EPN, j = i - t * EPN;
    int s, d;
    if (j < NE) {
      const int* eb = t == 0 ? e0 : t == 1 ? e1 : t == 2 ? e2 : e3;
      d = eb[NE + j];
      if (d < dlo || d >= dhi) continue;
      s = eb[j];
    } else {
      s = d = j - NE;
      if (d < dlo || d >= dhi) continue;
    }
    int pos = atomicAdd(&tmp[t * NN + d], 1);
    col[(size_t)t * EPN + pos] = s;
  }
}

// -------- prep: PT tables, bmean, bf16 W^T, and x->bf16 convert (fused) -------
__global__ void k_prep(const float* __restrict__ W0, const float* __restrict__ as0,
                       const float* __restrict__ ad0, const float* __restrict__ b0,
                       const float* __restrict__ W1, const float* __restrict__ as1,
                       const float* __restrict__ ad1, const float* __restrict__ b1,
                       float* __restrict__ PT0, float* __restrict__ PT1,
                       float* __restrict__ bmean,
                       unsigned short* __restrict__ WbT0,
                       unsigned short* __restrict__ WbT1,
                       const float4* __restrict__ xin, ushort4* __restrict__ xb0) {
  int i = blockIdx.x * blockDim.x + threadIdx.x;
  if (i < 4096) {
    int r = i >> 7, k = i & 127;
    int sd = r >> 4, t = (r >> 2) & 3, h = r & 3;
    const float* a = (sd ? ad0 : as0) + (t * 4 + h) * 64;
    const float* wr = W0 + ((size_t)t * 128 + k) * 256 + h * 64;
    float s = 0.f;
    for (int c = 0; c < 64; c++) s = fmaf(wr[c], a[c], s);
    PT0[r * 128 + k] = s;
  } else if (i < 6144) {
    int j = i - 4096;
    int r = j >> 6, k = j & 63;
    int sd = r >> 4, t = (r >> 2) & 3, h = r & 3;
    const float* a = (sd ? ad1 : as1) + (t * 4 + h) * 64;
    const float* wr = W1 + ((size_t)t * 64 + k) * 256 + h * 64;
    float s = 0.f;
    for (int c = 0; c < 64; c++) s = fmaf(wr[c], a[c], s);
    PT1[r * 64 + k] = s;
  } else if (i < 6272) {
    int j = i - 6144;
    int l = j >> 6, c = j & 63;
    const float* b = l ? b1 : b0;
    bmean[j] = 0.25f * (b[c] + b[64 + c] + b[128 + c] + b[192 + c]);
  } else if (i < 6272 + 64 * 2048) {
    int j = i - 6272;
    int c = j >> 11, kt = j & 2047;            // kt = (t*4+h)*128 + k
    int t = kt >> 9, h = (kt >> 7) & 3, k = kt & 127;
    WbT0[(size_t)c * 2048 + kt] = bf16r(W0[((size_t)t * 128 + k) * 256 + h * 64 + c]);
  } else if (i < 6272 + 64 * 2048 + 64 * 1024) {
    int j = i - 6272 - 64 * 2048;
    int c = j >> 10, kt = j & 1023;            // kt = (t*4+h)*64 + k
    int t = kt >> 8, h = (kt >> 6) & 3, k = kt & 63;
    WbT1[(size_t)c * 1024 + kt] = bf16r(W1[((size_t)t * 64 + k) * 256 + h * 64 + c]);
  } else if (i < 6272 + 64 * 2048 + 64 * 1024 + NN * 32) {
    int j = i - (6272 + 64 * 2048 + 64 * 1024);
    float4 v = xin[j];
    ushort4 o;
    o.x = bf16r(v.x); o.y = bf16r(v.y); o.z = bf16r(v.z); o.w = bf16r(v.w);
    xb0[j] = o;
  }
}

// ---------------- layer-0 coefficients: asrc/adst[v][16] = x[v] @ PT0^T -------
template <int K>
__global__ __launch_bounds__(256) void k_coef(const float* __restrict__ xin,
                                              const float* __restrict__ PT,
                                              float* __restrict__ asrc,
                                              float* __restrict__ adst) {
  __shared__ float PTs[32][K + 4];
  __shared__ float Xs[4][K];
  int tid = threadIdx.x;
#pragma unroll
  for (int j = 0; j < (32 * K) / 1024; j++) {
    int f4 = tid + j * 256;
    int r = f4 / (K / 4), c4 = (f4 % (K / 4)) * 4;
    *(float4*)&PTs[r][c4] = *(const float4*)(PT + r * K + c4);
  }
  int w = tid >> 6, lane = tid & 63;
  int v = blockIdx.x * 4 + w;
  if (lane * 2 < K)
    *(float2*)&Xs[w][lane * 2] = *(const float2*)(xin + (size_t)v * K + lane * 2);
  __syncthreads();
  int s = lane & 31, h2 = lane >> 5;
  float acc = 0.f;
#pragma unroll
  for (int i = 0; i < K / 8; i++) {
    int k = h2 * (K / 2) + i * 4;
    float4 p = *(const float4*)&PTs[s][k];
    float4 xv = *(const float4*)&Xs[w][k];
    acc = fmaf(p.x, xv.x, fmaf(p.y, xv.y, fmaf(p.z, xv.z, fmaf(p.w, xv.w, acc))));
  }
  acc += __shfl_xor(acc, 32);
  if (lane < 16) asrc[(size_t)v * 16 + lane] = acc;
  else if (lane < 32) adst[(size_t)v * 16 + (lane - 16)] = acc;
}

// ------- x-space aggregation v4: block = 1 node, wave = 1 type -------
// Pass1: (edge,head)-per-lane (16 edges x 4 heads = 64 lanes), NO max
// subtraction (|e| <~ 10, exp exact reassociation), 4-stage z-reduce.
// Pass2: packed-f32 gather as before.
template <int K>
__global__ __launch_bounds__(256) void k_aggx4(
    const int* __restrict__ rp, const int* __restrict__ col,
    const float* __restrict__ asrc, const float* __restrict__ adst,
    const unsigned short* __restrict__ xb, unsigned short* __restrict__ y) {
  constexpr int GL = K / 4;    // lanes per group (32 / 16)
  constexpr int G = 64 / GL;   // edge groups per wave (2 / 4)
  __shared__ float wl[4][DCAP * 4];
  __shared__ int scol[4][DCAP];   // stores s*K (pre-multiplied)
  __shared__ float zs[4][4];
  int t = threadIdx.x >> 6, lane = threadIdx.x & 63;
  int v = blockIdx.x;
  int beg = rp[t * RP_STRIDE + v], deg = rp[t * RP_STRIDE + v + 1] - beg;
  const int* colt = col + (size_t)t * EPN + beg;
  int g = lane / GL, c4 = (lane % GL) * 4;
  f32x2 acc[4][2] = {};   // [col][head-pair]
  float rz[4];

  if (deg <= DCAP) {
    int il = lane & 15, hq = lane >> 4;
    float advh = adst[(size_t)v * 16 + t * 4 + hq];
    float z = 0.f;
    for (int i = il; i < deg; i += 16) {
      int s = colt[i];
      if (hq == 0) scol[t][i] = s * K;
      float e = asrc[(size_t)s * 16 + t * 4 + hq] + advh;
      float w = __expf(LRELU(e));
      wl[t][i * 4 + hq] = w;
      z += w;
    }
    z += __shfl_xor(z, 1); z += __shfl_xor(z, 2);
    z += __shfl_xor(z, 4); z += __shfl_xor(z, 8);
    if (il == 0) zs[t][hq] = z;
    // pass 2: packed gather (wave-synchronous LDS, no barrier needed)
    const unsigned short* xc = xb + c4;
    int i = g;
    for (; i + G < deg; i += 2 * G) {
      float4 wv0 = *(const float4*)&wl[t][i * 4];
      float4 wv1 = *(const float4*)&wl[t][(i + G) * 4];
      uint2 r0 = *(const uint2*)(xc + scol[t][i]);
      uint2 r1 = *(const uint2*)(xc + scol[t][i + G]);
      accumpk(acc, wv0, r0);
      accumpk(acc, wv1, r1);
    }
    if (i < deg) {
      float4 wv0 = *(const float4*)&wl[t][i * 4];
      uint2 r0 = *(const uint2*)(xc + scol[t][i]);
      accumpk(acc, wv0, r0);
    }
#pragma unroll
    for (int h = 0; h < 4; h++) rz[h] = 1.f / zs[t][h];
  } else {
    // fallback: online softmax (deg unbounded; effectively never taken)
    float4 adv = *(const float4*)(adst + (size_t)v * 16 + t * 4);
    float m[4] = {-1e30f, -1e30f, -1e30f, -1e30f};
    float z[4] = {0.f, 0.f, 0.f, 0.f};
    float advv[4] = {adv.x, adv.y, adv.z, adv.w};
    for (int i = g; i < deg; i += G) {
      int s = colt[i];
      float4 a = *(const float4*)(asrc + (size_t)s * 16 + t * 4);
      float av[4] = {a.x, a.y, a.z, a.w};
#pragma unroll
      for (int h = 0; h < 4; h++) {
        float e = LRELU(av[h] + advv[h]);
        float nm = fmaxf(m[h], e);
        z[h] = z[h] * __expf(m[h] - nm) + __expf(e - nm);
        m[h] = nm;
      }
    }
#pragma unroll
    for (int st = GL; st < 64; st <<= 1)
#pragma unroll
      for (int h = 0; h < 4; h++) {
        float m2_ = __shfl_xor(m[h], st);
        float z2_ = __shfl_xor(z[h], st);
        float nm = fmaxf(m[h], m2_);
        z[h] = z[h] * __expf(m[h] - nm) + z2_ * __expf(m2_ - nm);
        m[h] = nm;
      }
#pragma unroll
    for (int h = 0; h < 4; h++) rz[h] = 1.f / z[h];
    for (int i = g; i < deg; i += G) {
      int s = colt[i];
      float4 a = *(const float4*)(asrc + (size_t)s * 16 + t * 4);
      uint2 raw = *(const uint2*)(xb + (size_t)s * K + c4);
      float av[4] = {a.x, a.y, a.z, a.w};
      float4 wv;
      wv.x = __expf(LRELU(av[0] + advv[0]) - m[0]);
      wv.y = __expf(LRELU(av[1] + advv[1]) - m[1]);
      wv.z = __expf(LRELU(av[2] + advv[2]) - m[2]);
      wv.w = __expf(LRELU(av[3] + advv[3]) - m[3]);
      accumpk(acc, wv, raw);
    }
  }
  // reduce across edge groups
#pragma unroll
  for (int st = GL; st < 64; st <<= 1)
#pragma unroll
    for (int c = 0; c < 4; c++)
#pragma unroll
      for (int p = 0; p < 2; p++) {
        acc[c][p].x += __shfl_xor(acc[c][p].x, st);
        acc[c][p].y += __shfl_xor(acc[c][p].y, st);
      }
  if (lane < GL) {
#pragma unroll
    for (int h = 0; h < 4; h++) {
      int p = h >> 1, j = h & 1;
      ushort4 o;
      o.x = bf16r((j ? acc[0][p].y : acc[0][p].x) * rz[h]);
      o.y = bf16r((j ? acc[1][p].y : acc[1][p].x) * rz[h]);
      o.z = bf16r((j ? acc[2][p].y : acc[2][p].x) * rz[h]);
      o.w = bf16r((j ? acc[3][p].y : acc[3][p].x) * rz[h]);
      *(ushort4*)(y + (size_t)v * (16 * K) + (size_t)(t * 4 + h) * K + c4) = o;
    }
  }
}

// ---- MFMA split-K output GEMM: part[ks] = y(bf16) @ WbT(bf16)^T chunk ----
template <int K>
__global__ __launch_bounds__(256) void k_out_mfma(
    const unsigned short* __restrict__ y, const unsigned short* __restrict__ WbT,
    float* __restrict__ part) {
  constexpr int KT = 16 * K;
  constexpr int CHUNK = KT / KSPLIT;
  int w = threadIdx.x >> 6, l = threadIdx.x & 63;
  int row0 = blockIdx.x * 64 + w * 16;
  int ks = blockIdx.y;
  int lr = l & 15, kg = l >> 4;
  int arow = row0 + lr;
  bool rowok = arow < NN;
  const unsigned short* yb = y + (size_t)arow * KT + ks * CHUNK + kg * 8;
  const unsigned short* wb = WbT + (size_t)lr * KT + ks * CHUNK + kg * 8;
  f32x4 a0 = {0.f, 0.f, 0.f, 0.f}, a1 = a0, a2 = a0, a3 = a0;
  for (int kk = 0; kk < CHUNK; kk += 32) {
    bf16x8 av = {};
    if (rowok) av = *(const bf16x8*)(yb + kk);
    bf16x8 b0 = *(const bf16x8*)(wb + kk);
    bf16x8 b1 = *(const bf16x8*)(wb + 16 * KT + kk);
    bf16x8 b2 = *(const bf16x8*)(wb + 32 * KT + kk);
    bf16x8 b3 = *(const bf16x8*)(wb + 48 * KT + kk);
    a0 = __builtin_amdgcn_mfma_f32_16x16x32_bf16(av, b0, a0, 0, 0, 0);
    a1 = __builtin_amdgcn_mfma_f32_16x16x32_bf16(av, b1, a1, 0, 0, 0);
    a2 = __builtin_amdgcn_mfma_f32_16x16x32_bf16(av, b2, a2, 0, 0, 0);
    a3 = __builtin_amdgcn_mfma_f32_16x16x32_bf16(av, b3, a3, 0, 0, 0);
  }
  int orow = row0 + kg * 4;
  float* pb = part + (size_t)ks * NN * 64 + (size_t)orow * 64 + lr;
#pragma unroll
  for (int j = 0; j < 4; j++) {
    if (orow + j < NN) {
      pb[(size_t)j * 64 + 0]  = a0[j];
      pb[(size_t)j * 64 + 16] = a1[j];
      pb[(size_t)j * 64 + 32] = a2[j];
      pb[(size_t)j * 64 + 48] = a3[j];
    }
  }
}

// ---- layer-0 reduce FUSED with layer-1 coefficients ----
// block = 4 nodes; computes xmid in LDS, writes xb1 (bf16) + asrc/adst.
__global__ __launch_bounds__(256) void k_red_coef(
    const float* __restrict__ part, const float* __restrict__ bm,
    const float* __restrict__ PT1, unsigned short* __restrict__ xb1,
    float* __restrict__ asrc, float* __restrict__ adst) {
  __shared__ float xv[4][64];
  __shared__ float PTs[32][65];
  int tid = threadIdx.x;
  for (int j = tid; j < 2048; j += 256) PTs[j >> 6][j & 63] = PT1[j];
  int n = tid >> 6, c = tid & 63;
  int v = blockIdx.x * 4 + n;
  float s = 0.f;
#pragma unroll
  for (int ks = 0; ks < KSPLIT; ks++)
    s += part[(size_t)ks * NN * 64 + (size_t)v * 64 + c];
  float xval = fmaxf(0.0625f * s + bm[c], 0.f);
  xv[n][c] = xval;
  xb1[(size_t)v * 64 + c] = bf16r(xval);
  __syncthreads();
  int row = c & 31, half = c >> 5;
  const float* xr = xv[n] + half * 32;
  const float* pr = &PTs[row][half * 32];
  float dot = 0.f;
#pragma unroll 8
  for (int j = 0; j < 32; j++) dot = fmaf(pr[j], xr[j], dot);
  dot += __shfl_xor(dot, 32);
  if (half == 0) {
    if (row < 16) asrc[(size_t)v * 16 + row] = dot;
    else adst[(size_t)v * 16 + (row - 16)] = dot;
  }
}

// layer-1 reduce fused with final linear
__global__ __launch_bounds__(256) void k_red_lin(
    const float* __restrict__ part, const float* __restrict__ bm,
    const float* __restrict__ linW, const float* __restrict__ linb,
    float* __restrict__ out) {
  __shared__ float xv[4][64];
  int n = threadIdx.x >> 6, c = threadIdx.x & 63;
  int v = blockIdx.x * 4 + n;
  float s = 0.f;
#pragma unroll
  for (int ks = 0; ks < KSPLIT; ks++)
    s += part[(size_t)ks * NN * 64 + (size_t)v * 64 + c];
  xv[n][c] = fmaxf(0.0625f * s + bm[c], 0.f);
  __syncthreads();
  if (c < 32) {
    float acc = linb[c];
#pragma unroll
    for (int cc = 0; cc < 64; cc++) acc = fmaf(xv[n][cc], linW[cc * 32 + c], acc);
    out[(size_t)v * 32 + c] = acc;
  }
}

extern "C" void kernel_launch(void* const* d_in, const int* in_sizes, int n_in,
                              void* d_out, int out_size, void* d_ws, size_t ws_size,
                              hipStream_t stream) {
  const float* x = (const float*)d_in[0];
  const int* e0 = (const int*)d_in[1];
  const int* e1 = (const int*)d_in[2];
  const int* e2 = (const int*)d_in[3];
  const int* e3 = (const int*)d_in[4];
  const float* W0 = (const float*)d_in[5];
  const float* as0 = (const float*)d_in[6];
  const float* ad0 = (const float*)d_in[7];
  const float* b0 = (const float*)d_in[8];
  const float* W1 = (const float*)d_in[9];
  const float* as1 = (const float*)d_in[10];
  const float* ad1 = (const float*)d_in[11];
  const float* b1 = (const float*)d_in[12];
  const float* linW = (const float*)d_in[13];
  const float* linb = (const float*)d_in[14];
  float* out = (float*)d_out;
  (void)in_sizes; (void)n_in; (void)out_size; (void)ws_size;

  char* wsb = (char*)d_ws;
  size_t off = 0;
  auto carve = [&](size_t bytes) -> char* {
    off = (off + 255) & ~(size_t)255;
    char* p = wsb + off;
    off += bytes;
    return p;
  };
  int* cnt     = (int*)carve((size_t)4 * NN * sizeof(int));
  int* tmp     = (int*)carve((size_t)4 * NN * sizeof(int));
  int* rp      = (int*)carve((size_t)4 * RP_STRIDE * sizeof(int));
  int* col     = (int*)carve((size_t)4 * EPN * sizeof(int));
  float* asrc  = (float*)carve((size_t)NN * 16 * sizeof(float));
  float* adst  = (float*)carve((size_t)NN * 16 * sizeof(float));
  float* PT0   = (float*)carve((size_t)32 * 128 * sizeof(float));
  float* PT1   = (float*)carve((size_t)32 * 64 * sizeof(float));
  float* bmean = (float*)carve((size_t)128 * sizeof(float));
  unsigned short* WbT0 = (unsigned short*)carve((size_t)64 * 2048 * sizeof(unsigned short));
  unsigned short* WbT1 = (unsigned short*)carve((size_t)64 * 1024 * sizeof(unsigned short));
  unsigned short* xb0 = (unsigned short*)carve((size_t)NN * 128 * sizeof(unsigned short));
  unsigned short* xb1 = (unsigned short*)carve((size_t)NN * 64 * sizeof(unsigned short));
  unsigned short* y = (unsigned short*)carve((size_t)NN * 2048 * sizeof(unsigned short));
  float* part  = (float*)carve((size_t)KSPLIT * NN * 64 * sizeof(float));

  // CSR build
  hipMemsetAsync(cnt, 0, (size_t)4 * NN * sizeof(int), stream);
  k_count<<<(4 * NQ + 255) / 256, 256, 0, stream>>>(
      (const int4*)(e0 + NE), (const int4*)(e1 + NE),
      (const int4*)(e2 + NE), (const int4*)(e3 + NE), cnt);
  k_scan<<<4, 256, 0, stream>>>(cnt, rp, tmp);
  k_fill<<<dim3(8, (4 * EPN + FCHUNK - 1) / FCHUNK), 256, 0, stream>>>(
      e0, e1, e2, e3, tmp, col);

  const int PREP_N = 6272 + 64 * 2048 + 64 * 1024 + NN * 32;
  k_prep<<<(PREP_N + 255) / 256, 256, 0, stream>>>(
      W0, as0, ad0, b0, W1, as1, ad1, b1, PT0, PT1, bmean, WbT0, WbT1,
      (const float4*)x, (ushort4*)xb0);

  // ---- layer 0 (K=128, KT=2048) ----
  k_coef<128><<<5000, 256, 0, stream>>>(x, PT0, asrc, adst);
  k_aggx4<128><<<NN, 256, 0, stream>>>(rp, col, asrc, adst, xb0, y);
  k_out_mfma<128><<<dim3(313, KSPLIT), 256, 0, stream>>>(y, WbT0, part);
  k_red_coef<<<NN / 4, 256, 0, stream>>>(part, bmean, PT1, xb1, asrc, adst);

  // ---- layer 1 (K=64, KT=1024) ----
  k_aggx4<64><<<NN, 256, 0, stream>>>(rp, col, asrc, adst, xb1, y);
  k_out_mfma<64><<<dim3(313, KSPLIT), 256, 0, stream>>>(y, WbT1, part);
  k_red_lin<<<NN / 4, 256, 0, stream>>>(part, bmean + 64, linW, linb, out);
}

// Round 17
// 385.739 us; speedup vs baseline: 1.5210x; 1.0702x over previous
//
#include <hip/hip_runtime.h>

#define NN 20000
#define NE 320000
#define EPN (NE + NN)   // edges + self loops = 340000
#define RP_STRIDE 20004
#define DCAP 64
#define KSPLIT 4
#define NQ (NE / 4)

#define LRELU(e) ((e) > 0.f ? (e) : 0.2f * (e))

typedef __attribute__((ext_vector_type(8))) short bf16x8;
typedef __attribute__((ext_vector_type(4))) float f32x4;
typedef __attribute__((ext_vector_type(2))) float f32x2;

// round-to-nearest-even fp32 -> bf16
__device__ __forceinline__ unsigned short bf16r(float f) {
  union { float f; unsigned int u; } c;
  c.f = f;
  unsigned int r = (c.u + 0x7FFFu + ((c.u >> 16) & 1u)) >> 16;
  return (unsigned short)r;
}
__device__ __forceinline__ float bflo(unsigned int u) {
  return __uint_as_float(u << 16);
}
__device__ __forceinline__ float bfhi(unsigned int u) {
  return __uint_as_float(u & 0xFFFF0000u);
}

// packed accumulate: acc[c][p] covers (head p*2, head p*2+1) at column c.
__device__ __forceinline__ void accumpk(f32x2 acc[4][2], const float4& wv, uint2 raw) {
  f32x2 wlo = {wv.x, wv.y};
  f32x2 whi = {wv.z, wv.w};
  float x0 = bflo(raw.x), x1 = bfhi(raw.x);
  float x2 = bflo(raw.y), x3 = bfhi(raw.y);
  f32x2 s0 = {x0, x0}, s1 = {x1, x1}, s2 = {x2, x2}, s3 = {x3, x3};
  acc[0][0] = __builtin_elementwise_fma(wlo, s0, acc[0][0]);
  acc[0][1] = __builtin_elementwise_fma(whi, s0, acc[0][1]);
  acc[1][0] = __builtin_elementwise_fma(wlo, s1, acc[1][0]);
  acc[1][1] = __builtin_elementwise_fma(whi, s1, acc[1][1]);
  acc[2][0] = __builtin_elementwise_fma(wlo, s2, acc[2][0]);
  acc[2][1] = __builtin_elementwise_fma(whi, s2, acc[2][1]);
  acc[3][0] = __builtin_elementwise_fma(wlo, s3, acc[3][0]);
  acc[3][1] = __builtin_elementwise_fma(whi, s3, acc[3][1]);
}

// ---------------- CSR build ----------------
__global__ void k_count(const int4* __restrict__ d0, const int4* __restrict__ d1,
                        const int4* __restrict__ d2, const int4* __restrict__ d3,
                        int* __restrict__ cnt) {
  int i = blockIdx.x * blockDim.x + threadIdx.x;
  if (i >= 4 * NQ) return;
  int t = i / NQ, j = i - t * NQ;
  const int4* d = t == 0 ? d0 : t == 1 ? d1 : t == 2 ? d2 : d3;
  int4 v = d[j];
  int* c = cnt + t * NN;
  atomicAdd(&c[v.x], 1); atomicAdd(&c[v.y], 1);
  atomicAdd(&c[v.z], 1); atomicAdd(&c[v.w], 1);
}

// self-loop (+1 per node) folded into the scan
__global__ void k_scan(const int* __restrict__ cnt, int* __restrict__ rp, int* __restrict__ tmp) {
  int t = blockIdx.x;
  const int* c = cnt + t * NN;
  int* r = rp + t * RP_STRIDE;
  int* tm = tmp + t * NN;
  __shared__ int part[256];
  int tid = threadIdx.x;
  const int CH = (NN + 255) / 256;
  int lo = tid * CH, hi = min(lo + CH, NN);
  int s = 0;
  for (int i = lo; i < hi; i++) s += c[i] + 1;
  part[tid] = s;
  __syncthreads();
  if (tid == 0) {
    int run = 0;
    for (int i = 0; i < 256; i++) { int v = part[i]; part[i] = run; run += v; }
  }
  __syncthreads();
  int run = part[tid];
  for (int i = lo; i < hi; i++) { r[i] = run; tm[i] = run; run += c[i] + 1; }
  if (lo < NN && hi == NN) r[NN] = run;
}

// dst-partitioned fill
#define FCHUNK 4096
__global__ __launch_bounds__(256) void k_fill(
    const int* __restrict__ e0, const int* __restrict__ e1,
    const int* __restrict__ e2, const int* __restrict__ e3,
    int* __restrict__ tmp, int* __restrict__ col) {
  int p = blockIdx.x;
  int dlo = p * (NN / 8), dhi = dlo + (NN / 8);
  int base = blockIdx.y * FCHUNK;
  for (int o = threadIdx.x; o < FCHUNK; o += 256) {
    int i = base + o;
    if (i >= 4 * EPN) return;
    int t = i / EPN, j = i - t * EPN;
    int s, d;
    if (j < NE) {
      const int* eb = t == 0 ? e0 : t == 1 ? e1 : t == 2 ? e2 : e3;
      d = eb[NE + j];
      if (d < dlo || d >= dhi) continue;
      s = eb[j];
    } else {
      s = d = j - NE;
      if (d < dlo || d >= dhi) continue;
    }
    int pos = atomicAdd(&tmp[t * NN + d], 1);
    col[(size_t)t * EPN + pos] = s;
  }
}

// -------- prep: PT tables, bmean, bf16 W^T, and x->bf16 convert (fused) -------
__global__ void k_prep(const float* __restrict__ W0, const float* __restrict__ as0,
                       const float* __restrict__ ad0, const float* __restrict__ b0,
                       const float* __restrict__ W1, const float* __restrict__ as1,
                       const float* __restrict__ ad1, const float* __restrict__ b1,
                       float* __restrict__ PT0, float* __restrict__ PT1,
                       float* __restrict__ bmean,
                       unsigned short* __restrict__ WbT0,
                       unsigned short* __restrict__ WbT1,
                       const float4* __restrict__ xin, ushort4* __restrict__ xb0) {
  int i = blockIdx.x * blockDim.x + threadIdx.x;
  if (i < 4096) {
    int r = i >> 7, k = i & 127;
    int sd = r >> 4, t = (r >> 2) & 3, h = r & 3;
    const float* a = (sd ? ad0 : as0) + (t * 4 + h) * 64;
    const float* wr = W0 + ((size_t)t * 128 + k) * 256 + h * 64;
    float s = 0.f;
    for (int c = 0; c < 64; c++) s = fmaf(wr[c], a[c], s);
    PT0[r * 128 + k] = s;
  } else if (i < 6144) {
    int j = i - 4096;
    int r = j >> 6, k = j & 63;
    int sd = r >> 4, t = (r >> 2) & 3, h = r & 3;
    const float* a = (sd ? ad1 : as1) + (t * 4 + h) * 64;
    const float* wr = W1 + ((size_t)t * 64 + k) * 256 + h * 64;
    float s = 0.f;
    for (int c = 0; c < 64; c++) s = fmaf(wr[c], a[c], s);
    PT1[r * 64 + k] = s;
  } else if (i < 6272) {
    int j = i - 6144;
    int l = j >> 6, c = j & 63;
    const float* b = l ? b1 : b0;
    bmean[j] = 0.25f * (b[c] + b[64 + c] + b[128 + c] + b[192 + c]);
  } else if (i < 6272 + 64 * 2048) {
    int j = i - 6272;
    int c = j >> 11, kt = j & 2047;            // kt = (t*4+h)*128 + k
    int t = kt >> 9, h = (kt >> 7) & 3, k = kt & 127;
    WbT0[(size_t)c * 2048 + kt] = bf16r(W0[((size_t)t * 128 + k) * 256 + h * 64 + c]);
  } else if (i < 6272 + 64 * 2048 + 64 * 1024) {
    int j = i - 6272 - 64 * 2048;
    int c = j >> 10, kt = j & 1023;            // kt = (t*4+h)*64 + k
    int t = kt >> 8, h = (kt >> 6) & 3, k = kt & 63;
    WbT1[(size_t)c * 1024 + kt] = bf16r(W1[((size_t)t * 64 + k) * 256 + h * 64 + c]);
  } else if (i < 6272 + 64 * 2048 + 64 * 1024 + NN * 32) {
    int j = i - (6272 + 64 * 2048 + 64 * 1024);
    float4 v = xin[j];
    ushort4 o;
    o.x = bf16r(v.x); o.y = bf16r(v.y); o.z = bf16r(v.z); o.w = bf16r(v.w);
    xb0[j] = o;
  }
}

// ---------------- layer-0 coefficients: asrc/adst[v][16] = x[v] @ PT0^T -------
template <int K>
__global__ __launch_bounds__(256) void k_coef(const float* __restrict__ xin,
                                              const float* __restrict__ PT,
                                              float* __restrict__ asrc,
                                              float* __restrict__ adst) {
  __shared__ float PTs[32][K + 4];
  __shared__ float Xs[4][K];
  int tid = threadIdx.x;
#pragma unroll
  for (int j = 0; j < (32 * K) / 1024; j++) {
    int f4 = tid + j * 256;
    int r = f4 / (K / 4), c4 = (f4 % (K / 4)) * 4;
    *(float4*)&PTs[r][c4] = *(const float4*)(PT + r * K + c4);
  }
  int w = tid >> 6, lane = tid & 63;
  int v = blockIdx.x * 4 + w;
  if (lane * 2 < K)
    *(float2*)&Xs[w][lane * 2] = *(const float2*)(xin + (size_t)v * K + lane * 2);
  __syncthreads();
  int s = lane & 31, h2 = lane >> 5;
  float acc = 0.f;
#pragma unroll
  for (int i = 0; i < K / 8; i++) {
    int k = h2 * (K / 2) + i * 4;
    float4 p = *(const float4*)&PTs[s][k];
    float4 xv = *(const float4*)&Xs[w][k];
    acc = fmaf(p.x, xv.x, fmaf(p.y, xv.y, fmaf(p.z, xv.z, fmaf(p.w, xv.w, acc))));
  }
  acc += __shfl_xor(acc, 32);
  if (lane < 16) asrc[(size_t)v * 16 + lane] = acc;
  else if (lane < 32) adst[(size_t)v * 16 + (lane - 16)] = acc;
}

// ------- x-space aggregation v5: block = 2 nodes, wave = 1 type -------
// Wave halves (32 lanes) each own one node. K=128: one 32-lane edge group per
// node (4 cols/lane) -> NO cross-group reduce. K=64: 2 groups/node -> 1 stage.
// Pass1: (edge,head)-per-lane (8 edges x 4 heads per half), no max subtraction.
template <int K>
__global__ __launch_bounds__(256) void k_aggx5(
    const int* __restrict__ rp, const int* __restrict__ col,
    const float* __restrict__ asrc, const float* __restrict__ adst,
    const unsigned short* __restrict__ xb, unsigned short* __restrict__ y) {
  __shared__ float wl[4][2][DCAP * 4];
  __shared__ int scol[4][2][DCAP];   // stores s*K (pre-multiplied)
  __shared__ float zs[4][2][4];
  int t = threadIdx.x >> 6, lane = threadIdx.x & 63;
  int nh = lane >> 5, ll = lane & 31;
  int v = blockIdx.x * 2 + nh;
  int beg = rp[t * RP_STRIDE + v], deg = rp[t * RP_STRIDE + v + 1] - beg;
  const int* colt = col + (size_t)t * EPN + beg;
  // pass-2 geometry: K=128 -> 1 group of 32; K=64 -> 2 groups of 16
  int g = (K == 128) ? 0 : (ll >> 4);
  int step = (K == 128) ? 1 : 2;
  int c4 = (K == 128) ? (ll * 4) : ((ll & 15) * 4);
  f32x2 acc[4][2] = {};   // [col][head-pair]
  float rz[4];

  if (deg <= DCAP) {
    int il = ll & 7, hq = ll >> 3;
    float advh = adst[(size_t)v * 16 + t * 4 + hq];
    float z = 0.f;
    for (int i = il; i < deg; i += 8) {
      int s = colt[i];
      if (hq == 0) scol[t][nh][i] = s * K;
      float e = asrc[(size_t)s * 16 + t * 4 + hq] + advh;
      float w = __expf(LRELU(e));
      wl[t][nh][i * 4 + hq] = w;
      z += w;
    }
    z += __shfl_xor(z, 1); z += __shfl_xor(z, 2); z += __shfl_xor(z, 4);
    if (il == 0) zs[t][nh][hq] = z;
    // pass 2: packed gather (wave-synchronous LDS, no barrier needed)
    const unsigned short* xc = xb + c4;
    const float* wlp = wl[t][nh];
    const int* scp = scol[t][nh];
    int i = g;
    for (; i + step < deg; i += 2 * step) {
      float4 wv0 = *(const float4*)&wlp[i * 4];
      float4 wv1 = *(const float4*)&wlp[(i + step) * 4];
      uint2 r0 = *(const uint2*)(xc + scp[i]);
      uint2 r1 = *(const uint2*)(xc + scp[i + step]);
      accumpk(acc, wv0, r0);
      accumpk(acc, wv1, r1);
    }
    if (i < deg) {
      float4 wv0 = *(const float4*)&wlp[i * 4];
      uint2 r0 = *(const uint2*)(xc + scp[i]);
      accumpk(acc, wv0, r0);
    }
#pragma unroll
    for (int h = 0; h < 4; h++) rz[h] = 1.f / zs[t][nh][h];
  } else {
    // fallback: online softmax (deg unbounded; practically never taken)
    float4 adv = *(const float4*)(adst + (size_t)v * 16 + t * 4);
    float m[4] = {-1e30f, -1e30f, -1e30f, -1e30f};
    float z[4] = {0.f, 0.f, 0.f, 0.f};
    float advv[4] = {adv.x, adv.y, adv.z, adv.w};
    for (int i = g; i < deg; i += step) {
      int s = colt[i];
      float4 a = *(const float4*)(asrc + (size_t)s * 16 + t * 4);
      float av[4] = {a.x, a.y, a.z, a.w};
#pragma unroll
      for (int h = 0; h < 4; h++) {
        float e = LRELU(av[h] + advv[h]);
        float nm = fmaxf(m[h], e);
        z[h] = z[h] * __expf(m[h] - nm) + __expf(e - nm);
        m[h] = nm;
      }
    }
    if (K == 64) {
#pragma unroll
      for (int h = 0; h < 4; h++) {
        float m2_ = __shfl_xor(m[h], 16);
        float z2_ = __shfl_xor(z[h], 16);
        float nm = fmaxf(m[h], m2_);
        z[h] = z[h] * __expf(m[h] - nm) + z2_ * __expf(m2_ - nm);
        m[h] = nm;
      }
    }
#pragma unroll
    for (int h = 0; h < 4; h++) rz[h] = 1.f / z[h];
    for (int i = g; i < deg; i += step) {
      int s = colt[i];
      float4 a = *(const float4*)(asrc + (size_t)s * 16 + t * 4);
      uint2 raw = *(const uint2*)(xb + (size_t)s * K + c4);
      float av[4] = {a.x, a.y, a.z, a.w};
      float4 wv;
      wv.x = __expf(LRELU(av[0] + advv[0]) - m[0]);
      wv.y = __expf(LRELU(av[1] + advv[1]) - m[1]);
      wv.z = __expf(LRELU(av[2] + advv[2]) - m[2]);
      wv.w = __expf(LRELU(av[3] + advv[3]) - m[3]);
      accumpk(acc, wv, raw);
    }
  }
  // K=64: combine the node's 2 edge groups (xor 16 stays within the half)
  if (K == 64) {
#pragma unroll
    for (int c = 0; c < 4; c++)
#pragma unroll
      for (int p = 0; p < 2; p++) {
        acc[c][p].x += __shfl_xor(acc[c][p].x, 16);
        acc[c][p].y += __shfl_xor(acc[c][p].y, 16);
      }
  }
  if (K == 128 || (ll & 16) == 0) {
#pragma unroll
    for (int h = 0; h < 4; h++) {
      int p = h >> 1, j = h & 1;
      ushort4 o;
      o.x = bf16r((j ? acc[0][p].y : acc[0][p].x) * rz[h]);
      o.y = bf16r((j ? acc[1][p].y : acc[1][p].x) * rz[h]);
      o.z = bf16r((j ? acc[2][p].y : acc[2][p].x) * rz[h]);
      o.w = bf16r((j ? acc[3][p].y : acc[3][p].x) * rz[h]);
      *(ushort4*)(y + (size_t)v * (16 * K) + (size_t)(t * 4 + h) * K + c4) = o;
    }
  }
}

// ---- MFMA split-K output GEMM: part[ks] = y(bf16) @ WbT(bf16)^T chunk ----
template <int K>
__global__ __launch_bounds__(256) void k_out_mfma(
    const unsigned short* __restrict__ y, const unsigned short* __restrict__ WbT,
    float* __restrict__ part) {
  constexpr int KT = 16 * K;
  constexpr int CHUNK = KT / KSPLIT;
  int w = threadIdx.x >> 6, l = threadIdx.x & 63;
  int row0 = blockIdx.x * 64 + w * 16;
  int ks = blockIdx.y;
  int lr = l & 15, kg = l >> 4;
  int arow = row0 + lr;
  bool rowok = arow < NN;
  const unsigned short* yb = y + (size_t)arow * KT + ks * CHUNK + kg * 8;
  const unsigned short* wb = WbT + (size_t)lr * KT + ks * CHUNK + kg * 8;
  f32x4 a0 = {0.f, 0.f, 0.f, 0.f}, a1 = a0, a2 = a0, a3 = a0;
  for (int kk = 0; kk < CHUNK; kk += 32) {
    bf16x8 av = {};
    if (rowok) av = *(const bf16x8*)(yb + kk);
    bf16x8 b0 = *(const bf16x8*)(wb + kk);
    bf16x8 b1 = *(const bf16x8*)(wb + 16 * KT + kk);
    bf16x8 b2 = *(const bf16x8*)(wb + 32 * KT + kk);
    bf16x8 b3 = *(const bf16x8*)(wb + 48 * KT + kk);
    a0 = __builtin_amdgcn_mfma_f32_16x16x32_bf16(av, b0, a0, 0, 0, 0);
    a1 = __builtin_amdgcn_mfma_f32_16x16x32_bf16(av, b1, a1, 0, 0, 0);
    a2 = __builtin_amdgcn_mfma_f32_16x16x32_bf16(av, b2, a2, 0, 0, 0);
    a3 = __builtin_amdgcn_mfma_f32_16x16x32_bf16(av, b3, a3, 0, 0, 0);
  }
  int orow = row0 + kg * 4;
  float* pb = part + (size_t)ks * NN * 64 + (size_t)orow * 64 + lr;
#pragma unroll
  for (int j = 0; j < 4; j++) {
    if (orow + j < NN) {
      pb[(size_t)j * 64 + 0]  = a0[j];
      pb[(size_t)j * 64 + 16] = a1[j];
      pb[(size_t)j * 64 + 32] = a2[j];
      pb[(size_t)j * 64 + 48] = a3[j];
    }
  }
}

// ---- layer-0 reduce FUSED with layer-1 coefficients ----
__global__ __launch_bounds__(256) void k_red_coef(
    const float* __restrict__ part, const float* __restrict__ bm,
    const float* __restrict__ PT1, unsigned short* __restrict__ xb1,
    float* __restrict__ asrc, float* __restrict__ adst) {
  __shared__ float xv[4][64];
  __shared__ float PTs[32][65];
  int tid = threadIdx.x;
  for (int j = tid; j < 2048; j += 256) PTs[j >> 6][j & 63] = PT1[j];
  int n = tid >> 6, c = tid & 63;
  int v = blockIdx.x * 4 + n;
  float s = 0.f;
#pragma unroll
  for (int ks = 0; ks < KSPLIT; ks++)
    s += part[(size_t)ks * NN * 64 + (size_t)v * 64 + c];
  float xval = fmaxf(0.0625f * s + bm[c], 0.f);
  xv[n][c] = xval;
  xb1[(size_t)v * 64 + c] = bf16r(xval);
  __syncthreads();
  int row = c & 31, half = c >> 5;
  const float* xr = xv[n] + half * 32;
  const float* pr = &PTs[row][half * 32];
  float dot = 0.f;
#pragma unroll 8
  for (int j = 0; j < 32; j++) dot = fmaf(pr[j], xr[j], dot);
  dot += __shfl_xor(dot, 32);
  if (half == 0) {
    if (row < 16) asrc[(size_t)v * 16 + row] = dot;
    else adst[(size_t)v * 16 + (row - 16)] = dot;
  }
}

// layer-1 reduce fused with final linear
__global__ __launch_bounds__(256) void k_red_lin(
    const float* __restrict__ part, const float* __restrict__ bm,
    const float* __restrict__ linW, const float* __restrict__ linb,
    float* __restrict__ out) {
  __shared__ float xv[4][64];
  int n = threadIdx.x >> 6, c = threadIdx.x & 63;
  int v = blockIdx.x * 4 + n;
  float s = 0.f;
#pragma unroll
  for (int ks = 0; ks < KSPLIT; ks++)
    s += part[(size_t)ks * NN * 64 + (size_t)v * 64 + c];
  xv[n][c] = fmaxf(0.0625f * s + bm[c], 0.f);
  __syncthreads();
  if (c < 32) {
    float acc = linb[c];
#pragma unroll
    for (int cc = 0; cc < 64; cc++) acc = fmaf(xv[n][cc], linW[cc * 32 + c], acc);
    out[(size_t)v * 32 + c] = acc;
  }
}

extern "C" void kernel_launch(void* const* d_in, const int* in_sizes, int n_in,
                              void* d_out, int out_size, void* d_ws, size_t ws_size,
                              hipStream_t stream) {
  const float* x = (const float*)d_in[0];
  const int* e0 = (const int*)d_in[1];
  const int* e1 = (const int*)d_in[2];
  const int* e2 = (const int*)d_in[3];
  const int* e3 = (const int*)d_in[4];
  const float* W0 = (const float*)d_in[5];
  const float* as0 = (const float*)d_in[6];
  const float* ad0 = (const float*)d_in[7];
  const float* b0 = (const float*)d_in[8];
  const float* W1 = (const float*)d_in[9];
  const float* as1 = (const float*)d_in[10];
  const float* ad1 = (const float*)d_in[11];
  const float* b1 = (const float*)d_in[12];
  const float* linW = (const float*)d_in[13];
  const float* linb = (const float*)d_in[14];
  float* out = (float*)d_out;
  (void)in_sizes; (void)n_in; (void)out_size; (void)ws_size;

  char* wsb = (char*)d_ws;
  size_t off = 0;
  auto carve = [&](size_t bytes) -> char* {
    off = (off + 255) & ~(size_t)255;
    char* p = wsb + off;
    off += bytes;
    return p;
  };
  int* cnt     = (int*)carve((size_t)4 * NN * sizeof(int));
  int* tmp     = (int*)carve((size_t)4 * NN * sizeof(int));
  int* rp      = (int*)carve((size_t)4 * RP_STRIDE * sizeof(int));
  int* col     = (int*)carve((size_t)4 * EPN * sizeof(int));
  float* asrc  = (float*)carve((size_t)NN * 16 * sizeof(float));
  float* adst  = (float*)carve((size_t)NN * 16 * sizeof(float));
  float* PT0   = (float*)carve((size_t)32 * 128 * sizeof(float));
  float* PT1   = (float*)carve((size_t)32 * 64 * sizeof(float));
  float* bmean = (float*)carve((size_t)128 * sizeof(float));
  unsigned short* WbT0 = (unsigned short*)carve((size_t)64 * 2048 * sizeof(unsigned short));
  unsigned short* WbT1 = (unsigned short*)carve((size_t)64 * 1024 * sizeof(unsigned short));
  unsigned short* xb0 = (unsigned short*)carve((size_t)NN * 128 * sizeof(unsigned short));
  unsigned short* xb1 = (unsigned short*)carve((size_t)NN * 64 * sizeof(unsigned short));
  unsigned short* y = (unsigned short*)carve((size_t)NN * 2048 * sizeof(unsigned short));
  float* part  = (float*)carve((size_t)KSPLIT * NN * 64 * sizeof(float));

  // CSR build
  hipMemsetAsync(cnt, 0, (size_t)4 * NN * sizeof(int), stream);
  k_count<<<(4 * NQ + 255) / 256, 256, 0, stream>>>(
      (const int4*)(e0 + NE), (const int4*)(e1 + NE),
      (const int4*)(e2 + NE), (const int4*)(e3 + NE), cnt);
  k_scan<<<4, 256, 0, stream>>>(cnt, rp, tmp);
  k_fill<<<dim3(8, (4 * EPN + FCHUNK - 1) / FCHUNK), 256, 0, stream>>>(
      e0, e1, e2, e3, tmp, col);

  const int PREP_N = 6272 + 64 * 2048 + 64 * 1024 + NN * 32;
  k_prep<<<(PREP_N + 255) / 256, 256, 0, stream>>>(
      W0, as0, ad0, b0, W1, as1, ad1, b1, PT0, PT1, bmean, WbT0, WbT1,
      (const float4*)x, (ushort4*)xb0);

  // ---- layer 0 (K=128, KT=2048) ----
  k_coef<128><<<5000, 256, 0, stream>>>(x, PT0, asrc, adst);
  k_aggx5<128><<<NN / 2, 256, 0, stream>>>(rp, col, asrc, adst, xb0, y);
  k_out_mfma<128><<<dim3(313, KSPLIT), 256, 0, stream>>>(y, WbT0, part);
  k_red_coef<<<NN / 4, 256, 0, stream>>>(part, bmean, PT1, xb1, asrc, adst);

  // ---- layer 1 (K=64, KT=1024) ----
  k_aggx5<64><<<NN / 2, 256, 0, stream>>>(rp, col, asrc, adst, xb1, y);
  k_out_mfma<64><<<dim3(313, KSPLIT), 256, 0, stream>>>(y, WbT1, part);
  k_red_lin<<<NN / 4, 256, 0, stream>>>(part, bmean + 64, linW, linb, out);
}

// Round 18
// 385.467 us; speedup vs baseline: 1.5221x; 1.0007x over previous
//
#include <hip/hip_runtime.h>

#define NN 20000
#define NE 320000
#define EPN (NE + NN)   // edges + self loops = 340000
#define RP_STRIDE 20004
#define DCAP 64
#define KSPLIT 4
#define NQ (NE / 4)

#define LRELU(e) ((e) > 0.f ? (e) : 0.2f * (e))

typedef __attribute__((ext_vector_type(8))) short bf16x8;
typedef __attribute__((ext_vector_type(4))) float f32x4;
typedef __attribute__((ext_vector_type(2))) float f32x2;

// round-to-nearest-even fp32 -> bf16
__device__ __forceinline__ unsigned short bf16r(float f) {
  union { float f; unsigned int u; } c;
  c.f = f;
  unsigned int r = (c.u + 0x7FFFu + ((c.u >> 16) & 1u)) >> 16;
  return (unsigned short)r;
}
__device__ __forceinline__ float bflo(unsigned int u) {
  return __uint_as_float(u << 16);
}
__device__ __forceinline__ float bfhi(unsigned int u) {
  return __uint_as_float(u & 0xFFFF0000u);
}

// packed accumulate: acc[c][p] covers (head p*2, head p*2+1) at column c.
__device__ __forceinline__ void accumpk(f32x2 acc[4][2], const float4& wv, uint2 raw) {
  f32x2 wlo = {wv.x, wv.y};
  f32x2 whi = {wv.z, wv.w};
  float x0 = bflo(raw.x), x1 = bfhi(raw.x);
  float x2 = bflo(raw.y), x3 = bfhi(raw.y);
  f32x2 s0 = {x0, x0}, s1 = {x1, x1}, s2 = {x2, x2}, s3 = {x3, x3};
  acc[0][0] = __builtin_elementwise_fma(wlo, s0, acc[0][0]);
  acc[0][1] = __builtin_elementwise_fma(whi, s0, acc[0][1]);
  acc[1][0] = __builtin_elementwise_fma(wlo, s1, acc[1][0]);
  acc[1][1] = __builtin_elementwise_fma(whi, s1, acc[1][1]);
  acc[2][0] = __builtin_elementwise_fma(wlo, s2, acc[2][0]);
  acc[2][1] = __builtin_elementwise_fma(whi, s2, acc[2][1]);
  acc[3][0] = __builtin_elementwise_fma(wlo, s3, acc[3][0]);
  acc[3][1] = __builtin_elementwise_fma(whi, s3, acc[3][1]);
}

// ---------------- CSR build ----------------
__global__ void k_count(const int4* __restrict__ d0, const int4* __restrict__ d1,
                        const int4* __restrict__ d2, const int4* __restrict__ d3,
                        int* __restrict__ cnt) {
  int i = blockIdx.x * blockDim.x + threadIdx.x;
  if (i >= 4 * NQ) return;
  int t = i / NQ, j = i - t * NQ;
  const int4* d = t == 0 ? d0 : t == 1 ? d1 : t == 2 ? d2 : d3;
  int4 v = d[j];
  int* c = cnt + t * NN;
  atomicAdd(&c[v.x], 1); atomicAdd(&c[v.y], 1);
  atomicAdd(&c[v.z], 1); atomicAdd(&c[v.w], 1);
}

// self-loop (+1 per node) folded into the scan
__global__ void k_scan(const int* __restrict__ cnt, int* __restrict__ rp, int* __restrict__ tmp) {
  int t = blockIdx.x;
  const int* c = cnt + t * NN;
  int* r = rp + t * RP_STRIDE;
  int* tm = tmp + t * NN;
  __shared__ int part[256];
  int tid = threadIdx.x;
  const int CH = (NN + 255) / 256;
  int lo = tid * CH, hi = min(lo + CH, NN);
  int s = 0;
  for (int i = lo; i < hi; i++) s += c[i] + 1;
  part[tid] = s;
  __syncthreads();
  if (tid == 0) {
    int run = 0;
    for (int i = 0; i < 256; i++) { int v = part[i]; part[i] = run; run += v; }
  }
  __syncthreads();
  int run = part[tid];
  for (int i = lo; i < hi; i++) { r[i] = run; tm[i] = run; run += c[i] + 1; }
  if (lo < NN && hi == NN) r[NN] = run;
}

// dst-partitioned edge fill, int4-vectorized: 4 independent atomic chains/thread.
__global__ __launch_bounds__(256) void k_fill_e(
    const int* __restrict__ e0, const int* __restrict__ e1,
    const int* __restrict__ e2, const int* __restrict__ e3,
    int* __restrict__ tmp, int* __restrict__ col) {
  int p = blockIdx.x;
  int dlo = p * (NN / 8), dhi = dlo + (NN / 8);
  int i4 = blockIdx.y * 256 + threadIdx.x;
  if (i4 >= 4 * NQ) return;
  int t = i4 / NQ, j4 = i4 - t * NQ;
  const int* eb = t == 0 ? e0 : t == 1 ? e1 : t == 2 ? e2 : e3;
  int4 d4 = ((const int4*)(eb + NE))[j4];
  int4 s4 = ((const int4*)eb)[j4];
  int dd[4] = {d4.x, d4.y, d4.z, d4.w};
  int ss[4] = {s4.x, s4.y, s4.z, s4.w};
  int* tt = tmp + t * NN;
  int* ct = col + (size_t)t * EPN;
#pragma unroll
  for (int c = 0; c < 4; c++) {
    if (dd[c] >= dlo && dd[c] < dhi) {
      int pos = atomicAdd(&tt[dd[c]], 1);
      ct[pos] = ss[c];
    }
  }
}

// self loops (non-aligned tail of each bucket; order within bucket irrelevant)
__global__ void k_fill_sl(int* __restrict__ tmp, int* __restrict__ col) {
  int i = blockIdx.x * blockDim.x + threadIdx.x;
  if (i >= 4 * NN) return;
  int t = i / NN, d = i - t * NN;
  int pos = atomicAdd(&tmp[t * NN + d], 1);
  col[(size_t)t * EPN + pos] = d;
}

// -------- prep: PT tables, bmean, bf16 W^T, and x->bf16 convert (fused) -------
__global__ void k_prep(const float* __restrict__ W0, const float* __restrict__ as0,
                       const float* __restrict__ ad0, const float* __restrict__ b0,
                       const float* __restrict__ W1, const float* __restrict__ as1,
                       const float* __restrict__ ad1, const float* __restrict__ b1,
                       float* __restrict__ PT0, float* __restrict__ PT1,
                       float* __restrict__ bmean,
                       unsigned short* __restrict__ WbT0,
                       unsigned short* __restrict__ WbT1,
                       const float4* __restrict__ xin, ushort4* __restrict__ xb0) {
  int i = blockIdx.x * blockDim.x + threadIdx.x;
  if (i < 4096) {
    int r = i >> 7, k = i & 127;
    int sd = r >> 4, t = (r >> 2) & 3, h = r & 3;
    const float* a = (sd ? ad0 : as0) + (t * 4 + h) * 64;
    const float* wr = W0 + ((size_t)t * 128 + k) * 256 + h * 64;
    float s = 0.f;
    for (int c = 0; c < 64; c++) s = fmaf(wr[c], a[c], s);
    PT0[r * 128 + k] = s;
  } else if (i < 6144) {
    int j = i - 4096;
    int r = j >> 6, k = j & 63;
    int sd = r >> 4, t = (r >> 2) & 3, h = r & 3;
    const float* a = (sd ? ad1 : as1) + (t * 4 + h) * 64;
    const float* wr = W1 + ((size_t)t * 64 + k) * 256 + h * 64;
    float s = 0.f;
    for (int c = 0; c < 64; c++) s = fmaf(wr[c], a[c], s);
    PT1[r * 64 + k] = s;
  } else if (i < 6272) {
    int j = i - 6144;
    int l = j >> 6, c = j & 63;
    const float* b = l ? b1 : b0;
    bmean[j] = 0.25f * (b[c] + b[64 + c] + b[128 + c] + b[192 + c]);
  } else if (i < 6272 + 64 * 2048) {
    int j = i - 6272;
    int c = j >> 11, kt = j & 2047;            // kt = (t*4+h)*128 + k
    int t = kt >> 9, h = (kt >> 7) & 3, k = kt & 127;
    WbT0[(size_t)c * 2048 + kt] = bf16r(W0[((size_t)t * 128 + k) * 256 + h * 64 + c]);
  } else if (i < 6272 + 64 * 2048 + 64 * 1024) {
    int j = i - 6272 - 64 * 2048;
    int c = j >> 10, kt = j & 1023;            // kt = (t*4+h)*64 + k
    int t = kt >> 8, h = (kt >> 6) & 3, k = kt & 63;
    WbT1[(size_t)c * 1024 + kt] = bf16r(W1[((size_t)t * 64 + k) * 256 + h * 64 + c]);
  } else if (i < 6272 + 64 * 2048 + 64 * 1024 + NN * 32) {
    int j = i - (6272 + 64 * 2048 + 64 * 1024);
    float4 v = xin[j];
    ushort4 o;
    o.x = bf16r(v.x); o.y = bf16r(v.y); o.z = bf16r(v.z); o.w = bf16r(v.w);
    xb0[j] = o;
  }
}

// ---------------- layer-0 coefficients: asrc/adst[v][16] = x[v] @ PT0^T -------
template <int K>
__global__ __launch_bounds__(256) void k_coef(const float* __restrict__ xin,
                                              const float* __restrict__ PT,
                                              float* __restrict__ asrc,
                                              float* __restrict__ adst) {
  __shared__ float PTs[32][K + 4];
  __shared__ float Xs[4][K];
  int tid = threadIdx.x;
#pragma unroll
  for (int j = 0; j < (32 * K) / 1024; j++) {
    int f4 = tid + j * 256;
    int r = f4 / (K / 4), c4 = (f4 % (K / 4)) * 4;
    *(float4*)&PTs[r][c4] = *(const float4*)(PT + r * K + c4);
  }
  int w = tid >> 6, lane = tid & 63;
  int v = blockIdx.x * 4 + w;
  if (lane * 2 < K)
    *(float2*)&Xs[w][lane * 2] = *(const float2*)(xin + (size_t)v * K + lane * 2);
  __syncthreads();
  int s = lane & 31, h2 = lane >> 5;
  float acc = 0.f;
#pragma unroll
  for (int i = 0; i < K / 8; i++) {
    int k = h2 * (K / 2) + i * 4;
    float4 p = *(const float4*)&PTs[s][k];
    float4 xv = *(const float4*)&Xs[w][k];
    acc = fmaf(p.x, xv.x, fmaf(p.y, xv.y, fmaf(p.z, xv.z, fmaf(p.w, xv.w, acc))));
  }
  acc += __shfl_xor(acc, 32);
  if (lane < 16) asrc[(size_t)v * 16 + lane] = acc;
  else if (lane < 32) adst[(size_t)v * 16 + (lane - 16)] = acc;
}

// ------- x-space aggregation v5: block = 2 nodes, wave = 1 type -------
template <int K>
__global__ __launch_bounds__(256) void k_aggx5(
    const int* __restrict__ rp, const int* __restrict__ col,
    const float* __restrict__ asrc, const float* __restrict__ adst,
    const unsigned short* __restrict__ xb, unsigned short* __restrict__ y) {
  __shared__ float wl[4][2][DCAP * 4];
  __shared__ int scol[4][2][DCAP];   // stores s*K (pre-multiplied)
  __shared__ float zs[4][2][4];
  int t = threadIdx.x >> 6, lane = threadIdx.x & 63;
  int nh = lane >> 5, ll = lane & 31;
  int v = blockIdx.x * 2 + nh;
  int beg = rp[t * RP_STRIDE + v], deg = rp[t * RP_STRIDE + v + 1] - beg;
  const int* colt = col + (size_t)t * EPN + beg;
  int g = (K == 128) ? 0 : (ll >> 4);
  int step = (K == 128) ? 1 : 2;
  int c4 = (K == 128) ? (ll * 4) : ((ll & 15) * 4);
  f32x2 acc[4][2] = {};   // [col][head-pair]
  float rz[4];

  if (deg <= DCAP) {
    int il = ll & 7, hq = ll >> 3;
    float advh = adst[(size_t)v * 16 + t * 4 + hq];
    float z = 0.f;
    for (int i = il; i < deg; i += 8) {
      int s = colt[i];
      if (hq == 0) scol[t][nh][i] = s * K;
      float e = asrc[(size_t)s * 16 + t * 4 + hq] + advh;
      float w = __expf(LRELU(e));
      wl[t][nh][i * 4 + hq] = w;
      z += w;
    }
    z += __shfl_xor(z, 1); z += __shfl_xor(z, 2); z += __shfl_xor(z, 4);
    if (il == 0) zs[t][nh][hq] = z;
    const unsigned short* xc = xb + c4;
    const float* wlp = wl[t][nh];
    const int* scp = scol[t][nh];
    int i = g;
    for (; i + step < deg; i += 2 * step) {
      float4 wv0 = *(const float4*)&wlp[i * 4];
      float4 wv1 = *(const float4*)&wlp[(i + step) * 4];
      uint2 r0 = *(const uint2*)(xc + scp[i]);
      uint2 r1 = *(const uint2*)(xc + scp[i + step]);
      accumpk(acc, wv0, r0);
      accumpk(acc, wv1, r1);
    }
    if (i < deg) {
      float4 wv0 = *(const float4*)&wlp[i * 4];
      uint2 r0 = *(const uint2*)(xc + scp[i]);
      accumpk(acc, wv0, r0);
    }
#pragma unroll
    for (int h = 0; h < 4; h++) rz[h] = 1.f / zs[t][nh][h];
  } else {
    // fallback: online softmax (deg unbounded; practically never taken)
    float4 adv = *(const float4*)(adst + (size_t)v * 16 + t * 4);
    float m[4] = {-1e30f, -1e30f, -1e30f, -1e30f};
    float z[4] = {0.f, 0.f, 0.f, 0.f};
    float advv[4] = {adv.x, adv.y, adv.z, adv.w};
    for (int i = g; i < deg; i += step) {
      int s = colt[i];
      float4 a = *(const float4*)(asrc + (size_t)s * 16 + t * 4);
      float av[4] = {a.x, a.y, a.z, a.w};
#pragma unroll
      for (int h = 0; h < 4; h++) {
        float e = LRELU(av[h] + advv[h]);
        float nm = fmaxf(m[h], e);
        z[h] = z[h] * __expf(m[h] - nm) + __expf(e - nm);
        m[h] = nm;
      }
    }
    if (K == 64) {
#pragma unroll
      for (int h = 0; h < 4; h++) {
        float m2_ = __shfl_xor(m[h], 16);
        float z2_ = __shfl_xor(z[h], 16);
        float nm = fmaxf(m[h], m2_);
        z[h] = z[h] * __expf(m[h] - nm) + z2_ * __expf(m2_ - nm);
        m[h] = nm;
      }
    }
#pragma unroll
    for (int h = 0; h < 4; h++) rz[h] = 1.f / z[h];
    for (int i = g; i < deg; i += step) {
      int s = colt[i];
      float4 a = *(const float4*)(asrc + (size_t)s * 16 + t * 4);
      uint2 raw = *(const uint2*)(xb + (size_t)s * K + c4);
      float av[4] = {a.x, a.y, a.z, a.w};
      float4 wv;
      wv.x = __expf(LRELU(av[0] + advv[0]) - m[0]);
      wv.y = __expf(LRELU(av[1] + advv[1]) - m[1]);
      wv.z = __expf(LRELU(av[2] + advv[2]) - m[2]);
      wv.w = __expf(LRELU(av[3] + advv[3]) - m[3]);
      accumpk(acc, wv, raw);
    }
  }
  if (K == 64) {
#pragma unroll
    for (int c = 0; c < 4; c++)
#pragma unroll
      for (int p = 0; p < 2; p++) {
        acc[c][p].x += __shfl_xor(acc[c][p].x, 16);
        acc[c][p].y += __shfl_xor(acc[c][p].y, 16);
      }
  }
  if (K == 128 || (ll & 16) == 0) {
#pragma unroll
    for (int h = 0; h < 4; h++) {
      int p = h >> 1, j = h & 1;
      ushort4 o;
      o.x = bf16r((j ? acc[0][p].y : acc[0][p].x) * rz[h]);
      o.y = bf16r((j ? acc[1][p].y : acc[1][p].x) * rz[h]);
      o.z = bf16r((j ? acc[2][p].y : acc[2][p].x) * rz[h]);
      o.w = bf16r((j ? acc[3][p].y : acc[3][p].x) * rz[h]);
      *(ushort4*)(y + (size_t)v * (16 * K) + (size_t)(t * 4 + h) * K + c4) = o;
    }
  }
}

// ---- MFMA split-K output GEMM: part[ks] = y(bf16) @ WbT(bf16)^T chunk ----
template <int K>
__global__ __launch_bounds__(256) void k_out_mfma(
    const unsigned short* __restrict__ y, const unsigned short* __restrict__ WbT,
    float* __restrict__ part) {
  constexpr int KT = 16 * K;
  constexpr int CHUNK = KT / KSPLIT;
  int w = threadIdx.x >> 6, l = threadIdx.x & 63;
  int row0 = blockIdx.x * 64 + w * 16;
  int ks = blockIdx.y;
  int lr = l & 15, kg = l >> 4;
  int arow = row0 + lr;
  bool rowok = arow < NN;
  const unsigned short* yb = y + (size_t)arow * KT + ks * CHUNK + kg * 8;
  const unsigned short* wb = WbT + (size_t)lr * KT + ks * CHUNK + kg * 8;
  f32x4 a0 = {0.f, 0.f, 0.f, 0.f}, a1 = a0, a2 = a0, a3 = a0;
  for (int kk = 0; kk < CHUNK; kk += 32) {
    bf16x8 av = {};
    if (rowok) av = *(const bf16x8*)(yb + kk);
    bf16x8 b0 = *(const bf16x8*)(wb + kk);
    bf16x8 b1 = *(const bf16x8*)(wb + 16 * KT + kk);
    bf16x8 b2 = *(const bf16x8*)(wb + 32 * KT + kk);
    bf16x8 b3 = *(const bf16x8*)(wb + 48 * KT + kk);
    a0 = __builtin_amdgcn_mfma_f32_16x16x32_bf16(av, b0, a0, 0, 0, 0);
    a1 = __builtin_amdgcn_mfma_f32_16x16x32_bf16(av, b1, a1, 0, 0, 0);
    a2 = __builtin_amdgcn_mfma_f32_16x16x32_bf16(av, b2, a2, 0, 0, 0);
    a3 = __builtin_amdgcn_mfma_f32_16x16x32_bf16(av, b3, a3, 0, 0, 0);
  }
  int orow = row0 + kg * 4;
  float* pb = part + (size_t)ks * NN * 64 + (size_t)orow * 64 + lr;
#pragma unroll
  for (int j = 0; j < 4; j++) {
    if (orow + j < NN) {
      pb[(size_t)j * 64 + 0]  = a0[j];
      pb[(size_t)j * 64 + 16] = a1[j];
      pb[(size_t)j * 64 + 32] = a2[j];
      pb[(size_t)j * 64 + 48] = a3[j];
    }
  }
}

// ---- layer-0 reduce FUSED with layer-1 coefficients ----
__global__ __launch_bounds__(256) void k_red_coef(
    const float* __restrict__ part, const float* __restrict__ bm,
    const float* __restrict__ PT1, unsigned short* __restrict__ xb1,
    float* __restrict__ asrc, float* __restrict__ adst) {
  __shared__ float xv[4][64];
  __shared__ float PTs[32][65];
  int tid = threadIdx.x;
  for (int j = tid; j < 2048; j += 256) PTs[j >> 6][j & 63] = PT1[j];
  int n = tid >> 6, c = tid & 63;
  int v = blockIdx.x * 4 + n;
  float s = 0.f;
#pragma unroll
  for (int ks = 0; ks < KSPLIT; ks++)
    s += part[(size_t)ks * NN * 64 + (size_t)v * 64 + c];
  float xval = fmaxf(0.0625f * s + bm[c], 0.f);
  xv[n][c] = xval;
  xb1[(size_t)v * 64 + c] = bf16r(xval);
  __syncthreads();
  int row = c & 31, half = c >> 5;
  const float* xr = xv[n] + half * 32;
  const float* pr = &PTs[row][half * 32];
  float dot = 0.f;
#pragma unroll 8
  for (int j = 0; j < 32; j++) dot = fmaf(pr[j], xr[j], dot);
  dot += __shfl_xor(dot, 32);
  if (half == 0) {
    if (row < 16) asrc[(size_t)v * 16 + row] = dot;
    else adst[(size_t)v * 16 + (row - 16)] = dot;
  }
}

// layer-1 reduce fused with final linear
__global__ __launch_bounds__(256) void k_red_lin(
    const float* __restrict__ part, const float* __restrict__ bm,
    const float* __restrict__ linW, const float* __restrict__ linb,
    float* __restrict__ out) {
  __shared__ float xv[4][64];
  int n = threadIdx.x >> 6, c = threadIdx.x & 63;
  int v = blockIdx.x * 4 + n;
  float s = 0.f;
#pragma unroll
  for (int ks = 0; ks < KSPLIT; ks++)
    s += part[(size_t)ks * NN * 64 + (size_t)v * 64 + c];
  xv[n][c] = fmaxf(0.0625f * s + bm[c], 0.f);
  __syncthreads();
  if (c < 32) {
    float acc = linb[c];
#pragma unroll
    for (int cc = 0; cc < 64; cc++) acc = fmaf(xv[n][cc], linW[cc * 32 + c], acc);
    out[(size_t)v * 32 + c] = acc;
  }
}

extern "C" void kernel_launch(void* const* d_in, const int* in_sizes, int n_in,
                              void* d_out, int out_size, void* d_ws, size_t ws_size,
                              hipStream_t stream) {
  const float* x = (const float*)d_in[0];
  const int* e0 = (const int*)d_in[1];
  const int* e1 = (const int*)d_in[2];
  const int* e2 = (const int*)d_in[3];
  const int* e3 = (const int*)d_in[4];
  const float* W0 = (const float*)d_in[5];
  const float* as0 = (const float*)d_in[6];
  const float* ad0 = (const float*)d_in[7];
  const float* b0 = (const float*)d_in[8];
  const float* W1 = (const float*)d_in[9];
  const float* as1 = (const float*)d_in[10];
  const float* ad1 = (const float*)d_in[11];
  const float* b1 = (const float*)d_in[12];
  const float* linW = (const float*)d_in[13];
  const float* linb = (const float*)d_in[14];
  float* out = (float*)d_out;
  (void)in_sizes; (void)n_in; (void)out_size; (void)ws_size;

  char* wsb = (char*)d_ws;
  size_t off = 0;
  auto carve = [&](size_t bytes) -> char* {
    off = (off + 255) & ~(size_t)255;
    char* p = wsb + off;
    off += bytes;
    return p;
  };
  int* cnt     = (int*)carve((size_t)4 * NN * sizeof(int));
  int* tmp     = (int*)carve((size_t)4 * NN * sizeof(int));
  int* rp      = (int*)carve((size_t)4 * RP_STRIDE * sizeof(int));
  int* col     = (int*)carve((size_t)4 * EPN * sizeof(int));
  float* asrc  = (float*)carve((size_t)NN * 16 * sizeof(float));
  float* adst  = (float*)carve((size_t)NN * 16 * sizeof(float));
  float* PT0   = (float*)carve((size_t)32 * 128 * sizeof(float));
  float* PT1   = (float*)carve((size_t)32 * 64 * sizeof(float));
  float* bmean = (float*)carve((size_t)128 * sizeof(float));
  unsigned short* WbT0 = (unsigned short*)carve((size_t)64 * 2048 * sizeof(unsigned short));
  unsigned short* WbT1 = (unsigned short*)carve((size_t)64 * 1024 * sizeof(unsigned short));
  unsigned short* xb0 = (unsigned short*)carve((size_t)NN * 128 * sizeof(unsigned short));
  unsigned short* xb1 = (unsigned short*)carve((size_t)NN * 64 * sizeof(unsigned short));
  unsigned short* y = (unsigned short*)carve((size_t)NN * 2048 * sizeof(unsigned short));
  float* part  = (float*)carve((size_t)KSPLIT * NN * 64 * sizeof(float));

  // CSR build
  hipMemsetAsync(cnt, 0, (size_t)4 * NN * sizeof(int), stream);
  k_count<<<(4 * NQ + 255) / 256, 256, 0, stream>>>(
      (const int4*)(e0 + NE), (const int4*)(e1 + NE),
      (const int4*)(e2 + NE), (const int4*)(e3 + NE), cnt);
  k_scan<<<4, 256, 0, stream>>>(cnt, rp, tmp);
  k_fill_e<<<dim3(8, (4 * NQ + 255) / 256), 256, 0, stream>>>(
      e0, e1, e2, e3, tmp, col);
  k_fill_sl<<<(4 * NN + 255) / 256, 256, 0, stream>>>(tmp, col);

  const int PREP_N = 6272 + 64 * 2048 + 64 * 1024 + NN * 32;
  k_prep<<<(PREP_N + 255) / 256, 256, 0, stream>>>(
      W0, as0, ad0, b0, W1, as1, ad1, b1, PT0, PT1, bmean, WbT0, WbT1,
      (const float4*)x, (ushort4*)xb0);

  // ---- layer 0 (K=128, KT=2048) ----
  k_coef<128><<<5000, 256, 0, stream>>>(x, PT0, asrc, adst);
  k_aggx5<128><<<NN / 2, 256, 0, stream>>>(rp, col, asrc, adst, xb0, y);
  k_out_mfma<128><<<dim3(313, KSPLIT), 256, 0, stream>>>(y, WbT0, part);
  k_red_coef<<<NN / 4, 256, 0, stream>>>(part, bmean, PT1, xb1, asrc, adst);

  // ---- layer 1 (K=64, KT=1024) ----
  k_aggx5<64><<<NN / 2, 256, 0, stream>>>(rp, col, asrc, adst, xb1, y);
  k_out_mfma<64><<<dim3(313, KSPLIT), 256, 0, stream>>>(y, WbT1, part);
  k_red_lin<<<NN / 4, 256, 0, stream>>>(part, bmean + 64, linW, linb, out);
}